// Round 21
// baseline (349.559 us; speedup 1.0000x reference)
//
#include <hip/hip_runtime.h>
#include <cstdint>
#include <cstddef>

typedef unsigned short u16;
typedef __attribute__((ext_vector_type(8))) __bf16 bf16x8;
typedef __attribute__((ext_vector_type(4))) float f32x4;
typedef __attribute__((ext_vector_type(16))) float f32x16;
typedef __attribute__((ext_vector_type(4))) unsigned u32x4;

#define E_ 2048
#define H_ 16
#define D_ 128
#define QR_ 64
#define KR_ 128
#define S_ 2048
#define B_ 2
#define T_ 4096
#define NSEL_ 2176
#define EPS_ 1e-5f
#define SCALE_ 0.08838834764831845f
#define SCL2_ 0.12751743f  // SCALE_ * log2(e); softmax in exp2 domain

typedef __attribute__((address_space(1))) const void gvoid;
typedef __attribute__((address_space(3))) void lvoid;

__device__ __forceinline__ u16 f2bf(float f) {
  unsigned u = __float_as_uint(f);
  unsigned r = (u + 0x7FFFu + ((u >> 16) & 1u)) >> 16;
  return (u16)r;
}

// ---------------- RoPE tables ----------------
__global__ void k_rope_tables(float* __restrict__ cos_t, float* __restrict__ sin_t) {
  int idx = blockIdx.x * 256 + threadIdx.x;
  if (idx >= S_ * 32) return;
  int t = idx >> 5, j = idx & 31;
  float inv = powf(10000.0f, -(float)j / 32.0f);
  float a = (float)t * inv;
  cos_t[idx] = cosf(a);
  sin_t[idx] = sinf(a);
}

// ---------------- dual LayerNorm ----------------
__global__ __launch_bounds__(256) void k_ln(
    const float* __restrict__ x, const float* __restrict__ gq,
    const float* __restrict__ gkv, u16* __restrict__ lnq, u16* __restrict__ lnkv) {
  int row = blockIdx.x;
  const float* xr = x + (size_t)row * E_;
  int base = threadIdx.x * 8;
  float4 v0 = *(const float4*)(xr + base);
  float4 v1 = *(const float4*)(xr + base + 4);
  float xv[8] = {v0.x, v0.y, v0.z, v0.w, v1.x, v1.y, v1.z, v1.w};
  float s0 = 0.f, s1 = 0.f;
#pragma unroll
  for (int i = 0; i < 8; i++) { s0 += xv[i]; s1 += xv[i] * xv[i]; }
  for (int off = 32; off > 0; off >>= 1) {
    s0 += __shfl_down(s0, off);
    s1 += __shfl_down(s1, off);
  }
  __shared__ float red[2][4];
  int wid = threadIdx.x >> 6, lane = threadIdx.x & 63;
  if (lane == 0) { red[0][wid] = s0; red[1][wid] = s1; }
  __syncthreads();
  s0 = red[0][0] + red[0][1] + red[0][2] + red[0][3];
  s1 = red[1][0] + red[1][1] + red[1][2] + red[1][3];
  float mu = s0 * (1.0f / E_);
  float var = s1 * (1.0f / E_) - mu * mu;
  float rs = rsqrtf(var + EPS_);
  u16 oq[8], okv[8];
#pragma unroll
  for (int i = 0; i < 8; i++) {
    float nv = (xv[i] - mu) * rs;
    oq[i] = f2bf(nv * gq[base + i]);
    okv[i] = f2bf(nv * gkv[base + i]);
  }
  *(ushort4*)(lnq + (size_t)row * E_ + base) = make_ushort4(oq[0], oq[1], oq[2], oq[3]);
  *(ushort4*)(lnq + (size_t)row * E_ + base + 4) = make_ushort4(oq[4], oq[5], oq[6], oq[7]);
  *(ushort4*)(lnkv + (size_t)row * E_ + base) = make_ushort4(okv[0], okv[1], okv[2], okv[3]);
  *(ushort4*)(lnkv + (size_t)row * E_ + base + 4) = make_ushort4(okv[4], okv[5], okv[6], okv[7]);
}

// ---------------- transpose f32 -> bf16 (out[N'][K]) ----------------
template <bool SEL>
__global__ __launch_bounds__(256) void k_transp(
    const float* __restrict__ in, u16* __restrict__ out, int K, int Nin) {
  __shared__ float t[32][33];
  int orb = blockIdx.x * 32;
  int icb;
  if (SEL) {
    icb = (orb < 128) ? orb : 128 + ((orb - 128) >> 7) * 256 + ((orb - 128) & 127);
  } else {
    icb = orb;
  }
  int kb = blockIdx.y * 32;
  int tx = threadIdx.x & 31, ty = threadIdx.x >> 5;
#pragma unroll
  for (int i = 0; i < 4; i++)
    t[ty + i * 8][tx] = in[(size_t)(kb + ty + i * 8) * Nin + icb + tx];
  __syncthreads();
#pragma unroll
  for (int i = 0; i < 4; i++)
    out[(size_t)(orb + ty + i * 8) * K + kb + tx] = f2bf(t[tx][ty + i * 8]);
}

// ---------------- bf16 per-batch 2048x2048 transpose: v_nat -> v_t ----------------
__global__ __launch_bounds__(256) void k_vtr(
    const u16* __restrict__ vn, u16* __restrict__ vt) {
  __shared__ u16 t[32][33];
  int c0 = blockIdx.x * 32;
  int b = blockIdx.y >> 6;
  int s0 = (blockIdx.y & 63) * 32;
  int tx = threadIdx.x & 31, ty = threadIdx.x >> 5;
#pragma unroll
  for (int i = 0; i < 4; i++)
    t[ty + i * 8][tx] = vn[((size_t)(b * 2048 + s0 + ty + i * 8)) * 2048 + c0 + tx];
  __syncthreads();
#pragma unroll
  for (int i = 0; i < 4; i++)
    vt[((size_t)(b * 2048 + c0 + ty + i * 8)) * 2048 + s0 + tx] = t[tx][ty + i * 8];
}

// ---------------- GEMM: C = A[M][K] x Bt[N][K]^T  (T3-min single-barrier, XCD swz) --
struct EpiP {
  float* of32;
  u16* obf;
  u16* kc;
  u16* vt;
  u16* qk;
  const float* cost;
  const float* sint;
};

template <int BM, int BN, int EPI>
__global__ __launch_bounds__(256, 3) void k_gemm(
    const u16* __restrict__ A, const u16* __restrict__ Bt,
    int M, int N, int K, EpiP ep) {
  constexpr int WM = BM / 2;
  constexpr int MI = WM / 16;
  constexpr int WN = BN / 2;
  constexpr int NI = WN / 16;
  __shared__ alignas(16) u16 lsA[2][BM * 32];
  __shared__ alignas(16) u16 lsB[2][BN * 32];
  int tid = threadIdx.x, lane = tid & 63, wid = tid >> 6;
  int wr = wid >> 1, wc = wid & 1;
  // T1: bijective XCD swizzle (all launches have nwg % 8 == 0)
  int gx = gridDim.x;
  int nwg = gx * gridDim.y;
  int flat = blockIdx.y * gx + blockIdx.x;
  int cpx = nwg >> 3;
  int swz = (flat & 7) * cpx + (flat >> 3);
  int bm = swz / gx, bn = swz % gx;
  f32x4 zero4 = {0.f, 0.f, 0.f, 0.f};
  f32x4 acc[MI][NI];
#pragma unroll
  for (int m = 0; m < MI; m++)
#pragma unroll
    for (int n = 0; n < NI; n++) acc[m][n] = zero4;
  const int nkt = K >> 5;
  const u16* Ab = A + (size_t)bm * BM * K;
  const u16* Bb = Bt + (size_t)bn * BN * K;
  int arow = tid >> 2, acol8 = (tid & 3) * 8;
  int lg = lane >> 4, li = lane & 15;

  auto stage = [&](int buf, int kt) {
    int k0 = kt * 32;
#pragma unroll
    for (int c = 0; c < BM / 64; c++) {
      int row = c * 64 + arow;
      __builtin_amdgcn_global_load_lds(
          (gvoid*)(Ab + (size_t)row * K + k0 + acol8),
          (lvoid*)(&lsA[buf][row * 32 + acol8]), 16, 0, 0);
    }
#pragma unroll
    for (int c = 0; c < BN / 64; c++) {
      int row = c * 64 + arow;
      __builtin_amdgcn_global_load_lds(
          (gvoid*)(Bb + (size_t)row * K + k0 + acol8),
          (lvoid*)(&lsB[buf][row * 32 + acol8]), 16, 0, 0);
    }
  };

  // T3-min prologue: tile0 staged + landed before loop
  stage(0, 0);
  asm volatile("s_waitcnt vmcnt(0)" ::: "memory");
  __builtin_amdgcn_s_barrier();
  asm volatile("" ::: "memory");
  for (int kt = 0; kt < nkt; ++kt) {
    int cur = kt & 1;
    if (kt + 1 < nkt) stage(cur ^ 1, kt + 1);  // issue next-tile loads FIRST
    bf16x8 af[MI], bfr[NI];
#pragma unroll
    for (int m = 0; m < MI; m++)
      af[m] = *reinterpret_cast<const bf16x8*>(&lsA[cur][(wr * WM + m * 16 + li) * 32 + lg * 8]);
#pragma unroll
    for (int n = 0; n < NI; n++)
      bfr[n] = *reinterpret_cast<const bf16x8*>(&lsB[cur][(wc * WN + n * 16 + li) * 32 + lg * 8]);
#pragma unroll
    for (int m = 0; m < MI; m++)
#pragma unroll
      for (int n = 0; n < NI; n++)
        acc[m][n] = __builtin_amdgcn_mfma_f32_16x16x32_bf16(af[m], bfr[n], acc[m][n], 0, 0, 0);
    // ONE vmcnt(0)+barrier per K-step: next tile landed (flew under compute),
    // and read-before-overwrite is ordered by the same barrier.
    asm volatile("s_waitcnt vmcnt(0)" ::: "memory");
    __builtin_amdgcn_s_barrier();
    asm volatile("" ::: "memory");
  }
  // epilogue
#pragma unroll
  for (int m = 0; m < MI; m++) {
#pragma unroll
    for (int n = 0; n < NI; n++) {
      int col = bn * BN + wc * WN + n * 16 + li;
#pragma unroll
      for (int r = 0; r < 4; r++) {
        int row = bm * BM + wr * WM + m * 16 + lg * 4 + r;
        float val = acc[m][n][r];
        if constexpr (EPI == 0) {
          ep.obf[(size_t)row * 64 + col] = f2bf(val);
        } else if constexpr (EPI == 1) {
          ep.of32[(size_t)row * E_ + col] = val;
        } else if constexpr (EPI == 2) {
          if (col < KR_) {
            ep.kc[(size_t)row * KR_ + col] = f2bf(val);
          } else {
            ep.vt[(size_t)row * 2048 + (col - KR_)] = f2bf(val);  // coalesced natural v
          }
        } else {  // EPI 3: RoPE + per-head store
          int h = col >> 7, dl = col & 127;
          int b = row >> 11, sp = row & 2047;
          float outv;
          if (dl < 64) {
            float pv = acc[m][n ^ 2][r];
            int j = dl & 31;
            float c = ep.cost[sp * 32 + j];
            float s = ep.sint[sp * 32 + j];
            float rot = (dl < 32) ? -pv : pv;
            outv = val * c + rot * s;
          } else {
            outv = val;
          }
          ep.qk[((size_t)(b * H_ + h) * S_ + sp) * D_ + dl] = f2bf(outv);
        }
      }
    }
  }
}

// ---------------- causal flash attention (split-K + LPT refill, K in registers) ------
// K read per-lane straight from global (row li; 2nd wave of the grp hits L1) -> Ks LDS
// eliminated: 33 KB total -> 3 blocks/CU resident (was 2). V stays LDS double-buffered
// (packed layout needs the gather). Merge buffer reuses Vs (dead after the loop).
__global__ __launch_bounds__(256, 3) void k_attn(
    const u16* __restrict__ q_r, const u16* __restrict__ k_r,
    const u16* __restrict__ v_t, u16* __restrict__ y) {
  __shared__ alignas(16) u16 Vs[2][2][64 * 64];   // [dbuf][grp] packed V^T, 32 KB
  __shared__ float Ml[2][2][32];
  int tid = threadIdx.x, lane = tid & 63, wid = tid >> 6;  // wid 0..3
  int id = blockIdx.x;
  int bh = ((id & 7) << 2) | ((id >> 3) & 3);  // XCD-pinned: 4 bh per XCD
  int j = 31 - (id >> 5);                      // heavy tiles dispatched first
  int w2 = wid & 1, grp = wid >> 1;
  int b = bh >> 4, h = bh & 15;
  int li = lane & 31, hi = lane >> 5;
  int qb = 64 * j + w2 * 32;
  int qrow = qb + li;
  int n = j + 1;
  int kg_base = grp * 32 * n;
  const u16* qbase = q_r + (size_t)bh * S_ * D_;
  const u16* kbase = k_r + (size_t)bh * S_ * D_;
  const u16* vbase = v_t + (size_t)bh * D_ * S_;

  bf16x8 aq[8];
#pragma unroll
  for (int step = 0; step < 8; step++)
    aq[step] = *(const bf16x8*)&qbase[(size_t)qrow * D_ + step * 16 + hi * 8];

  f32x16 o[4];
#pragma unroll
  for (int dt = 0; dt < 4; dt++)
#pragma unroll
    for (int r = 0; r < 16; r++) o[dt][r] = 0.f;
  float mreg = -1e30f, lreg = 0.f;

  auto stage = [&](int nb, int p) {
    int kg0 = kg_base + p * 32;
    u16* Vst = &Vs[nb][grp][0];
#pragma unroll
    for (int i = 0; i < 4; i++) {
      int r = w2 * 32 + i * 8 + (lane >> 3);
      int ss = lane & 7;
      int s = ss ^ (r & 7);
      int d = ((s >> 2) << 6) + r;        // slot half selects d or d+64
      int kk = kg0 + (s & 3) * 8;
      __builtin_amdgcn_global_load_lds(
          (gvoid*)(vbase + (size_t)d * S_ + kk),
          (lvoid*)(&Vst[r * 64 + ss * 8]), 16, 0, 0);
    }
  };

  stage(0, 0);
  int cbuf = 0;

  for (int p = 0; p < n; ++p) {
    int kg0 = kg_base + p * 32;
    asm volatile("s_waitcnt vmcnt(0)" ::: "memory");  // my V loads landed (flew under compute)
    __builtin_amdgcn_s_barrier();                      // everyone's V landed
    asm volatile("" ::: "memory");                     // fence only; scheduling stays free
    if (p + 1 < n) stage(cbuf ^ 1, p + 1);             // overlaps this iter's compute
    if (kg0 <= qb + 31) {
      bool domask = (kg0 + 31 > qb);
      const char* Vc = (const char*)&Vs[cbuf][grp][0];
      // ---- QK^T (swapped), 32 keys; K straight from global (L1/L2-resident) ----
      bf16x8 kf[8];
#pragma unroll
      for (int step = 0; step < 8; step++)
        kf[step] = *(const bf16x8*)&kbase[(size_t)(kg0 + li) * D_ + step * 16 + hi * 8];
      f32x16 c0, c1;
#pragma unroll
      for (int r = 0; r < 16; r++) { c0[r] = 0.f; c1[r] = 0.f; }
      __builtin_amdgcn_s_setprio(1);
#pragma unroll
      for (int step = 0; step < 4; step++) {
        c0 = __builtin_amdgcn_mfma_f32_32x32x16_bf16(kf[step], aq[step], c0, 0, 0, 0);
        c1 = __builtin_amdgcn_mfma_f32_32x32x16_bf16(kf[step + 4], aq[step + 4], c1, 0, 0, 0);
      }
      __builtin_amdgcn_s_setprio(0);
      float ps[16];
#pragma unroll
      for (int r = 0; r < 16; r++) ps[r] = (c0[r] + c1[r]) * SCL2_;  // exp2 domain
      if (domask) {  // wave-uniform boundary branch
#pragma unroll
        for (int r = 0; r < 16; r++) {
          int k = kg0 + (r & 3) + 8 * (r >> 2) + 4 * hi;
          if (k > qrow) ps[r] = -1e30f;
        }
      }
      // ---- in-register softmax (one q row per lane) ----
      float t8[8];
#pragma unroll
      for (int r = 0; r < 8; r++) t8[r] = fmaxf(ps[r], ps[r + 8]);
#pragma unroll
      for (int r = 0; r < 4; r++) t8[r] = fmaxf(t8[r], t8[r + 4]);
      float mt = fmaxf(fmaxf(t8[0], t8[1]), fmaxf(t8[2], t8[3]));
      mt = fmaxf(mt, __shfl_xor(mt, 32));
      // T13 defer-max
      if (!__all(mt <= mreg + 8.f)) {
        float mn = fmaxf(mreg, mt);
        float al = __builtin_amdgcn_exp2f(mreg - mn);
        mreg = mn;
        lreg *= al;
#pragma unroll
        for (int dt = 0; dt < 4; dt++)
#pragma unroll
          for (int r = 0; r < 16; r++) o[dt][r] *= al;
      }
#pragma unroll
      for (int r = 0; r < 16; r++) ps[r] = __builtin_amdgcn_exp2f(ps[r] - mreg);
      float s8[8];
#pragma unroll
      for (int r = 0; r < 8; r++) s8[r] = ps[r] + ps[r + 8];
#pragma unroll
      for (int r = 0; r < 4; r++) s8[r] = s8[r] + s8[r + 4];
      float rs = (s8[0] + s8[1]) + (s8[2] + s8[3]);
      rs += __shfl_xor(rs, 32);
      lreg += rs;
      // ---- PV: B-fragment in-register via cvt_pk + permlane32_swap (T12) ----
#pragma unroll
      for (int ks = 0; ks < 2; ks++) {
        const int bix = ks * 8;
        unsigned P0, P1, P2, P3;
        asm("v_cvt_pk_bf16_f32 %0, %1, %2" : "=v"(P0) : "v"(ps[bix + 0]), "v"(ps[bix + 1]));
        asm("v_cvt_pk_bf16_f32 %0, %1, %2" : "=v"(P1) : "v"(ps[bix + 2]), "v"(ps[bix + 3]));
        asm("v_cvt_pk_bf16_f32 %0, %1, %2" : "=v"(P2) : "v"(ps[bix + 4]), "v"(ps[bix + 5]));
        asm("v_cvt_pk_bf16_f32 %0, %1, %2" : "=v"(P3) : "v"(ps[bix + 6]), "v"(ps[bix + 7]));
        asm("v_permlane32_swap_b32 %0, %1" : "+v"(P0), "+v"(P2));
        asm("v_permlane32_swap_b32 %0, %1" : "+v"(P1), "+v"(P3));
        bf16x8 bp = __builtin_bit_cast(bf16x8, (u32x4){P0, P1, P2, P3});
        bf16x8 vf[4];
#pragma unroll
        for (int dt = 0; dt < 4; dt++) {
          int row = ((dt & 1) << 5) + li;
          vf[dt] = *(const bf16x8*)(Vc + row * 128 +
                                    ((((dt >> 1) * 4 + ks * 2 + hi) * 16) ^ ((row & 7) << 4)));
        }
        __builtin_amdgcn_s_setprio(1);
#pragma unroll
        for (int dt = 0; dt < 4; dt++)
          o[dt] = __builtin_amdgcn_mfma_f32_32x32x16_bf16(vf[dt], bp, o[dt], 0, 0, 0);
        __builtin_amdgcn_s_setprio(0);
      }
    }
    cbuf ^= 1;
  }
  // ---- merge partials: grp0 writes, grp1 combines + stores (fb reuses Vs) ----
  __syncthreads();
  float* fb = (float*)&Vs[0][0][0] + w2 * 4096;  // 16 KB region per writer wave
  if (grp == 0) {
#pragma unroll
    for (int k = 0; k < 64; ++k) fb[k * 64 + lane] = o[k >> 4][k & 15];
    if (lane < 32) {
      Ml[w2][0][li] = mreg;
      Ml[w2][1][li] = lreg;
    }
  }
  __syncthreads();
  if (grp == 1) {
    float m1 = Ml[w2][0][li], l1 = Ml[w2][1][li];
    float m = fmaxf(mreg, m1);
    float s2 = __builtin_amdgcn_exp2f(mreg - m);
    float s1 = __builtin_amdgcn_exp2f(m1 - m);
    float lsum = lreg * s2 + l1 * s1;
    float rl = 1.0f / lsum;
    u16* yrow = y + ((size_t)(b * S_ + qrow)) * E_ + h * D_;
#pragma unroll
    for (int dt = 0; dt < 4; dt++) {
#pragma unroll
      for (int g2 = 0; g2 < 4; g2++) {
        int d = dt * 32 + 8 * g2 + 4 * hi;
        ushort4 sv;
        float v0 = (o[dt][4 * g2 + 0] * s2 + fb[(dt * 16 + 4 * g2 + 0) * 64 + lane] * s1) * rl;
        float v1 = (o[dt][4 * g2 + 1] * s2 + fb[(dt * 16 + 4 * g2 + 1) * 64 + lane] * s1) * rl;
        float v2 = (o[dt][4 * g2 + 2] * s2 + fb[(dt * 16 + 4 * g2 + 2) * 64 + lane] * s1) * rl;
        float v3 = (o[dt][4 * g2 + 3] * s2 + fb[(dt * 16 + 4 * g2 + 3) * 64 + lane] * s1) * rl;
        sv.x = f2bf(v0);
        sv.y = f2bf(v1);
        sv.z = f2bf(v2);
        sv.w = f2bf(v3);
        *(ushort4*)(yrow + d) = sv;
      }
    }
  }
}

// ---------------- host ----------------
extern "C" void kernel_launch(void* const* d_in, const int* in_sizes, int n_in,
                              void* d_out, int out_size, void* d_ws, size_t ws_size,
                              hipStream_t stream) {
  const float* x = (const float*)d_in[0];
  const float* g_q = (const float*)d_in[1];
  const float* g_kv = (const float*)d_in[2];
  const float* w_qa = (const float*)d_in[3];
  const float* w_qb = (const float*)d_in[4];
  const float* w_kva = (const float*)d_in[5];
  const float* w_kvb = (const float*)d_in[6];
  const float* w_o = (const float*)d_in[7];
  float* out = (float*)d_out;
  char* ws = (char*)d_ws;

  size_t off = 0;
  float* cos_t = (float*)(ws + off); off += (size_t)S_ * 32 * 4;
  float* sin_t = (float*)(ws + off); off += (size_t)S_ * 32 * 4;
  u16* wqa_t = (u16*)(ws + off); off += (size_t)QR_ * E_ * 2;
  u16* wqb_t = (u16*)(ws + off); off += (size_t)E_ * QR_ * 2;
  u16* wkvb_t = (u16*)(ws + off); off += (size_t)E_ * KR_ * 2;
  u16* wo_t = (u16*)(ws + off); off += (size_t)E_ * E_ * 2;
  u16* wsel_t = (u16*)(ws + off); off += (size_t)NSEL_ * E_ * 2;
  u16* qlow = (u16*)(ws + off); off += (size_t)T_ * QR_ * 2;
  u16* kc = (u16*)(ws + off); off += (size_t)T_ * KR_ * 2;
  u16* ln_q = (u16*)(ws + off); off += (size_t)T_ * E_ * 2;   // reused as y
  u16* ln_kv = (u16*)(ws + off); off += (size_t)T_ * E_ * 2;  // reused as q_r
  u16* k_rb = (u16*)(ws + off); off += (size_t)T_ * E_ * 2;   // first v_nat, then k_r
  u16* v_tb = (u16*)(ws + off); off += (size_t)T_ * E_ * 2;
  u16* y = ln_q;
  u16* q_rb = ln_kv;
  u16* v_nat = k_rb;  // alias: consumed by k_vtr before k-GEMM writes k_r

  k_rope_tables<<<dim3(S_ * 32 / 256), dim3(256), 0, stream>>>(cos_t, sin_t);
  k_ln<<<dim3(T_), dim3(256), 0, stream>>>(x, g_q, g_kv, ln_q, ln_kv);

  k_transp<false><<<dim3(QR_ / 32, E_ / 32), dim3(256), 0, stream>>>(w_qa, wqa_t, E_, QR_);
  k_transp<false><<<dim3(E_ / 32, QR_ / 32), dim3(256), 0, stream>>>(w_qb, wqb_t, QR_, E_);
  k_transp<false><<<dim3(E_ / 32, KR_ / 32), dim3(256), 0, stream>>>(w_kvb, wkvb_t, KR_, E_);
  k_transp<false><<<dim3(E_ / 32, E_ / 32), dim3(256), 0, stream>>>(w_o, wo_t, E_, E_);
  k_transp<true><<<dim3(NSEL_ / 32, E_ / 32), dim3(256), 0, stream>>>(w_kva, wsel_t, E_, 128 + H_ * 2 * D_);

  EpiP ep{};

  // q_low = ln_q @ w_qa  (M=4096, N=64, K=2048) -- BM=64: 64 blocks
  ep = EpiP{}; ep.obf = qlow;
  k_gemm<64, 64, 0><<<dim3(1, T_ / 64), dim3(256), 0, stream>>>(ln_q, wqa_t, T_, QR_, E_, ep);

  // kv = ln_kv @ w_kva_sel  (M=4096, N=2176, K=2048) -> kc + v natural (coalesced)
  ep = EpiP{}; ep.kc = kc; ep.vt = v_nat;
  k_gemm<128, 128, 2><<<dim3(NSEL_ / 128, T_ / 128), dim3(256), 0, stream>>>(ln_kv, wsel_t, T_, NSEL_, E_, ep);

  // q = q_low @ w_qb + RoPE  (M=4096, N=2048, K=64) -> q_r
  ep = EpiP{}; ep.qk = q_rb; ep.cost = cos_t; ep.sint = sin_t;
  k_gemm<128, 128, 3><<<dim3(E_ / 128, T_ / 128), dim3(256), 0, stream>>>(qlow, wqb_t, T_, E_, QR_, ep);

  // v^T: per-batch 2048x2048 bf16 transpose (v_nat -> v_tb)
  k_vtr<<<dim3(64, 128), dim3(256), 0, stream>>>(v_nat, v_tb);

  // k = kc @ w_kvb + RoPE  (M=4096, N=2048, K=128) -> k_r
  ep = EpiP{}; ep.qk = k_rb; ep.cost = cos_t; ep.sint = sin_t;
  k_gemm<128, 128, 3><<<dim3(E_ / 128, T_ / 128), dim3(256), 0, stream>>>(kc, wkvb_t, T_, E_, KR_, ep);

  // attention -> y (overwrites ln_q). 1024 blocks x 4 waves; K in regs, 3 blocks/CU.
  k_attn<<<dim3(1024), dim3(256), 0, stream>>>(q_rb, k_rb, v_tb, y);

  // out = y @ w_o  (M=4096, N=2048, K=2048), fp32
  ep = EpiP{}; ep.of32 = out;
  k_gemm<128, 128, 1><<<dim3(E_ / 128, T_ / 128), dim3(256), 0, stream>>>(y, wo_t, T_, E_, E_, ep);
}

// Round 22
// 264.364 us; speedup vs baseline: 1.3223x; 1.3223x over previous
//
#include <hip/hip_runtime.h>
#include <cstdint>
#include <cstddef>

typedef unsigned short u16;
typedef __attribute__((ext_vector_type(8))) __bf16 bf16x8;
typedef __attribute__((ext_vector_type(4))) float f32x4;
typedef __attribute__((ext_vector_type(16))) float f32x16;
typedef __attribute__((ext_vector_type(4))) unsigned u32x4;

#define E_ 2048
#define H_ 16
#define D_ 128
#define QR_ 64
#define KR_ 128
#define S_ 2048
#define B_ 2
#define T_ 4096
#define NSEL_ 2176
#define EPS_ 1e-5f
#define SCALE_ 0.08838834764831845f
#define SCL2_ 0.12751743f  // SCALE_ * log2(e); softmax in exp2 domain

typedef __attribute__((address_space(1))) const void gvoid;
typedef __attribute__((address_space(3))) void lvoid;

__device__ __forceinline__ u16 f2bf(float f) {
  unsigned u = __float_as_uint(f);
  unsigned r = (u + 0x7FFFu + ((u >> 16) & 1u)) >> 16;
  return (u16)r;
}

// ---------------- RoPE tables ----------------
__global__ void k_rope_tables(float* __restrict__ cos_t, float* __restrict__ sin_t) {
  int idx = blockIdx.x * 256 + threadIdx.x;
  if (idx >= S_ * 32) return;
  int t = idx >> 5, j = idx & 31;
  float inv = powf(10000.0f, -(float)j / 32.0f);
  float a = (float)t * inv;
  cos_t[idx] = cosf(a);
  sin_t[idx] = sinf(a);
}

// ---------------- dual LayerNorm ----------------
__global__ __launch_bounds__(256) void k_ln(
    const float* __restrict__ x, const float* __restrict__ gq,
    const float* __restrict__ gkv, u16* __restrict__ lnq, u16* __restrict__ lnkv) {
  int row = blockIdx.x;
  const float* xr = x + (size_t)row * E_;
  int base = threadIdx.x * 8;
  float4 v0 = *(const float4*)(xr + base);
  float4 v1 = *(const float4*)(xr + base + 4);
  float xv[8] = {v0.x, v0.y, v0.z, v0.w, v1.x, v1.y, v1.z, v1.w};
  float s0 = 0.f, s1 = 0.f;
#pragma unroll
  for (int i = 0; i < 8; i++) { s0 += xv[i]; s1 += xv[i] * xv[i]; }
  for (int off = 32; off > 0; off >>= 1) {
    s0 += __shfl_down(s0, off);
    s1 += __shfl_down(s1, off);
  }
  __shared__ float red[2][4];
  int wid = threadIdx.x >> 6, lane = threadIdx.x & 63;
  if (lane == 0) { red[0][wid] = s0; red[1][wid] = s1; }
  __syncthreads();
  s0 = red[0][0] + red[0][1] + red[0][2] + red[0][3];
  s1 = red[1][0] + red[1][1] + red[1][2] + red[1][3];
  float mu = s0 * (1.0f / E_);
  float var = s1 * (1.0f / E_) - mu * mu;
  float rs = rsqrtf(var + EPS_);
  u16 oq[8], okv[8];
#pragma unroll
  for (int i = 0; i < 8; i++) {
    float nv = (xv[i] - mu) * rs;
    oq[i] = f2bf(nv * gq[base + i]);
    okv[i] = f2bf(nv * gkv[base + i]);
  }
  *(ushort4*)(lnq + (size_t)row * E_ + base) = make_ushort4(oq[0], oq[1], oq[2], oq[3]);
  *(ushort4*)(lnq + (size_t)row * E_ + base + 4) = make_ushort4(oq[4], oq[5], oq[6], oq[7]);
  *(ushort4*)(lnkv + (size_t)row * E_ + base) = make_ushort4(okv[0], okv[1], okv[2], okv[3]);
  *(ushort4*)(lnkv + (size_t)row * E_ + base + 4) = make_ushort4(okv[4], okv[5], okv[6], okv[7]);
}

// ---------------- transpose f32 -> bf16 (out[N'][K]) ----------------
template <bool SEL>
__global__ __launch_bounds__(256) void k_transp(
    const float* __restrict__ in, u16* __restrict__ out, int K, int Nin) {
  __shared__ float t[32][33];
  int orb = blockIdx.x * 32;
  int icb;
  if (SEL) {
    icb = (orb < 128) ? orb : 128 + ((orb - 128) >> 7) * 256 + ((orb - 128) & 127);
  } else {
    icb = orb;
  }
  int kb = blockIdx.y * 32;
  int tx = threadIdx.x & 31, ty = threadIdx.x >> 5;
#pragma unroll
  for (int i = 0; i < 4; i++)
    t[ty + i * 8][tx] = in[(size_t)(kb + ty + i * 8) * Nin + icb + tx];
  __syncthreads();
#pragma unroll
  for (int i = 0; i < 4; i++)
    out[(size_t)(orb + ty + i * 8) * K + kb + tx] = f2bf(t[tx][ty + i * 8]);
}

// ---------------- bf16 per-batch 2048x2048 transpose: v_nat -> v_t ----------------
__global__ __launch_bounds__(256) void k_vtr(
    const u16* __restrict__ vn, u16* __restrict__ vt) {
  __shared__ u16 t[32][33];
  int c0 = blockIdx.x * 32;
  int b = blockIdx.y >> 6;
  int s0 = (blockIdx.y & 63) * 32;
  int tx = threadIdx.x & 31, ty = threadIdx.x >> 5;
#pragma unroll
  for (int i = 0; i < 4; i++)
    t[ty + i * 8][tx] = vn[((size_t)(b * 2048 + s0 + ty + i * 8)) * 2048 + c0 + tx];
  __syncthreads();
#pragma unroll
  for (int i = 0; i < 4; i++)
    vt[((size_t)(b * 2048 + c0 + ty + i * 8)) * 2048 + s0 + tx] = t[tx][ty + i * 8];
}

// ---------------- GEMM: C = A[M][K] x Bt[N][K]^T  (T3-min single-barrier, XCD swz) --
struct EpiP {
  float* of32;
  u16* obf;
  u16* kc;
  u16* vt;
  u16* qk;
  const float* cost;
  const float* sint;
};

template <int BM, int BN, int EPI>
__global__ __launch_bounds__(256, 3) void k_gemm(
    const u16* __restrict__ A, const u16* __restrict__ Bt,
    int M, int N, int K, EpiP ep) {
  constexpr int WM = BM / 2;
  constexpr int MI = WM / 16;
  constexpr int WN = BN / 2;
  constexpr int NI = WN / 16;
  __shared__ alignas(16) u16 lsA[2][BM * 32];
  __shared__ alignas(16) u16 lsB[2][BN * 32];
  int tid = threadIdx.x, lane = tid & 63, wid = tid >> 6;
  int wr = wid >> 1, wc = wid & 1;
  // T1: bijective XCD swizzle (all launches have nwg % 8 == 0)
  int gx = gridDim.x;
  int nwg = gx * gridDim.y;
  int flat = blockIdx.y * gx + blockIdx.x;
  int cpx = nwg >> 3;
  int swz = (flat & 7) * cpx + (flat >> 3);
  int bm = swz / gx, bn = swz % gx;
  f32x4 zero4 = {0.f, 0.f, 0.f, 0.f};
  f32x4 acc[MI][NI];
#pragma unroll
  for (int m = 0; m < MI; m++)
#pragma unroll
    for (int n = 0; n < NI; n++) acc[m][n] = zero4;
  const int nkt = K >> 5;
  const u16* Ab = A + (size_t)bm * BM * K;
  const u16* Bb = Bt + (size_t)bn * BN * K;
  int arow = tid >> 2, acol8 = (tid & 3) * 8;
  int lg = lane >> 4, li = lane & 15;

  auto stage = [&](int buf, int kt) {
    int k0 = kt * 32;
#pragma unroll
    for (int c = 0; c < BM / 64; c++) {
      int row = c * 64 + arow;
      __builtin_amdgcn_global_load_lds(
          (gvoid*)(Ab + (size_t)row * K + k0 + acol8),
          (lvoid*)(&lsA[buf][row * 32 + acol8]), 16, 0, 0);
    }
#pragma unroll
    for (int c = 0; c < BN / 64; c++) {
      int row = c * 64 + arow;
      __builtin_amdgcn_global_load_lds(
          (gvoid*)(Bb + (size_t)row * K + k0 + acol8),
          (lvoid*)(&lsB[buf][row * 32 + acol8]), 16, 0, 0);
    }
  };

  // T3-min prologue: tile0 staged + landed before loop
  stage(0, 0);
  asm volatile("s_waitcnt vmcnt(0)" ::: "memory");
  __builtin_amdgcn_s_barrier();
  asm volatile("" ::: "memory");
  for (int kt = 0; kt < nkt; ++kt) {
    int cur = kt & 1;
    if (kt + 1 < nkt) stage(cur ^ 1, kt + 1);  // issue next-tile loads FIRST
    bf16x8 af[MI], bfr[NI];
#pragma unroll
    for (int m = 0; m < MI; m++)
      af[m] = *reinterpret_cast<const bf16x8*>(&lsA[cur][(wr * WM + m * 16 + li) * 32 + lg * 8]);
#pragma unroll
    for (int n = 0; n < NI; n++)
      bfr[n] = *reinterpret_cast<const bf16x8*>(&lsB[cur][(wc * WN + n * 16 + li) * 32 + lg * 8]);
#pragma unroll
    for (int m = 0; m < MI; m++)
#pragma unroll
      for (int n = 0; n < NI; n++)
        acc[m][n] = __builtin_amdgcn_mfma_f32_16x16x32_bf16(af[m], bfr[n], acc[m][n], 0, 0, 0);
    // ONE vmcnt(0)+barrier per K-step: next tile landed (flew under compute),
    // and read-before-overwrite is ordered by the same barrier.
    asm volatile("s_waitcnt vmcnt(0)" ::: "memory");
    __builtin_amdgcn_s_barrier();
    asm volatile("" ::: "memory");
  }
  // epilogue
#pragma unroll
  for (int m = 0; m < MI; m++) {
#pragma unroll
    for (int n = 0; n < NI; n++) {
      int col = bn * BN + wc * WN + n * 16 + li;
#pragma unroll
      for (int r = 0; r < 4; r++) {
        int row = bm * BM + wr * WM + m * 16 + lg * 4 + r;
        float val = acc[m][n][r];
        if constexpr (EPI == 0) {
          ep.obf[(size_t)row * 64 + col] = f2bf(val);
        } else if constexpr (EPI == 1) {
          ep.of32[(size_t)row * E_ + col] = val;
        } else if constexpr (EPI == 2) {
          if (col < KR_) {
            ep.kc[(size_t)row * KR_ + col] = f2bf(val);
          } else {
            ep.vt[(size_t)row * 2048 + (col - KR_)] = f2bf(val);  // coalesced natural v
          }
        } else {  // EPI 3: RoPE + per-head store
          int h = col >> 7, dl = col & 127;
          int b = row >> 11, sp = row & 2047;
          float outv;
          if (dl < 64) {
            float pv = acc[m][n ^ 2][r];
            int j = dl & 31;
            float c = ep.cost[sp * 32 + j];
            float s = ep.sint[sp * 32 + j];
            float rot = (dl < 32) ? -pv : pv;
            outv = val * c + rot * s;
          } else {
            outv = val;
          }
          ep.qk[((size_t)(b * H_ + h) * S_ + sp) * D_ + dl] = f2bf(outv);
        }
      }
    }
  }
}

// ---------------- causal flash attention (split-K blocks + LPT refill) ----------------
// Block = (bh, 64-row q-tile j), 4 waves: waves {0,1} = subtiles 0,1 sweeping keys
// [0, 32(j+1)); waves {2,3} = same subtiles sweeping [32(j+1), 64(j+1)). Every wave
// computes every iteration (n = j+1 for all waves). Partials merged through LDS at the
// end (flash combine). 1024 blocks, heavy-j first with 2 resident/CU -> LPT refill.
__global__ __launch_bounds__(256, 2) void k_attn(
    const u16* __restrict__ q_r, const u16* __restrict__ k_r,
    const u16* __restrict__ v_t, u16* __restrict__ y) {
  __shared__ alignas(16) u16 Ks[2][2][32 * 128];  // [dbuf][grp] K tile 32x128
  __shared__ alignas(16) u16 Vs[2][2][64 * 64];   // [dbuf][grp] packed V^T
  __shared__ float Ml[2][2][32];
  int tid = threadIdx.x, lane = tid & 63, wid = tid >> 6;  // wid 0..3
  int id = blockIdx.x;
  int bh = ((id & 7) << 2) | ((id >> 3) & 3);  // XCD-pinned: 4 bh per XCD
  int j = 31 - (id >> 5);                      // heavy tiles dispatched first
  int w2 = wid & 1, grp = wid >> 1;
  int b = bh >> 4, h = bh & 15;
  int li = lane & 31, hi = lane >> 5;
  int qb = 64 * j + w2 * 32;
  int qrow = qb + li;
  int n = j + 1;
  int kg_base = grp * 32 * n;
  const u16* qbase = q_r + (size_t)bh * S_ * D_;
  const u16* kbase = k_r + (size_t)bh * S_ * D_;
  const u16* vbase = v_t + (size_t)bh * D_ * S_;

  bf16x8 aq[8];
#pragma unroll
  for (int step = 0; step < 8; step++)
    aq[step] = *(const bf16x8*)&qbase[(size_t)qrow * D_ + step * 16 + hi * 8];

  f32x16 o[4];
#pragma unroll
  for (int dt = 0; dt < 4; dt++)
#pragma unroll
    for (int r = 0; r < 16; r++) o[dt][r] = 0.f;
  float mreg = -1e30f, lreg = 0.f;

  int kr_l = w2 * 16 + (lane >> 4);  // + i*4
  int kc_l = (lane & 15) * 8;
  int kswz = (li & 7) << 4;

  auto stage = [&](int nb, int p) {
    int kg0 = kg_base + p * 32;
    u16* Kst = &Ks[nb][grp][0];
    u16* Vst = &Vs[nb][grp][0];
#pragma unroll
    for (int i = 0; i < 4; i++) {
      int r = kr_l + i * 4;
      __builtin_amdgcn_global_load_lds(
          (gvoid*)(kbase + (size_t)(kg0 + r) * D_ + (kc_l ^ ((r & 7) << 3))),
          (lvoid*)(&Kst[r * 128 + kc_l]), 16, 0, 0);
    }
#pragma unroll
    for (int i = 0; i < 4; i++) {
      int r = w2 * 32 + i * 8 + (lane >> 3);
      int ss = lane & 7;
      int s = ss ^ (r & 7);
      int d = ((s >> 2) << 6) + r;        // slot half selects d or d+64
      int kk = kg0 + (s & 3) * 8;
      __builtin_amdgcn_global_load_lds(
          (gvoid*)(vbase + (size_t)d * S_ + kk),
          (lvoid*)(&Vst[r * 64 + ss * 8]), 16, 0, 0);
    }
  };

  stage(0, 0);
  int cbuf = 0;

  for (int p = 0; p < n; ++p) {
    int kg0 = kg_base + p * 32;
    asm volatile("s_waitcnt vmcnt(0)" ::: "memory");  // my loads landed (flew under compute)
    __builtin_amdgcn_s_barrier();                      // everyone's loads landed
    asm volatile("" ::: "memory");                     // fence only; scheduling stays free
    if (p + 1 < n) stage(cbuf ^ 1, p + 1);             // overlaps this iter's compute
    if (kg0 <= qb + 31) {
      bool domask = (kg0 + 31 > qb);
      const char* Kc = (const char*)&Ks[cbuf][grp][0];
      const char* Vc = (const char*)&Vs[cbuf][grp][0];
      // ---- QK^T (swapped), 32 keys; accumulator chain split in two (latency) ----
      bf16x8 kf[8];
#pragma unroll
      for (int step = 0; step < 8; step++)
        kf[step] = *(const bf16x8*)(Kc + li * 256 + ((step * 32 + hi * 16) ^ kswz));
      f32x16 c0, c1;
#pragma unroll
      for (int r = 0; r < 16; r++) { c0[r] = 0.f; c1[r] = 0.f; }
      __builtin_amdgcn_s_setprio(1);
#pragma unroll
      for (int step = 0; step < 4; step++) {
        c0 = __builtin_amdgcn_mfma_f32_32x32x16_bf16(kf[step], aq[step], c0, 0, 0, 0);
        c1 = __builtin_amdgcn_mfma_f32_32x32x16_bf16(kf[step + 4], aq[step + 4], c1, 0, 0, 0);
      }
      __builtin_amdgcn_s_setprio(0);
      float ps[16];
#pragma unroll
      for (int r = 0; r < 16; r++) ps[r] = (c0[r] + c1[r]) * SCL2_;  // exp2 domain
      if (domask) {  // wave-uniform boundary branch
#pragma unroll
        for (int r = 0; r < 16; r++) {
          int k = kg0 + (r & 3) + 8 * (r >> 2) + 4 * hi;
          if (k > qrow) ps[r] = -1e30f;
        }
      }
      // ---- in-register softmax (one q row per lane) ----
      float t8[8];
#pragma unroll
      for (int r = 0; r < 8; r++) t8[r] = fmaxf(ps[r], ps[r + 8]);
#pragma unroll
      for (int r = 0; r < 4; r++) t8[r] = fmaxf(t8[r], t8[r + 4]);
      float mt = fmaxf(fmaxf(t8[0], t8[1]), fmaxf(t8[2], t8[3]));
      mt = fmaxf(mt, __shfl_xor(mt, 32));
      // T13 defer-max
      if (!__all(mt <= mreg + 8.f)) {
        float mn = fmaxf(mreg, mt);
        float al = __builtin_amdgcn_exp2f(mreg - mn);
        mreg = mn;
        lreg *= al;
#pragma unroll
        for (int dt = 0; dt < 4; dt++)
#pragma unroll
          for (int r = 0; r < 16; r++) o[dt][r] *= al;
      }
#pragma unroll
      for (int r = 0; r < 16; r++) ps[r] = __builtin_amdgcn_exp2f(ps[r] - mreg);
      float s8[8];
#pragma unroll
      for (int r = 0; r < 8; r++) s8[r] = ps[r] + ps[r + 8];
#pragma unroll
      for (int r = 0; r < 4; r++) s8[r] = s8[r] + s8[r + 4];
      float rs = (s8[0] + s8[1]) + (s8[2] + s8[3]);
      rs += __shfl_xor(rs, 32);
      lreg += rs;
      // ---- PV: B-fragment in-register via cvt_pk + permlane32_swap (T12) ----
#pragma unroll
      for (int ks = 0; ks < 2; ks++) {
        const int bix = ks * 8;
        unsigned P0, P1, P2, P3;
        asm("v_cvt_pk_bf16_f32 %0, %1, %2" : "=v"(P0) : "v"(ps[bix + 0]), "v"(ps[bix + 1]));
        asm("v_cvt_pk_bf16_f32 %0, %1, %2" : "=v"(P1) : "v"(ps[bix + 2]), "v"(ps[bix + 3]));
        asm("v_cvt_pk_bf16_f32 %0, %1, %2" : "=v"(P2) : "v"(ps[bix + 4]), "v"(ps[bix + 5]));
        asm("v_cvt_pk_bf16_f32 %0, %1, %2" : "=v"(P3) : "v"(ps[bix + 6]), "v"(ps[bix + 7]));
        asm("v_permlane32_swap_b32 %0, %1" : "+v"(P0), "+v"(P2));
        asm("v_permlane32_swap_b32 %0, %1" : "+v"(P1), "+v"(P3));
        bf16x8 bp = __builtin_bit_cast(bf16x8, (u32x4){P0, P1, P2, P3});
        bf16x8 vf[4];
#pragma unroll
        for (int dt = 0; dt < 4; dt++) {
          int row = ((dt & 1) << 5) + li;
          vf[dt] = *(const bf16x8*)(Vc + row * 128 +
                                    ((((dt >> 1) * 4 + ks * 2 + hi) * 16) ^ ((row & 7) << 4)));
        }
        __builtin_amdgcn_s_setprio(1);
#pragma unroll
        for (int dt = 0; dt < 4; dt++)
          o[dt] = __builtin_amdgcn_mfma_f32_32x32x16_bf16(vf[dt], bp, o[dt], 0, 0, 0);
        __builtin_amdgcn_s_setprio(0);
      }
    }
    cbuf ^= 1;
  }
  // ---- merge partials: grp0 writes, grp1 combines + stores ----
  __syncthreads();
  float* fb = (float*)&Ks[0][0][0] + w2 * 4096;  // 16 KB region per writer wave
  if (grp == 0) {
#pragma unroll
    for (int k = 0; k < 64; ++k) fb[k * 64 + lane] = o[k >> 4][k & 15];
    if (lane < 32) {
      Ml[w2][0][li] = mreg;
      Ml[w2][1][li] = lreg;
    }
  }
  __syncthreads();
  if (grp == 1) {
    float m1 = Ml[w2][0][li], l1 = Ml[w2][1][li];
    float m = fmaxf(mreg, m1);
    float s2 = __builtin_amdgcn_exp2f(mreg - m);
    float s1 = __builtin_amdgcn_exp2f(m1 - m);
    float lsum = lreg * s2 + l1 * s1;
    float rl = 1.0f / lsum;
    u16* yrow = y + ((size_t)(b * S_ + qrow)) * E_ + h * D_;
#pragma unroll
    for (int dt = 0; dt < 4; dt++) {
#pragma unroll
      for (int g2 = 0; g2 < 4; g2++) {
        int d = dt * 32 + 8 * g2 + 4 * hi;
        ushort4 sv;
        float v0 = (o[dt][4 * g2 + 0] * s2 + fb[(dt * 16 + 4 * g2 + 0) * 64 + lane] * s1) * rl;
        float v1 = (o[dt][4 * g2 + 1] * s2 + fb[(dt * 16 + 4 * g2 + 1) * 64 + lane] * s1) * rl;
        float v2 = (o[dt][4 * g2 + 2] * s2 + fb[(dt * 16 + 4 * g2 + 2) * 64 + lane] * s1) * rl;
        float v3 = (o[dt][4 * g2 + 3] * s2 + fb[(dt * 16 + 4 * g2 + 3) * 64 + lane] * s1) * rl;
        sv.x = f2bf(v0);
        sv.y = f2bf(v1);
        sv.z = f2bf(v2);
        sv.w = f2bf(v3);
        *(ushort4*)(yrow + d) = sv;
      }
    }
  }
}

// ---------------- host ----------------
extern "C" void kernel_launch(void* const* d_in, const int* in_sizes, int n_in,
                              void* d_out, int out_size, void* d_ws, size_t ws_size,
                              hipStream_t stream) {
  const float* x = (const float*)d_in[0];
  const float* g_q = (const float*)d_in[1];
  const float* g_kv = (const float*)d_in[2];
  const float* w_qa = (const float*)d_in[3];
  const float* w_qb = (const float*)d_in[4];
  const float* w_kva = (const float*)d_in[5];
  const float* w_kvb = (const float*)d_in[6];
  const float* w_o = (const float*)d_in[7];
  float* out = (float*)d_out;
  char* ws = (char*)d_ws;

  size_t off = 0;
  float* cos_t = (float*)(ws + off); off += (size_t)S_ * 32 * 4;
  float* sin_t = (float*)(ws + off); off += (size_t)S_ * 32 * 4;
  u16* wqa_t = (u16*)(ws + off); off += (size_t)QR_ * E_ * 2;
  u16* wqb_t = (u16*)(ws + off); off += (size_t)E_ * QR_ * 2;
  u16* wkvb_t = (u16*)(ws + off); off += (size_t)E_ * KR_ * 2;
  u16* wo_t = (u16*)(ws + off); off += (size_t)E_ * E_ * 2;
  u16* wsel_t = (u16*)(ws + off); off += (size_t)NSEL_ * E_ * 2;
  u16* qlow = (u16*)(ws + off); off += (size_t)T_ * QR_ * 2;
  u16* kc = (u16*)(ws + off); off += (size_t)T_ * KR_ * 2;
  u16* ln_q = (u16*)(ws + off); off += (size_t)T_ * E_ * 2;   // reused as y
  u16* ln_kv = (u16*)(ws + off); off += (size_t)T_ * E_ * 2;  // reused as q_r
  u16* k_rb = (u16*)(ws + off); off += (size_t)T_ * E_ * 2;   // first v_nat, then k_r
  u16* v_tb = (u16*)(ws + off); off += (size_t)T_ * E_ * 2;
  u16* y = ln_q;
  u16* q_rb = ln_kv;
  u16* v_nat = k_rb;  // alias: consumed by k_vtr before k-GEMM writes k_r

  k_rope_tables<<<dim3(S_ * 32 / 256), dim3(256), 0, stream>>>(cos_t, sin_t);
  k_ln<<<dim3(T_), dim3(256), 0, stream>>>(x, g_q, g_kv, ln_q, ln_kv);

  k_transp<false><<<dim3(QR_ / 32, E_ / 32), dim3(256), 0, stream>>>(w_qa, wqa_t, E_, QR_);
  k_transp<false><<<dim3(E_ / 32, QR_ / 32), dim3(256), 0, stream>>>(w_qb, wqb_t, QR_, E_);
  k_transp<false><<<dim3(E_ / 32, KR_ / 32), dim3(256), 0, stream>>>(w_kvb, wkvb_t, KR_, E_);
  k_transp<false><<<dim3(E_ / 32, E_ / 32), dim3(256), 0, stream>>>(w_o, wo_t, E_, E_);
  k_transp<true><<<dim3(NSEL_ / 32, E_ / 32), dim3(256), 0, stream>>>(w_kva, wsel_t, E_, 128 + H_ * 2 * D_);

  EpiP ep{};

  // q_low = ln_q @ w_qa  (M=4096, N=64, K=2048) -- BM=64: 64 blocks
  ep = EpiP{}; ep.obf = qlow;
  k_gemm<64, 64, 0><<<dim3(1, T_ / 64), dim3(256), 0, stream>>>(ln_q, wqa_t, T_, QR_, E_, ep);

  // kv = ln_kv @ w_kva_sel  (M=4096, N=2176, K=2048) -> kc + v natural (coalesced)
  ep = EpiP{}; ep.kc = kc; ep.vt = v_nat;
  k_gemm<128, 128, 2><<<dim3(NSEL_ / 128, T_ / 128), dim3(256), 0, stream>>>(ln_kv, wsel_t, T_, NSEL_, E_, ep);

  // q = q_low @ w_qb + RoPE  (M=4096, N=2048, K=64) -> q_r
  ep = EpiP{}; ep.qk = q_rb; ep.cost = cos_t; ep.sint = sin_t;
  k_gemm<128, 128, 3><<<dim3(E_ / 128, T_ / 128), dim3(256), 0, stream>>>(qlow, wqb_t, T_, E_, QR_, ep);

  // v^T: per-batch 2048x2048 bf16 transpose (v_nat -> v_tb)
  k_vtr<<<dim3(64, 128), dim3(256), 0, stream>>>(v_nat, v_tb);

  // k = kc @ w_kvb + RoPE  (M=4096, N=2048, K=128) -> k_r
  ep = EpiP{}; ep.qk = k_rb; ep.cost = cos_t; ep.sint = sin_t;
  k_gemm<128, 128, 3><<<dim3(E_ / 128, T_ / 128), dim3(256), 0, stream>>>(kc, wkvb_t, T_, E_, KR_, ep);

  // attention -> y (overwrites ln_q). 1024 blocks x 4 waves, split-K + LPT refill.
  k_attn<<<dim3(1024), dim3(256), 0, stream>>>(q_rb, k_rb, v_tb, y);

  // out = y @ w_o  (M=4096, N=2048, K=2048), fp32
  ep = EpiP{}; ep.of32 = out;
  k_gemm<128, 128, 1><<<dim3(E_ / 128, T_ / 128), dim3(256), 0, stream>>>(y, wo_t, T_, E_, E_, ep);
}

// Round 23
// 259.951 us; speedup vs baseline: 1.3447x; 1.0170x over previous
//
#include <hip/hip_runtime.h>
#include <cstdint>
#include <cstddef>

typedef unsigned short u16;
typedef __attribute__((ext_vector_type(8))) __bf16 bf16x8;
typedef __attribute__((ext_vector_type(4))) float f32x4;
typedef __attribute__((ext_vector_type(16))) float f32x16;
typedef __attribute__((ext_vector_type(4))) unsigned u32x4;

#define E_ 2048
#define H_ 16
#define D_ 128
#define QR_ 64
#define KR_ 128
#define S_ 2048
#define B_ 2
#define T_ 4096
#define NSEL_ 2176
#define EPS_ 1e-5f
#define SCALE_ 0.08838834764831845f
#define SCL2_ 0.12751743f  // SCALE_ * log2(e); softmax in exp2 domain

typedef __attribute__((address_space(1))) const void gvoid;
typedef __attribute__((address_space(3))) void lvoid;

__device__ __forceinline__ u16 f2bf(float f) {
  unsigned u = __float_as_uint(f);
  unsigned r = (u + 0x7FFFu + ((u >> 16) & 1u)) >> 16;
  return (u16)r;
}

// ---------------- dual LayerNorm (+ fused RoPE table build in blocks 0..255) --------
__global__ __launch_bounds__(256) void k_ln(
    const float* __restrict__ x, const float* __restrict__ gq,
    const float* __restrict__ gkv, u16* __restrict__ lnq, u16* __restrict__ lnkv,
    float* __restrict__ cos_t, float* __restrict__ sin_t) {
  if (blockIdx.x < (S_ * 32) / 256) {  // fused k_rope_tables (same index math)
    int idx = blockIdx.x * 256 + threadIdx.x;
    int t = idx >> 5, j = idx & 31;
    float inv = powf(10000.0f, -(float)j / 32.0f);
    float a = (float)t * inv;
    cos_t[idx] = cosf(a);
    sin_t[idx] = sinf(a);
  }
  int row = blockIdx.x;
  const float* xr = x + (size_t)row * E_;
  int base = threadIdx.x * 8;
  float4 v0 = *(const float4*)(xr + base);
  float4 v1 = *(const float4*)(xr + base + 4);
  float xv[8] = {v0.x, v0.y, v0.z, v0.w, v1.x, v1.y, v1.z, v1.w};
  float s0 = 0.f, s1 = 0.f;
#pragma unroll
  for (int i = 0; i < 8; i++) { s0 += xv[i]; s1 += xv[i] * xv[i]; }
  for (int off = 32; off > 0; off >>= 1) {
    s0 += __shfl_down(s0, off);
    s1 += __shfl_down(s1, off);
  }
  __shared__ float red[2][4];
  int wid = threadIdx.x >> 6, lane = threadIdx.x & 63;
  if (lane == 0) { red[0][wid] = s0; red[1][wid] = s1; }
  __syncthreads();
  s0 = red[0][0] + red[0][1] + red[0][2] + red[0][3];
  s1 = red[1][0] + red[1][1] + red[1][2] + red[1][3];
  float mu = s0 * (1.0f / E_);
  float var = s1 * (1.0f / E_) - mu * mu;
  float rs = rsqrtf(var + EPS_);
  u16 oq[8], okv[8];
#pragma unroll
  for (int i = 0; i < 8; i++) {
    float nv = (xv[i] - mu) * rs;
    oq[i] = f2bf(nv * gq[base + i]);
    okv[i] = f2bf(nv * gkv[base + i]);
  }
  *(ushort4*)(lnq + (size_t)row * E_ + base) = make_ushort4(oq[0], oq[1], oq[2], oq[3]);
  *(ushort4*)(lnq + (size_t)row * E_ + base + 4) = make_ushort4(oq[4], oq[5], oq[6], oq[7]);
  *(ushort4*)(lnkv + (size_t)row * E_ + base) = make_ushort4(okv[0], okv[1], okv[2], okv[3]);
  *(ushort4*)(lnkv + (size_t)row * E_ + base + 4) = make_ushort4(okv[4], okv[5], okv[6], okv[7]);
}

// ---------------- transpose f32 -> bf16 (out[N'][K]) ----------------
template <bool SEL>
__global__ __launch_bounds__(256) void k_transp(
    const float* __restrict__ in, u16* __restrict__ out, int K, int Nin) {
  __shared__ float t[32][33];
  int orb = blockIdx.x * 32;
  int icb;
  if (SEL) {
    icb = (orb < 128) ? orb : 128 + ((orb - 128) >> 7) * 256 + ((orb - 128) & 127);
  } else {
    icb = orb;
  }
  int kb = blockIdx.y * 32;
  int tx = threadIdx.x & 31, ty = threadIdx.x >> 5;
#pragma unroll
  for (int i = 0; i < 4; i++)
    t[ty + i * 8][tx] = in[(size_t)(kb + ty + i * 8) * Nin + icb + tx];
  __syncthreads();
#pragma unroll
  for (int i = 0; i < 4; i++)
    out[(size_t)(orb + ty + i * 8) * K + kb + tx] = f2bf(t[tx][ty + i * 8]);
}

// ---------------- bf16 per-batch 2048x2048 transpose: v_nat -> v_t ----------------
__global__ __launch_bounds__(256) void k_vtr(
    const u16* __restrict__ vn, u16* __restrict__ vt) {
  __shared__ u16 t[32][33];
  int c0 = blockIdx.x * 32;
  int b = blockIdx.y >> 6;
  int s0 = (blockIdx.y & 63) * 32;
  int tx = threadIdx.x & 31, ty = threadIdx.x >> 5;
#pragma unroll
  for (int i = 0; i < 4; i++)
    t[ty + i * 8][tx] = vn[((size_t)(b * 2048 + s0 + ty + i * 8)) * 2048 + c0 + tx];
  __syncthreads();
#pragma unroll
  for (int i = 0; i < 4; i++)
    vt[((size_t)(b * 2048 + c0 + ty + i * 8)) * 2048 + s0 + tx] = t[tx][ty + i * 8];
}

// ---------------- GEMM: C = A[M][K] x Bt[N][K]^T  (T3-min single-barrier, XCD swz) --
struct EpiP {
  float* of32;
  u16* obf;
  u16* kc;
  u16* vt;
  u16* qk;
  const float* cost;
  const float* sint;
};

template <int BM, int BN, int EPI>
__global__ __launch_bounds__(256, 3) void k_gemm(
    const u16* __restrict__ A, const u16* __restrict__ Bt,
    int M, int N, int K, EpiP ep) {
  constexpr int WM = BM / 2;
  constexpr int MI = WM / 16;
  constexpr int WN = BN / 2;
  constexpr int NI = WN / 16;
  __shared__ alignas(16) u16 lsA[2][BM * 32];
  __shared__ alignas(16) u16 lsB[2][BN * 32];
  int tid = threadIdx.x, lane = tid & 63, wid = tid >> 6;
  int wr = wid >> 1, wc = wid & 1;
  // T1: bijective XCD swizzle (all launches have nwg % 8 == 0)
  int gx = gridDim.x;
  int nwg = gx * gridDim.y;
  int flat = blockIdx.y * gx + blockIdx.x;
  int cpx = nwg >> 3;
  int swz = (flat & 7) * cpx + (flat >> 3);
  int bm = swz / gx, bn = swz % gx;
  f32x4 zero4 = {0.f, 0.f, 0.f, 0.f};
  f32x4 acc[MI][NI];
#pragma unroll
  for (int m = 0; m < MI; m++)
#pragma unroll
    for (int n = 0; n < NI; n++) acc[m][n] = zero4;
  const int nkt = K >> 5;
  const u16* Ab = A + (size_t)bm * BM * K;
  const u16* Bb = Bt + (size_t)bn * BN * K;
  int arow = tid >> 2, acol8 = (tid & 3) * 8;
  int lg = lane >> 4, li = lane & 15;

  auto stage = [&](int buf, int kt) {
    int k0 = kt * 32;
#pragma unroll
    for (int c = 0; c < BM / 64; c++) {
      int row = c * 64 + arow;
      __builtin_amdgcn_global_load_lds(
          (gvoid*)(Ab + (size_t)row * K + k0 + acol8),
          (lvoid*)(&lsA[buf][row * 32 + acol8]), 16, 0, 0);
    }
#pragma unroll
    for (int c = 0; c < BN / 64; c++) {
      int row = c * 64 + arow;
      __builtin_amdgcn_global_load_lds(
          (gvoid*)(Bb + (size_t)row * K + k0 + acol8),
          (lvoid*)(&lsB[buf][row * 32 + acol8]), 16, 0, 0);
    }
  };

  // T3-min prologue: tile0 staged + landed before loop
  stage(0, 0);
  asm volatile("s_waitcnt vmcnt(0)" ::: "memory");
  __builtin_amdgcn_s_barrier();
  asm volatile("" ::: "memory");
  for (int kt = 0; kt < nkt; ++kt) {
    int cur = kt & 1;
    if (kt + 1 < nkt) stage(cur ^ 1, kt + 1);  // issue next-tile loads FIRST
    bf16x8 af[MI], bfr[NI];
#pragma unroll
    for (int m = 0; m < MI; m++)
      af[m] = *reinterpret_cast<const bf16x8*>(&lsA[cur][(wr * WM + m * 16 + li) * 32 + lg * 8]);
#pragma unroll
    for (int n = 0; n < NI; n++)
      bfr[n] = *reinterpret_cast<const bf16x8*>(&lsB[cur][(wc * WN + n * 16 + li) * 32 + lg * 8]);
#pragma unroll
    for (int m = 0; m < MI; m++)
#pragma unroll
      for (int n = 0; n < NI; n++)
        acc[m][n] = __builtin_amdgcn_mfma_f32_16x16x32_bf16(af[m], bfr[n], acc[m][n], 0, 0, 0);
    // ONE vmcnt(0)+barrier per K-step: next tile landed (flew under compute),
    // and read-before-overwrite is ordered by the same barrier.
    asm volatile("s_waitcnt vmcnt(0)" ::: "memory");
    __builtin_amdgcn_s_barrier();
    asm volatile("" ::: "memory");
  }
  // epilogue
#pragma unroll
  for (int m = 0; m < MI; m++) {
#pragma unroll
    for (int n = 0; n < NI; n++) {
      int col = bn * BN + wc * WN + n * 16 + li;
#pragma unroll
      for (int r = 0; r < 4; r++) {
        int row = bm * BM + wr * WM + m * 16 + lg * 4 + r;
        float val = acc[m][n][r];
        if constexpr (EPI == 0) {
          ep.obf[(size_t)row * 64 + col] = f2bf(val);
        } else if constexpr (EPI == 1) {
          ep.of32[(size_t)row * E_ + col] = val;
        } else if constexpr (EPI == 2) {
          if (col < KR_) {
            ep.kc[(size_t)row * KR_ + col] = f2bf(val);
          } else {
            ep.vt[(size_t)row * 2048 + (col - KR_)] = f2bf(val);  // coalesced natural v
          }
        } else {  // EPI 3: RoPE + per-head store
          int h = col >> 7, dl = col & 127;
          int b = row >> 11, sp = row & 2047;
          float outv;
          if (dl < 64) {
            float pv = acc[m][n ^ 2][r];
            int j = dl & 31;
            float c = ep.cost[sp * 32 + j];
            float s = ep.sint[sp * 32 + j];
            float rot = (dl < 32) ? -pv : pv;
            outv = val * c + rot * s;
          } else {
            outv = val;
          }
          ep.qk[((size_t)(b * H_ + h) * S_ + sp) * D_ + dl] = f2bf(outv);
        }
      }
    }
  }
}

// ---------------- causal flash attention (split-K blocks + LPT refill) ----------------
// Block = (bh, 64-row q-tile j), 4 waves: waves {0,1} = subtiles 0,1 sweeping keys
// [0, 32(j+1)); waves {2,3} = same subtiles sweeping [32(j+1), 64(j+1)). Every wave
// computes every iteration (n = j+1 for all waves). Partials merged through LDS at the
// end (flash combine). 1024 blocks, heavy-j first with 2 resident/CU -> LPT refill.
__global__ __launch_bounds__(256, 2) void k_attn(
    const u16* __restrict__ q_r, const u16* __restrict__ k_r,
    const u16* __restrict__ v_t, u16* __restrict__ y) {
  __shared__ alignas(16) u16 Ks[2][2][32 * 128];  // [dbuf][grp] K tile 32x128
  __shared__ alignas(16) u16 Vs[2][2][64 * 64];   // [dbuf][grp] packed V^T
  __shared__ float Ml[2][2][32];
  int tid = threadIdx.x, lane = tid & 63, wid = tid >> 6;  // wid 0..3
  int id = blockIdx.x;
  int bh = ((id & 7) << 2) | ((id >> 3) & 3);  // XCD-pinned: 4 bh per XCD
  int j = 31 - (id >> 5);                      // heavy tiles dispatched first
  int w2 = wid & 1, grp = wid >> 1;
  int b = bh >> 4, h = bh & 15;
  int li = lane & 31, hi = lane >> 5;
  int qb = 64 * j + w2 * 32;
  int qrow = qb + li;
  int n = j + 1;
  int kg_base = grp * 32 * n;
  const u16* qbase = q_r + (size_t)bh * S_ * D_;
  const u16* kbase = k_r + (size_t)bh * S_ * D_;
  const u16* vbase = v_t + (size_t)bh * D_ * S_;

  bf16x8 aq[8];
#pragma unroll
  for (int step = 0; step < 8; step++)
    aq[step] = *(const bf16x8*)&qbase[(size_t)qrow * D_ + step * 16 + hi * 8];

  f32x16 o[4];
#pragma unroll
  for (int dt = 0; dt < 4; dt++)
#pragma unroll
    for (int r = 0; r < 16; r++) o[dt][r] = 0.f;
  float mreg = -1e30f, lreg = 0.f;

  int kr_l = w2 * 16 + (lane >> 4);  // + i*4
  int kc_l = (lane & 15) * 8;
  int kswz = (li & 7) << 4;

  auto stage = [&](int nb, int p) {
    int kg0 = kg_base + p * 32;
    u16* Kst = &Ks[nb][grp][0];
    u16* Vst = &Vs[nb][grp][0];
#pragma unroll
    for (int i = 0; i < 4; i++) {
      int r = kr_l + i * 4;
      __builtin_amdgcn_global_load_lds(
          (gvoid*)(kbase + (size_t)(kg0 + r) * D_ + (kc_l ^ ((r & 7) << 3))),
          (lvoid*)(&Kst[r * 128 + kc_l]), 16, 0, 0);
    }
#pragma unroll
    for (int i = 0; i < 4; i++) {
      int r = w2 * 32 + i * 8 + (lane >> 3);
      int ss = lane & 7;
      int s = ss ^ (r & 7);
      int d = ((s >> 2) << 6) + r;        // slot half selects d or d+64
      int kk = kg0 + (s & 3) * 8;
      __builtin_amdgcn_global_load_lds(
          (gvoid*)(vbase + (size_t)d * S_ + kk),
          (lvoid*)(&Vst[r * 64 + ss * 8]), 16, 0, 0);
    }
  };

  stage(0, 0);
  int cbuf = 0;

  for (int p = 0; p < n; ++p) {
    int kg0 = kg_base + p * 32;
    asm volatile("s_waitcnt vmcnt(0)" ::: "memory");  // my loads landed (flew under compute)
    __builtin_amdgcn_s_barrier();                      // everyone's loads landed
    asm volatile("" ::: "memory");                     // fence only; scheduling stays free
    if (p + 1 < n) stage(cbuf ^ 1, p + 1);             // overlaps this iter's compute
    if (kg0 <= qb + 31) {
      bool domask = (kg0 + 31 > qb);
      const char* Kc = (const char*)&Ks[cbuf][grp][0];
      const char* Vc = (const char*)&Vs[cbuf][grp][0];
      // ---- QK^T (swapped), 32 keys; accumulator chain split in two (latency) ----
      bf16x8 kf[8];
#pragma unroll
      for (int step = 0; step < 8; step++)
        kf[step] = *(const bf16x8*)(Kc + li * 256 + ((step * 32 + hi * 16) ^ kswz));
      f32x16 c0, c1;
#pragma unroll
      for (int r = 0; r < 16; r++) { c0[r] = 0.f; c1[r] = 0.f; }
      __builtin_amdgcn_s_setprio(1);
#pragma unroll
      for (int step = 0; step < 4; step++) {
        c0 = __builtin_amdgcn_mfma_f32_32x32x16_bf16(kf[step], aq[step], c0, 0, 0, 0);
        c1 = __builtin_amdgcn_mfma_f32_32x32x16_bf16(kf[step + 4], aq[step + 4], c1, 0, 0, 0);
      }
      __builtin_amdgcn_s_setprio(0);
      float ps[16];
#pragma unroll
      for (int r = 0; r < 16; r++) ps[r] = (c0[r] + c1[r]) * SCL2_;  // exp2 domain
      if (domask) {  // wave-uniform boundary branch
#pragma unroll
        for (int r = 0; r < 16; r++) {
          int k = kg0 + (r & 3) + 8 * (r >> 2) + 4 * hi;
          if (k > qrow) ps[r] = -1e30f;
        }
      }
      // ---- in-register softmax (one q row per lane) ----
      float t8[8];
#pragma unroll
      for (int r = 0; r < 8; r++) t8[r] = fmaxf(ps[r], ps[r + 8]);
#pragma unroll
      for (int r = 0; r < 4; r++) t8[r] = fmaxf(t8[r], t8[r + 4]);
      float mt = fmaxf(fmaxf(t8[0], t8[1]), fmaxf(t8[2], t8[3]));
      mt = fmaxf(mt, __shfl_xor(mt, 32));
      // T13 defer-max
      if (!__all(mt <= mreg + 8.f)) {
        float mn = fmaxf(mreg, mt);
        float al = __builtin_amdgcn_exp2f(mreg - mn);
        mreg = mn;
        lreg *= al;
#pragma unroll
        for (int dt = 0; dt < 4; dt++)
#pragma unroll
          for (int r = 0; r < 16; r++) o[dt][r] *= al;
      }
#pragma unroll
      for (int r = 0; r < 16; r++) ps[r] = __builtin_amdgcn_exp2f(ps[r] - mreg);
      float s8[8];
#pragma unroll
      for (int r = 0; r < 8; r++) s8[r] = ps[r] + ps[r + 8];
#pragma unroll
      for (int r = 0; r < 4; r++) s8[r] = s8[r] + s8[r + 4];
      float rs = (s8[0] + s8[1]) + (s8[2] + s8[3]);
      rs += __shfl_xor(rs, 32);
      lreg += rs;
      // ---- PV: B-fragment in-register via cvt_pk + permlane32_swap (T12) ----
#pragma unroll
      for (int ks = 0; ks < 2; ks++) {
        const int bix = ks * 8;
        unsigned P0, P1, P2, P3;
        asm("v_cvt_pk_bf16_f32 %0, %1, %2" : "=v"(P0) : "v"(ps[bix + 0]), "v"(ps[bix + 1]));
        asm("v_cvt_pk_bf16_f32 %0, %1, %2" : "=v"(P1) : "v"(ps[bix + 2]), "v"(ps[bix + 3]));
        asm("v_cvt_pk_bf16_f32 %0, %1, %2" : "=v"(P2) : "v"(ps[bix + 4]), "v"(ps[bix + 5]));
        asm("v_cvt_pk_bf16_f32 %0, %1, %2" : "=v"(P3) : "v"(ps[bix + 6]), "v"(ps[bix + 7]));
        asm("v_permlane32_swap_b32 %0, %1" : "+v"(P0), "+v"(P2));
        asm("v_permlane32_swap_b32 %0, %1" : "+v"(P1), "+v"(P3));
        bf16x8 bp = __builtin_bit_cast(bf16x8, (u32x4){P0, P1, P2, P3});
        bf16x8 vf[4];
#pragma unroll
        for (int dt = 0; dt < 4; dt++) {
          int row = ((dt & 1) << 5) + li;
          vf[dt] = *(const bf16x8*)(Vc + row * 128 +
                                    ((((dt >> 1) * 4 + ks * 2 + hi) * 16) ^ ((row & 7) << 4)));
        }
        __builtin_amdgcn_s_setprio(1);
#pragma unroll
        for (int dt = 0; dt < 4; dt++)
          o[dt] = __builtin_amdgcn_mfma_f32_32x32x16_bf16(vf[dt], bp, o[dt], 0, 0, 0);
        __builtin_amdgcn_s_setprio(0);
      }
    }
    cbuf ^= 1;
  }
  // ---- merge partials: grp0 writes, grp1 combines + stores ----
  __syncthreads();
  float* fb = (float*)&Ks[0][0][0] + w2 * 4096;  // 16 KB region per writer wave
  if (grp == 0) {
#pragma unroll
    for (int k = 0; k < 64; ++k) fb[k * 64 + lane] = o[k >> 4][k & 15];
    if (lane < 32) {
      Ml[w2][0][li] = mreg;
      Ml[w2][1][li] = lreg;
    }
  }
  __syncthreads();
  if (grp == 1) {
    float m1 = Ml[w2][0][li], l1 = Ml[w2][1][li];
    float m = fmaxf(mreg, m1);
    float s2 = __builtin_amdgcn_exp2f(mreg - m);
    float s1 = __builtin_amdgcn_exp2f(m1 - m);
    float lsum = lreg * s2 + l1 * s1;
    float rl = 1.0f / lsum;
    u16* yrow = y + ((size_t)(b * S_ + qrow)) * E_ + h * D_;
#pragma unroll
    for (int dt = 0; dt < 4; dt++) {
#pragma unroll
      for (int g2 = 0; g2 < 4; g2++) {
        int d = dt * 32 + 8 * g2 + 4 * hi;
        ushort4 sv;
        float v0 = (o[dt][4 * g2 + 0] * s2 + fb[(dt * 16 + 4 * g2 + 0) * 64 + lane] * s1) * rl;
        float v1 = (o[dt][4 * g2 + 1] * s2 + fb[(dt * 16 + 4 * g2 + 1) * 64 + lane] * s1) * rl;
        float v2 = (o[dt][4 * g2 + 2] * s2 + fb[(dt * 16 + 4 * g2 + 2) * 64 + lane] * s1) * rl;
        float v3 = (o[dt][4 * g2 + 3] * s2 + fb[(dt * 16 + 4 * g2 + 3) * 64 + lane] * s1) * rl;
        sv.x = f2bf(v0);
        sv.y = f2bf(v1);
        sv.z = f2bf(v2);
        sv.w = f2bf(v3);
        *(ushort4*)(yrow + d) = sv;
      }
    }
  }
}

// ---------------- host ----------------
extern "C" void kernel_launch(void* const* d_in, const int* in_sizes, int n_in,
                              void* d_out, int out_size, void* d_ws, size_t ws_size,
                              hipStream_t stream) {
  const float* x = (const float*)d_in[0];
  const float* g_q = (const float*)d_in[1];
  const float* g_kv = (const float*)d_in[2];
  const float* w_qa = (const float*)d_in[3];
  const float* w_qb = (const float*)d_in[4];
  const float* w_kva = (const float*)d_in[5];
  const float* w_kvb = (const float*)d_in[6];
  const float* w_o = (const float*)d_in[7];
  float* out = (float*)d_out;
  char* ws = (char*)d_ws;

  size_t off = 0;
  float* cos_t = (float*)(ws + off); off += (size_t)S_ * 32 * 4;
  float* sin_t = (float*)(ws + off); off += (size_t)S_ * 32 * 4;
  u16* wqa_t = (u16*)(ws + off); off += (size_t)QR_ * E_ * 2;
  u16* wqb_t = (u16*)(ws + off); off += (size_t)E_ * QR_ * 2;
  u16* wkvb_t = (u16*)(ws + off); off += (size_t)E_ * KR_ * 2;
  u16* wo_t = (u16*)(ws + off); off += (size_t)E_ * E_ * 2;
  u16* wsel_t = (u16*)(ws + off); off += (size_t)NSEL_ * E_ * 2;
  u16* qlow = (u16*)(ws + off); off += (size_t)T_ * QR_ * 2;
  u16* kc = (u16*)(ws + off); off += (size_t)T_ * KR_ * 2;
  u16* ln_q = (u16*)(ws + off); off += (size_t)T_ * E_ * 2;   // reused as y
  u16* ln_kv = (u16*)(ws + off); off += (size_t)T_ * E_ * 2;  // reused as q_r
  u16* k_rb = (u16*)(ws + off); off += (size_t)T_ * E_ * 2;   // first v_nat, then k_r
  u16* v_tb = (u16*)(ws + off); off += (size_t)T_ * E_ * 2;
  u16* y = ln_q;
  u16* q_rb = ln_kv;
  u16* v_nat = k_rb;  // alias: consumed by k_vtr before k-GEMM writes k_r

  // LN + fused RoPE-table build (blocks 0..255 also fill cos_t/sin_t)
  k_ln<<<dim3(T_), dim3(256), 0, stream>>>(x, g_q, g_kv, ln_q, ln_kv, cos_t, sin_t);

  k_transp<false><<<dim3(QR_ / 32, E_ / 32), dim3(256), 0, stream>>>(w_qa, wqa_t, E_, QR_);
  k_transp<false><<<dim3(E_ / 32, QR_ / 32), dim3(256), 0, stream>>>(w_qb, wqb_t, QR_, E_);
  k_transp<false><<<dim3(E_ / 32, KR_ / 32), dim3(256), 0, stream>>>(w_kvb, wkvb_t, KR_, E_);
  k_transp<false><<<dim3(E_ / 32, E_ / 32), dim3(256), 0, stream>>>(w_o, wo_t, E_, E_);
  k_transp<true><<<dim3(NSEL_ / 32, E_ / 32), dim3(256), 0, stream>>>(w_kva, wsel_t, E_, 128 + H_ * 2 * D_);

  EpiP ep{};

  // q_low = ln_q @ w_qa  (M=4096, N=64, K=2048) -- BM=64: 64 blocks
  ep = EpiP{}; ep.obf = qlow;
  k_gemm<64, 64, 0><<<dim3(1, T_ / 64), dim3(256), 0, stream>>>(ln_q, wqa_t, T_, QR_, E_, ep);

  // kv = ln_kv @ w_kva_sel  (M=4096, N=2176, K=2048) -> kc + v natural (coalesced)
  ep = EpiP{}; ep.kc = kc; ep.vt = v_nat;
  k_gemm<128, 128, 2><<<dim3(NSEL_ / 128, T_ / 128), dim3(256), 0, stream>>>(ln_kv, wsel_t, T_, NSEL_, E_, ep);

  // q = q_low @ w_qb + RoPE  (M=4096, N=2048, K=64) -> q_r
  ep = EpiP{}; ep.qk = q_rb; ep.cost = cos_t; ep.sint = sin_t;
  k_gemm<128, 128, 3><<<dim3(E_ / 128, T_ / 128), dim3(256), 0, stream>>>(qlow, wqb_t, T_, E_, QR_, ep);

  // v^T: per-batch 2048x2048 bf16 transpose (v_nat -> v_tb)
  k_vtr<<<dim3(64, 128), dim3(256), 0, stream>>>(v_nat, v_tb);

  // k = kc @ w_kvb + RoPE  (M=4096, N=2048, K=128) -> k_r
  ep = EpiP{}; ep.qk = k_rb; ep.cost = cos_t; ep.sint = sin_t;
  k_gemm<128, 128, 3><<<dim3(E_ / 128, T_ / 128), dim3(256), 0, stream>>>(kc, wkvb_t, T_, E_, KR_, ep);

  // attention -> y (overwrites ln_q). 1024 blocks x 4 waves, split-K + LPT refill.
  k_attn<<<dim3(1024), dim3(256), 0, stream>>>(q_rb, k_rb, v_tb, y);

  // out = y @ w_o  (M=4096, N=2048, K=2048), fp32
  ep = EpiP{}; ep.of32 = out;
  k_gemm<128, 128, 1><<<dim3(E_ / 128, T_ / 128), dim3(256), 0, stream>>>(y, wo_t, T_, E_, E_, ep);
}

// Round 24
// 252.761 us; speedup vs baseline: 1.3830x; 1.0284x over previous
//
#include <hip/hip_runtime.h>
#include <cstdint>
#include <cstddef>

typedef unsigned short u16;
typedef __attribute__((ext_vector_type(8))) __bf16 bf16x8;
typedef __attribute__((ext_vector_type(4))) float f32x4;
typedef __attribute__((ext_vector_type(16))) float f32x16;
typedef __attribute__((ext_vector_type(4))) unsigned u32x4;

#define E_ 2048
#define H_ 16
#define D_ 128
#define QR_ 64
#define KR_ 128
#define S_ 2048
#define B_ 2
#define T_ 4096
#define NSEL_ 2176
#define EPS_ 1e-5f
#define SCALE_ 0.08838834764831845f
#define SCL2_ 0.12751743f  // SCALE_ * log2(e); softmax in exp2 domain

typedef __attribute__((address_space(1))) const void gvoid;
typedef __attribute__((address_space(3))) void lvoid;

__device__ __forceinline__ u16 f2bf(float f) {
  unsigned u = __float_as_uint(f);
  unsigned r = (u + 0x7FFFu + ((u >> 16) & 1u)) >> 16;
  return (u16)r;
}

// ---------------- dual LayerNorm (+ fused RoPE table build in blocks 0..255) --------
__global__ __launch_bounds__(256) void k_ln(
    const float* __restrict__ x, const float* __restrict__ gq,
    const float* __restrict__ gkv, u16* __restrict__ lnq, u16* __restrict__ lnkv,
    float* __restrict__ cos_t, float* __restrict__ sin_t) {
  if (blockIdx.x < (S_ * 32) / 256) {  // fused k_rope_tables (same index math)
    int idx = blockIdx.x * 256 + threadIdx.x;
    int t = idx >> 5, j = idx & 31;
    float inv = powf(10000.0f, -(float)j / 32.0f);
    float a = (float)t * inv;
    cos_t[idx] = cosf(a);
    sin_t[idx] = sinf(a);
  }
  int row = blockIdx.x;
  const float* xr = x + (size_t)row * E_;
  int base = threadIdx.x * 8;
  float4 v0 = *(const float4*)(xr + base);
  float4 v1 = *(const float4*)(xr + base + 4);
  float xv[8] = {v0.x, v0.y, v0.z, v0.w, v1.x, v1.y, v1.z, v1.w};
  float s0 = 0.f, s1 = 0.f;
#pragma unroll
  for (int i = 0; i < 8; i++) { s0 += xv[i]; s1 += xv[i] * xv[i]; }
  for (int off = 32; off > 0; off >>= 1) {
    s0 += __shfl_down(s0, off);
    s1 += __shfl_down(s1, off);
  }
  __shared__ float red[2][4];
  int wid = threadIdx.x >> 6, lane = threadIdx.x & 63;
  if (lane == 0) { red[0][wid] = s0; red[1][wid] = s1; }
  __syncthreads();
  s0 = red[0][0] + red[0][1] + red[0][2] + red[0][3];
  s1 = red[1][0] + red[1][1] + red[1][2] + red[1][3];
  float mu = s0 * (1.0f / E_);
  float var = s1 * (1.0f / E_) - mu * mu;
  float rs = rsqrtf(var + EPS_);
  u16 oq[8], okv[8];
#pragma unroll
  for (int i = 0; i < 8; i++) {
    float nv = (xv[i] - mu) * rs;
    oq[i] = f2bf(nv * gq[base + i]);
    okv[i] = f2bf(nv * gkv[base + i]);
  }
  *(ushort4*)(lnq + (size_t)row * E_ + base) = make_ushort4(oq[0], oq[1], oq[2], oq[3]);
  *(ushort4*)(lnq + (size_t)row * E_ + base + 4) = make_ushort4(oq[4], oq[5], oq[6], oq[7]);
  *(ushort4*)(lnkv + (size_t)row * E_ + base) = make_ushort4(okv[0], okv[1], okv[2], okv[3]);
  *(ushort4*)(lnkv + (size_t)row * E_ + base + 4) = make_ushort4(okv[4], okv[5], okv[6], okv[7]);
}

// ---------------- ALL weight transposes f32 -> bf16 (out[N'][K]) in ONE launch ------
// Flat block decode reproduces each original (gridDim, blockIdx) exactly:
//   [0,128)      w_qb  : grid (64,2)   K=QR,  Nin=E
//   [128,256)    w_qa  : grid (2,64)   K=E,   Nin=QR
//   [256,512)    w_kvb : grid (64,4)   K=KR,  Nin=E
//   [512,4608)   w_o   : grid (64,64)  K=E,   Nin=E
//   [4608,8960)  w_kva : grid (68,64)  K=E,   Nin=128+H*2*D, SEL column remap
__global__ __launch_bounds__(256) void k_transp_all(
    const float* __restrict__ w_qa, const float* __restrict__ w_qb,
    const float* __restrict__ w_kvb, const float* __restrict__ w_o,
    const float* __restrict__ w_kva,
    u16* __restrict__ wqa_t, u16* __restrict__ wqb_t, u16* __restrict__ wkvb_t,
    u16* __restrict__ wo_t, u16* __restrict__ wsel_t) {
  __shared__ float t[32][33];
  int f = blockIdx.x;
  const float* in;
  u16* out;
  int K, Nin, bx, by;
  bool sel = false;
  if (f < 128) {
    in = w_qb; out = wqb_t; K = QR_; Nin = E_; bx = f % 64; by = f / 64;
  } else if (f < 256) {
    f -= 128;
    in = w_qa; out = wqa_t; K = E_; Nin = QR_; bx = f % 2; by = f / 2;
  } else if (f < 512) {
    f -= 256;
    in = w_kvb; out = wkvb_t; K = KR_; Nin = E_; bx = f % 64; by = f / 64;
  } else if (f < 4608) {
    f -= 512;
    in = w_o; out = wo_t; K = E_; Nin = E_; bx = f % 64; by = f / 64;
  } else {
    f -= 4608;
    in = w_kva; out = wsel_t; K = E_; Nin = 128 + H_ * 2 * D_; sel = true;
    bx = f % 68; by = f / 68;
  }
  int orb = bx * 32;
  int icb;
  if (sel) {
    icb = (orb < 128) ? orb : 128 + ((orb - 128) >> 7) * 256 + ((orb - 128) & 127);
  } else {
    icb = orb;
  }
  int kb = by * 32;
  int tx = threadIdx.x & 31, ty = threadIdx.x >> 5;
#pragma unroll
  for (int i = 0; i < 4; i++)
    t[ty + i * 8][tx] = in[(size_t)(kb + ty + i * 8) * Nin + icb + tx];
  __syncthreads();
#pragma unroll
  for (int i = 0; i < 4; i++)
    out[(size_t)(orb + ty + i * 8) * K + kb + tx] = f2bf(t[tx][ty + i * 8]);
}

// ---------------- bf16 per-batch 2048x2048 transpose: v_nat -> v_t ----------------
__global__ __launch_bounds__(256) void k_vtr(
    const u16* __restrict__ vn, u16* __restrict__ vt) {
  __shared__ u16 t[32][33];
  int c0 = blockIdx.x * 32;
  int b = blockIdx.y >> 6;
  int s0 = (blockIdx.y & 63) * 32;
  int tx = threadIdx.x & 31, ty = threadIdx.x >> 5;
#pragma unroll
  for (int i = 0; i < 4; i++)
    t[ty + i * 8][tx] = vn[((size_t)(b * 2048 + s0 + ty + i * 8)) * 2048 + c0 + tx];
  __syncthreads();
#pragma unroll
  for (int i = 0; i < 4; i++)
    vt[((size_t)(b * 2048 + c0 + ty + i * 8)) * 2048 + s0 + tx] = t[tx][ty + i * 8];
}

// ---------------- GEMM: C = A[M][K] x Bt[N][K]^T  (T3-min single-barrier, XCD swz) --
struct EpiP {
  float* of32;
  u16* obf;
  u16* kc;
  u16* vt;
  u16* qk;
  const float* cost;
  const float* sint;
};

template <int BM, int BN, int EPI>
__global__ __launch_bounds__(256, 3) void k_gemm(
    const u16* __restrict__ A, const u16* __restrict__ Bt,
    int M, int N, int K, EpiP ep) {
  constexpr int WM = BM / 2;
  constexpr int MI = WM / 16;
  constexpr int WN = BN / 2;
  constexpr int NI = WN / 16;
  __shared__ alignas(16) u16 lsA[2][BM * 32];
  __shared__ alignas(16) u16 lsB[2][BN * 32];
  int tid = threadIdx.x, lane = tid & 63, wid = tid >> 6;
  int wr = wid >> 1, wc = wid & 1;
  // T1: bijective XCD swizzle (all launches have nwg % 8 == 0)
  int gx = gridDim.x;
  int nwg = gx * gridDim.y;
  int flat = blockIdx.y * gx + blockIdx.x;
  int cpx = nwg >> 3;
  int swz = (flat & 7) * cpx + (flat >> 3);
  int bm = swz / gx, bn = swz % gx;
  f32x4 zero4 = {0.f, 0.f, 0.f, 0.f};
  f32x4 acc[MI][NI];
#pragma unroll
  for (int m = 0; m < MI; m++)
#pragma unroll
    for (int n = 0; n < NI; n++) acc[m][n] = zero4;
  const int nkt = K >> 5;
  const u16* Ab = A + (size_t)bm * BM * K;
  const u16* Bb = Bt + (size_t)bn * BN * K;
  int arow = tid >> 2, acol8 = (tid & 3) * 8;
  int lg = lane >> 4, li = lane & 15;

  auto stage = [&](int buf, int kt) {
    int k0 = kt * 32;
#pragma unroll
    for (int c = 0; c < BM / 64; c++) {
      int row = c * 64 + arow;
      __builtin_amdgcn_global_load_lds(
          (gvoid*)(Ab + (size_t)row * K + k0 + acol8),
          (lvoid*)(&lsA[buf][row * 32 + acol8]), 16, 0, 0);
    }
#pragma unroll
    for (int c = 0; c < BN / 64; c++) {
      int row = c * 64 + arow;
      __builtin_amdgcn_global_load_lds(
          (gvoid*)(Bb + (size_t)row * K + k0 + acol8),
          (lvoid*)(&lsB[buf][row * 32 + acol8]), 16, 0, 0);
    }
  };

  // T3-min prologue: tile0 staged + landed before loop
  stage(0, 0);
  asm volatile("s_waitcnt vmcnt(0)" ::: "memory");
  __builtin_amdgcn_s_barrier();
  asm volatile("" ::: "memory");
  for (int kt = 0; kt < nkt; ++kt) {
    int cur = kt & 1;
    if (kt + 1 < nkt) stage(cur ^ 1, kt + 1);  // issue next-tile loads FIRST
    bf16x8 af[MI], bfr[NI];
#pragma unroll
    for (int m = 0; m < MI; m++)
      af[m] = *reinterpret_cast<const bf16x8*>(&lsA[cur][(wr * WM + m * 16 + li) * 32 + lg * 8]);
#pragma unroll
    for (int n = 0; n < NI; n++)
      bfr[n] = *reinterpret_cast<const bf16x8*>(&lsB[cur][(wc * WN + n * 16 + li) * 32 + lg * 8]);
#pragma unroll
    for (int m = 0; m < MI; m++)
#pragma unroll
      for (int n = 0; n < NI; n++)
        acc[m][n] = __builtin_amdgcn_mfma_f32_16x16x32_bf16(af[m], bfr[n], acc[m][n], 0, 0, 0);
    // ONE vmcnt(0)+barrier per K-step: next tile landed (flew under compute),
    // and read-before-overwrite is ordered by the same barrier.
    asm volatile("s_waitcnt vmcnt(0)" ::: "memory");
    __builtin_amdgcn_s_barrier();
    asm volatile("" ::: "memory");
  }
  // epilogue
#pragma unroll
  for (int m = 0; m < MI; m++) {
#pragma unroll
    for (int n = 0; n < NI; n++) {
      int col = bn * BN + wc * WN + n * 16 + li;
#pragma unroll
      for (int r = 0; r < 4; r++) {
        int row = bm * BM + wr * WM + m * 16 + lg * 4 + r;
        float val = acc[m][n][r];
        if constexpr (EPI == 0) {
          ep.obf[(size_t)row * 64 + col] = f2bf(val);
        } else if constexpr (EPI == 1) {
          ep.of32[(size_t)row * E_ + col] = val;
        } else if constexpr (EPI == 2) {
          if (col < KR_) {
            ep.kc[(size_t)row * KR_ + col] = f2bf(val);
          } else {
            ep.vt[(size_t)row * 2048 + (col - KR_)] = f2bf(val);  // coalesced natural v
          }
        } else {  // EPI 3: RoPE + per-head store
          int h = col >> 7, dl = col & 127;
          int b = row >> 11, sp = row & 2047;
          float outv;
          if (dl < 64) {
            float pv = acc[m][n ^ 2][r];
            int j = dl & 31;
            float c = ep.cost[sp * 32 + j];
            float s = ep.sint[sp * 32 + j];
            float rot = (dl < 32) ? -pv : pv;
            outv = val * c + rot * s;
          } else {
            outv = val;
          }
          ep.qk[((size_t)(b * H_ + h) * S_ + sp) * D_ + dl] = f2bf(outv);
        }
      }
    }
  }
}

// ---------------- causal flash attention (split-K blocks + LPT refill) ----------------
// Block = (bh, 64-row q-tile j), 4 waves: waves {0,1} = subtiles 0,1 sweeping keys
// [0, 32(j+1)); waves {2,3} = same subtiles sweeping [32(j+1), 64(j+1)). Every wave
// computes every iteration (n = j+1 for all waves). Partials merged through LDS at the
// end (flash combine). 1024 blocks, heavy-j first with 2 resident/CU -> LPT refill.
__global__ __launch_bounds__(256, 2) void k_attn(
    const u16* __restrict__ q_r, const u16* __restrict__ k_r,
    const u16* __restrict__ v_t, u16* __restrict__ y) {
  __shared__ alignas(16) u16 Ks[2][2][32 * 128];  // [dbuf][grp] K tile 32x128
  __shared__ alignas(16) u16 Vs[2][2][64 * 64];   // [dbuf][grp] packed V^T
  __shared__ float Ml[2][2][32];
  int tid = threadIdx.x, lane = tid & 63, wid = tid >> 6;  // wid 0..3
  int id = blockIdx.x;
  int bh = ((id & 7) << 2) | ((id >> 3) & 3);  // XCD-pinned: 4 bh per XCD
  int j = 31 - (id >> 5);                      // heavy tiles dispatched first
  int w2 = wid & 1, grp = wid >> 1;
  int b = bh >> 4, h = bh & 15;
  int li = lane & 31, hi = lane >> 5;
  int qb = 64 * j + w2 * 32;
  int qrow = qb + li;
  int n = j + 1;
  int kg_base = grp * 32 * n;
  const u16* qbase = q_r + (size_t)bh * S_ * D_;
  const u16* kbase = k_r + (size_t)bh * S_ * D_;
  const u16* vbase = v_t + (size_t)bh * D_ * S_;

  bf16x8 aq[8];
#pragma unroll
  for (int step = 0; step < 8; step++)
    aq[step] = *(const bf16x8*)&qbase[(size_t)qrow * D_ + step * 16 + hi * 8];

  f32x16 o[4];
#pragma unroll
  for (int dt = 0; dt < 4; dt++)
#pragma unroll
    for (int r = 0; r < 16; r++) o[dt][r] = 0.f;
  float mreg = -1e30f, lreg = 0.f;

  int kr_l = w2 * 16 + (lane >> 4);  // + i*4
  int kc_l = (lane & 15) * 8;
  int kswz = (li & 7) << 4;

  auto stage = [&](int nb, int p) {
    int kg0 = kg_base + p * 32;
    u16* Kst = &Ks[nb][grp][0];
    u16* Vst = &Vs[nb][grp][0];
#pragma unroll
    for (int i = 0; i < 4; i++) {
      int r = kr_l + i * 4;
      __builtin_amdgcn_global_load_lds(
          (gvoid*)(kbase + (size_t)(kg0 + r) * D_ + (kc_l ^ ((r & 7) << 3))),
          (lvoid*)(&Kst[r * 128 + kc_l]), 16, 0, 0);
    }
#pragma unroll
    for (int i = 0; i < 4; i++) {
      int r = w2 * 32 + i * 8 + (lane >> 3);
      int ss = lane & 7;
      int s = ss ^ (r & 7);
      int d = ((s >> 2) << 6) + r;        // slot half selects d or d+64
      int kk = kg0 + (s & 3) * 8;
      __builtin_amdgcn_global_load_lds(
          (gvoid*)(vbase + (size_t)d * S_ + kk),
          (lvoid*)(&Vst[r * 64 + ss * 8]), 16, 0, 0);
    }
  };

  stage(0, 0);
  int cbuf = 0;

  for (int p = 0; p < n; ++p) {
    int kg0 = kg_base + p * 32;
    asm volatile("s_waitcnt vmcnt(0)" ::: "memory");  // my loads landed (flew under compute)
    __builtin_amdgcn_s_barrier();                      // everyone's loads landed
    asm volatile("" ::: "memory");                     // fence only; scheduling stays free
    if (p + 1 < n) stage(cbuf ^ 1, p + 1);             // overlaps this iter's compute
    if (kg0 <= qb + 31) {
      bool domask = (kg0 + 31 > qb);
      const char* Kc = (const char*)&Ks[cbuf][grp][0];
      const char* Vc = (const char*)&Vs[cbuf][grp][0];
      // ---- QK^T (swapped), 32 keys; accumulator chain split in two (latency) ----
      bf16x8 kf[8];
#pragma unroll
      for (int step = 0; step < 8; step++)
        kf[step] = *(const bf16x8*)(Kc + li * 256 + ((step * 32 + hi * 16) ^ kswz));
      f32x16 c0, c1;
#pragma unroll
      for (int r = 0; r < 16; r++) { c0[r] = 0.f; c1[r] = 0.f; }
      __builtin_amdgcn_s_setprio(1);
#pragma unroll
      for (int step = 0; step < 4; step++) {
        c0 = __builtin_amdgcn_mfma_f32_32x32x16_bf16(kf[step], aq[step], c0, 0, 0, 0);
        c1 = __builtin_amdgcn_mfma_f32_32x32x16_bf16(kf[step + 4], aq[step + 4], c1, 0, 0, 0);
      }
      __builtin_amdgcn_s_setprio(0);
      float ps[16];
#pragma unroll
      for (int r = 0; r < 16; r++) ps[r] = (c0[r] + c1[r]) * SCL2_;  // exp2 domain
      if (domask) {  // wave-uniform boundary branch
#pragma unroll
        for (int r = 0; r < 16; r++) {
          int k = kg0 + (r & 3) + 8 * (r >> 2) + 4 * hi;
          if (k > qrow) ps[r] = -1e30f;
        }
      }
      // ---- in-register softmax (one q row per lane) ----
      float t8[8];
#pragma unroll
      for (int r = 0; r < 8; r++) t8[r] = fmaxf(ps[r], ps[r + 8]);
#pragma unroll
      for (int r = 0; r < 4; r++) t8[r] = fmaxf(t8[r], t8[r + 4]);
      float mt = fmaxf(fmaxf(t8[0], t8[1]), fmaxf(t8[2], t8[3]));
      mt = fmaxf(mt, __shfl_xor(mt, 32));
      // T13 defer-max
      if (!__all(mt <= mreg + 8.f)) {
        float mn = fmaxf(mreg, mt);
        float al = __builtin_amdgcn_exp2f(mreg - mn);
        mreg = mn;
        lreg *= al;
#pragma unroll
        for (int dt = 0; dt < 4; dt++)
#pragma unroll
          for (int r = 0; r < 16; r++) o[dt][r] *= al;
      }
#pragma unroll
      for (int r = 0; r < 16; r++) ps[r] = __builtin_amdgcn_exp2f(ps[r] - mreg);
      float s8[8];
#pragma unroll
      for (int r = 0; r < 8; r++) s8[r] = ps[r] + ps[r + 8];
#pragma unroll
      for (int r = 0; r < 4; r++) s8[r] = s8[r] + s8[r + 4];
      float rs = (s8[0] + s8[1]) + (s8[2] + s8[3]);
      rs += __shfl_xor(rs, 32);
      lreg += rs;
      // ---- PV: B-fragment in-register via cvt_pk + permlane32_swap (T12) ----
#pragma unroll
      for (int ks = 0; ks < 2; ks++) {
        const int bix = ks * 8;
        unsigned P0, P1, P2, P3;
        asm("v_cvt_pk_bf16_f32 %0, %1, %2" : "=v"(P0) : "v"(ps[bix + 0]), "v"(ps[bix + 1]));
        asm("v_cvt_pk_bf16_f32 %0, %1, %2" : "=v"(P1) : "v"(ps[bix + 2]), "v"(ps[bix + 3]));
        asm("v_cvt_pk_bf16_f32 %0, %1, %2" : "=v"(P2) : "v"(ps[bix + 4]), "v"(ps[bix + 5]));
        asm("v_cvt_pk_bf16_f32 %0, %1, %2" : "=v"(P3) : "v"(ps[bix + 6]), "v"(ps[bix + 7]));
        asm("v_permlane32_swap_b32 %0, %1" : "+v"(P0), "+v"(P2));
        asm("v_permlane32_swap_b32 %0, %1" : "+v"(P1), "+v"(P3));
        bf16x8 bp = __builtin_bit_cast(bf16x8, (u32x4){P0, P1, P2, P3});
        bf16x8 vf[4];
#pragma unroll
        for (int dt = 0; dt < 4; dt++) {
          int row = ((dt & 1) << 5) + li;
          vf[dt] = *(const bf16x8*)(Vc + row * 128 +
                                    ((((dt >> 1) * 4 + ks * 2 + hi) * 16) ^ ((row & 7) << 4)));
        }
        __builtin_amdgcn_s_setprio(1);
#pragma unroll
        for (int dt = 0; dt < 4; dt++)
          o[dt] = __builtin_amdgcn_mfma_f32_32x32x16_bf16(vf[dt], bp, o[dt], 0, 0, 0);
        __builtin_amdgcn_s_setprio(0);
      }
    }
    cbuf ^= 1;
  }
  // ---- merge partials: grp0 writes, grp1 combines + stores ----
  __syncthreads();
  float* fb = (float*)&Ks[0][0][0] + w2 * 4096;  // 16 KB region per writer wave
  if (grp == 0) {
#pragma unroll
    for (int k = 0; k < 64; ++k) fb[k * 64 + lane] = o[k >> 4][k & 15];
    if (lane < 32) {
      Ml[w2][0][li] = mreg;
      Ml[w2][1][li] = lreg;
    }
  }
  __syncthreads();
  if (grp == 1) {
    float m1 = Ml[w2][0][li], l1 = Ml[w2][1][li];
    float m = fmaxf(mreg, m1);
    float s2 = __builtin_amdgcn_exp2f(mreg - m);
    float s1 = __builtin_amdgcn_exp2f(m1 - m);
    float lsum = lreg * s2 + l1 * s1;
    float rl = 1.0f / lsum;
    u16* yrow = y + ((size_t)(b * S_ + qrow)) * E_ + h * D_;
#pragma unroll
    for (int dt = 0; dt < 4; dt++) {
#pragma unroll
      for (int g2 = 0; g2 < 4; g2++) {
        int d = dt * 32 + 8 * g2 + 4 * hi;
        ushort4 sv;
        float v0 = (o[dt][4 * g2 + 0] * s2 + fb[(dt * 16 + 4 * g2 + 0) * 64 + lane] * s1) * rl;
        float v1 = (o[dt][4 * g2 + 1] * s2 + fb[(dt * 16 + 4 * g2 + 1) * 64 + lane] * s1) * rl;
        float v2 = (o[dt][4 * g2 + 2] * s2 + fb[(dt * 16 + 4 * g2 + 2) * 64 + lane] * s1) * rl;
        float v3 = (o[dt][4 * g2 + 3] * s2 + fb[(dt * 16 + 4 * g2 + 3) * 64 + lane] * s1) * rl;
        sv.x = f2bf(v0);
        sv.y = f2bf(v1);
        sv.z = f2bf(v2);
        sv.w = f2bf(v3);
        *(ushort4*)(yrow + d) = sv;
      }
    }
  }
}

// ---------------- host ----------------
extern "C" void kernel_launch(void* const* d_in, const int* in_sizes, int n_in,
                              void* d_out, int out_size, void* d_ws, size_t ws_size,
                              hipStream_t stream) {
  const float* x = (const float*)d_in[0];
  const float* g_q = (const float*)d_in[1];
  const float* g_kv = (const float*)d_in[2];
  const float* w_qa = (const float*)d_in[3];
  const float* w_qb = (const float*)d_in[4];
  const float* w_kva = (const float*)d_in[5];
  const float* w_kvb = (const float*)d_in[6];
  const float* w_o = (const float*)d_in[7];
  float* out = (float*)d_out;
  char* ws = (char*)d_ws;

  size_t off = 0;
  float* cos_t = (float*)(ws + off); off += (size_t)S_ * 32 * 4;
  float* sin_t = (float*)(ws + off); off += (size_t)S_ * 32 * 4;
  u16* wqa_t = (u16*)(ws + off); off += (size_t)QR_ * E_ * 2;
  u16* wqb_t = (u16*)(ws + off); off += (size_t)E_ * QR_ * 2;
  u16* wkvb_t = (u16*)(ws + off); off += (size_t)E_ * KR_ * 2;
  u16* wo_t = (u16*)(ws + off); off += (size_t)E_ * E_ * 2;
  u16* wsel_t = (u16*)(ws + off); off += (size_t)NSEL_ * E_ * 2;
  u16* qlow = (u16*)(ws + off); off += (size_t)T_ * QR_ * 2;
  u16* kc = (u16*)(ws + off); off += (size_t)T_ * KR_ * 2;
  u16* ln_q = (u16*)(ws + off); off += (size_t)T_ * E_ * 2;   // reused as y
  u16* ln_kv = (u16*)(ws + off); off += (size_t)T_ * E_ * 2;  // reused as q_r
  u16* k_rb = (u16*)(ws + off); off += (size_t)T_ * E_ * 2;   // first v_nat, then k_r
  u16* v_tb = (u16*)(ws + off); off += (size_t)T_ * E_ * 2;
  u16* y = ln_q;
  u16* q_rb = ln_kv;
  u16* v_nat = k_rb;  // alias: consumed by k_vtr before k-GEMM writes k_r

  // LN + fused RoPE-table build (blocks 0..255 also fill cos_t/sin_t)
  k_ln<<<dim3(T_), dim3(256), 0, stream>>>(x, g_q, g_kv, ln_q, ln_kv, cos_t, sin_t);

  // all five weight transposes in one launch (8960 blocks)
  k_transp_all<<<dim3(8960), dim3(256), 0, stream>>>(
      w_qa, w_qb, w_kvb, w_o, w_kva, wqa_t, wqb_t, wkvb_t, wo_t, wsel_t);

  EpiP ep{};

  // q_low = ln_q @ w_qa  (M=4096, N=64, K=2048) -- BM=64: 64 blocks
  ep = EpiP{}; ep.obf = qlow;
  k_gemm<64, 64, 0><<<dim3(1, T_ / 64), dim3(256), 0, stream>>>(ln_q, wqa_t, T_, QR_, E_, ep);

  // kv = ln_kv @ w_kva_sel  (M=4096, N=2176, K=2048) -> kc + v natural (coalesced)
  ep = EpiP{}; ep.kc = kc; ep.vt = v_nat;
  k_gemm<128, 128, 2><<<dim3(NSEL_ / 128, T_ / 128), dim3(256), 0, stream>>>(ln_kv, wsel_t, T_, NSEL_, E_, ep);

  // q = q_low @ w_qb + RoPE  (M=4096, N=2048, K=64) -> q_r
  ep = EpiP{}; ep.qk = q_rb; ep.cost = cos_t; ep.sint = sin_t;
  k_gemm<128, 128, 3><<<dim3(E_ / 128, T_ / 128), dim3(256), 0, stream>>>(qlow, wqb_t, T_, E_, QR_, ep);

  // v^T: per-batch 2048x2048 bf16 transpose (v_nat -> v_tb)
  k_vtr<<<dim3(64, 128), dim3(256), 0, stream>>>(v_nat, v_tb);

  // k = kc @ w_kvb + RoPE  (M=4096, N=2048, K=128) -> k_r
  ep = EpiP{}; ep.qk = k_rb; ep.cost = cos_t; ep.sint = sin_t;
  k_gemm<128, 128, 3><<<dim3(E_ / 128, T_ / 128), dim3(256), 0, stream>>>(kc, wkvb_t, T_, E_, KR_, ep);

  // attention -> y (overwrites ln_q). 1024 blocks x 4 waves, split-K + LPT refill.
  k_attn<<<dim3(1024), dim3(256), 0, stream>>>(q_rb, k_rb, v_tb, y);

  // out = y @ w_o  (M=4096, N=2048, K=2048), fp32
  ep = EpiP{}; ep.of32 = out;
  k_gemm<128, 128, 1><<<dim3(E_ / 128, T_ / 128), dim3(256), 0, stream>>>(y, wo_t, T_, E_, E_, ep);
}

// Round 25
// 249.301 us; speedup vs baseline: 1.4022x; 1.0139x over previous
//
#include <hip/hip_runtime.h>
#include <cstdint>
#include <cstddef>

typedef unsigned short u16;
typedef __attribute__((ext_vector_type(8))) __bf16 bf16x8;
typedef __attribute__((ext_vector_type(4))) float f32x4;
typedef __attribute__((ext_vector_type(16))) float f32x16;
typedef __attribute__((ext_vector_type(4))) unsigned u32x4;

#define E_ 2048
#define H_ 16
#define D_ 128
#define QR_ 64
#define KR_ 128
#define S_ 2048
#define B_ 2
#define T_ 4096
#define NSEL_ 2176
#define EPS_ 1e-5f
#define SCALE_ 0.08838834764831845f
#define SCL2_ 0.12751743f  // SCALE_ * log2(e); softmax in exp2 domain

typedef __attribute__((address_space(1))) const void gvoid;
typedef __attribute__((address_space(3))) void lvoid;

__device__ __forceinline__ u16 f2bf(float f) {
  unsigned u = __float_as_uint(f);
  unsigned r = (u + 0x7FFFu + ((u >> 16) & 1u)) >> 16;
  return (u16)r;
}

// ---------------- dual LayerNorm (+ fused RoPE table build in blocks 0..255) --------
__global__ __launch_bounds__(256) void k_ln(
    const float* __restrict__ x, const float* __restrict__ gq,
    const float* __restrict__ gkv, u16* __restrict__ lnq, u16* __restrict__ lnkv,
    float* __restrict__ cos_t, float* __restrict__ sin_t) {
  if (blockIdx.x < (S_ * 32) / 256) {  // fused k_rope_tables (same index math)
    int idx = blockIdx.x * 256 + threadIdx.x;
    int t = idx >> 5, j = idx & 31;
    float inv = powf(10000.0f, -(float)j / 32.0f);
    float a = (float)t * inv;
    cos_t[idx] = cosf(a);
    sin_t[idx] = sinf(a);
  }
  int row = blockIdx.x;
  const float* xr = x + (size_t)row * E_;
  int base = threadIdx.x * 8;
  float4 v0 = *(const float4*)(xr + base);
  float4 v1 = *(const float4*)(xr + base + 4);
  float xv[8] = {v0.x, v0.y, v0.z, v0.w, v1.x, v1.y, v1.z, v1.w};
  float s0 = 0.f, s1 = 0.f;
#pragma unroll
  for (int i = 0; i < 8; i++) { s0 += xv[i]; s1 += xv[i] * xv[i]; }
  for (int off = 32; off > 0; off >>= 1) {
    s0 += __shfl_down(s0, off);
    s1 += __shfl_down(s1, off);
  }
  __shared__ float red[2][4];
  int wid = threadIdx.x >> 6, lane = threadIdx.x & 63;
  if (lane == 0) { red[0][wid] = s0; red[1][wid] = s1; }
  __syncthreads();
  s0 = red[0][0] + red[0][1] + red[0][2] + red[0][3];
  s1 = red[1][0] + red[1][1] + red[1][2] + red[1][3];
  float mu = s0 * (1.0f / E_);
  float var = s1 * (1.0f / E_) - mu * mu;
  float rs = rsqrtf(var + EPS_);
  u16 oq[8], okv[8];
#pragma unroll
  for (int i = 0; i < 8; i++) {
    float nv = (xv[i] - mu) * rs;
    oq[i] = f2bf(nv * gq[base + i]);
    okv[i] = f2bf(nv * gkv[base + i]);
  }
  *(ushort4*)(lnq + (size_t)row * E_ + base) = make_ushort4(oq[0], oq[1], oq[2], oq[3]);
  *(ushort4*)(lnq + (size_t)row * E_ + base + 4) = make_ushort4(oq[4], oq[5], oq[6], oq[7]);
  *(ushort4*)(lnkv + (size_t)row * E_ + base) = make_ushort4(okv[0], okv[1], okv[2], okv[3]);
  *(ushort4*)(lnkv + (size_t)row * E_ + base + 4) = make_ushort4(okv[4], okv[5], okv[6], okv[7]);
}

// ---------------- ALL weight transposes f32 -> bf16 (out[N'][K]) in ONE launch ------
// Flat block decode reproduces each original (gridDim, blockIdx) exactly:
//   [0,128)      w_qb  : grid (64,2)   K=QR,  Nin=E
//   [128,256)    w_qa  : grid (2,64)   K=E,   Nin=QR
//   [256,512)    w_kvb : grid (64,4)   K=KR,  Nin=E
//   [512,4608)   w_o   : grid (64,64)  K=E,   Nin=E
//   [4608,8960)  w_kva : grid (68,64)  K=E,   Nin=128+H*2*D, SEL column remap
__global__ __launch_bounds__(256) void k_transp_all(
    const float* __restrict__ w_qa, const float* __restrict__ w_qb,
    const float* __restrict__ w_kvb, const float* __restrict__ w_o,
    const float* __restrict__ w_kva,
    u16* __restrict__ wqa_t, u16* __restrict__ wqb_t, u16* __restrict__ wkvb_t,
    u16* __restrict__ wo_t, u16* __restrict__ wsel_t) {
  __shared__ float t[32][33];
  int f = blockIdx.x;
  const float* in;
  u16* out;
  int K, Nin, bx, by;
  bool sel = false;
  if (f < 128) {
    in = w_qb; out = wqb_t; K = QR_; Nin = E_; bx = f % 64; by = f / 64;
  } else if (f < 256) {
    f -= 128;
    in = w_qa; out = wqa_t; K = E_; Nin = QR_; bx = f % 2; by = f / 2;
  } else if (f < 512) {
    f -= 256;
    in = w_kvb; out = wkvb_t; K = KR_; Nin = E_; bx = f % 64; by = f / 64;
  } else if (f < 4608) {
    f -= 512;
    in = w_o; out = wo_t; K = E_; Nin = E_; bx = f % 64; by = f / 64;
  } else {
    f -= 4608;
    in = w_kva; out = wsel_t; K = E_; Nin = 128 + H_ * 2 * D_; sel = true;
    bx = f % 68; by = f / 68;
  }
  int orb = bx * 32;
  int icb;
  if (sel) {
    icb = (orb < 128) ? orb : 128 + ((orb - 128) >> 7) * 256 + ((orb - 128) & 127);
  } else {
    icb = orb;
  }
  int kb = by * 32;
  int tx = threadIdx.x & 31, ty = threadIdx.x >> 5;
#pragma unroll
  for (int i = 0; i < 4; i++)
    t[ty + i * 8][tx] = in[(size_t)(kb + ty + i * 8) * Nin + icb + tx];
  __syncthreads();
#pragma unroll
  for (int i = 0; i < 4; i++)
    out[(size_t)(orb + ty + i * 8) * K + kb + tx] = f2bf(t[tx][ty + i * 8]);
}

// ---------------- bf16 per-batch 2048x2048 transpose: v_nat -> v_t (vectorized) -----
// 64x64 tiles, ushort4 (8B) on both sides through padded LDS. vt[c][s] = vn[s][c].
__global__ __launch_bounds__(256) void k_vtr(
    const u16* __restrict__ vn, u16* __restrict__ vt) {
  __shared__ u16 t[64][68];
  int c0 = blockIdx.x * 64;
  int b = blockIdx.y >> 5;
  int s0 = (blockIdx.y & 31) * 64;
#pragma unroll
  for (int i = 0; i < 4; i++) {
    int flat = threadIdx.x + i * 256;
    int r = flat >> 4, q = flat & 15;
    ushort4 v = *(const ushort4*)&vn[((size_t)(b * 2048 + s0 + r)) * 2048 + c0 + q * 4];
    t[r][q * 4 + 0] = v.x;
    t[r][q * 4 + 1] = v.y;
    t[r][q * 4 + 2] = v.z;
    t[r][q * 4 + 3] = v.w;
  }
  __syncthreads();
#pragma unroll
  for (int i = 0; i < 4; i++) {
    int flat = threadIdx.x + i * 256;
    int c = flat >> 4, q = flat & 15;
    ushort4 v;
    v.x = t[q * 4 + 0][c];
    v.y = t[q * 4 + 1][c];
    v.z = t[q * 4 + 2][c];
    v.w = t[q * 4 + 3][c];
    *(ushort4*)&vt[((size_t)(b * 2048 + c0 + c)) * 2048 + s0 + q * 4] = v;
  }
}

// ---------------- GEMM: C = A[M][K] x Bt[N][K]^T  (T3-min single-barrier, XCD swz) --
struct EpiP {
  float* of32;
  u16* obf;
  u16* kc;
  u16* vt;
  u16* qk;
  const float* cost;
  const float* sint;
};

template <int BM, int BN, int EPI>
__global__ __launch_bounds__(256, 3) void k_gemm(
    const u16* __restrict__ A, const u16* __restrict__ Bt,
    int M, int N, int K, EpiP ep) {
  constexpr int WM = BM / 2;
  constexpr int MI = WM / 16;
  constexpr int WN = BN / 2;
  constexpr int NI = WN / 16;
  __shared__ alignas(16) u16 lsA[2][BM * 32];
  __shared__ alignas(16) u16 lsB[2][BN * 32];
  int tid = threadIdx.x, lane = tid & 63, wid = tid >> 6;
  int wr = wid >> 1, wc = wid & 1;
  // T1: bijective XCD swizzle (all launches have nwg % 8 == 0)
  int gx = gridDim.x;
  int nwg = gx * gridDim.y;
  int flat = blockIdx.y * gx + blockIdx.x;
  int cpx = nwg >> 3;
  int swz = (flat & 7) * cpx + (flat >> 3);
  int bm = swz / gx, bn = swz % gx;
  f32x4 zero4 = {0.f, 0.f, 0.f, 0.f};
  f32x4 acc[MI][NI];
#pragma unroll
  for (int m = 0; m < MI; m++)
#pragma unroll
    for (int n = 0; n < NI; n++) acc[m][n] = zero4;
  const int nkt = K >> 5;
  const u16* Ab = A + (size_t)bm * BM * K;
  const u16* Bb = Bt + (size_t)bn * BN * K;
  int arow = tid >> 2, acol8 = (tid & 3) * 8;
  int lg = lane >> 4, li = lane & 15;

  auto stage = [&](int buf, int kt) {
    int k0 = kt * 32;
#pragma unroll
    for (int c = 0; c < BM / 64; c++) {
      int row = c * 64 + arow;
      __builtin_amdgcn_global_load_lds(
          (gvoid*)(Ab + (size_t)row * K + k0 + acol8),
          (lvoid*)(&lsA[buf][row * 32 + acol8]), 16, 0, 0);
    }
#pragma unroll
    for (int c = 0; c < BN / 64; c++) {
      int row = c * 64 + arow;
      __builtin_amdgcn_global_load_lds(
          (gvoid*)(Bb + (size_t)row * K + k0 + acol8),
          (lvoid*)(&lsB[buf][row * 32 + acol8]), 16, 0, 0);
    }
  };

  // T3-min prologue: tile0 staged + landed before loop
  stage(0, 0);
  asm volatile("s_waitcnt vmcnt(0)" ::: "memory");
  __builtin_amdgcn_s_barrier();
  asm volatile("" ::: "memory");
  for (int kt = 0; kt < nkt; ++kt) {
    int cur = kt & 1;
    if (kt + 1 < nkt) stage(cur ^ 1, kt + 1);  // issue next-tile loads FIRST
    bf16x8 af[MI], bfr[NI];
#pragma unroll
    for (int m = 0; m < MI; m++)
      af[m] = *reinterpret_cast<const bf16x8*>(&lsA[cur][(wr * WM + m * 16 + li) * 32 + lg * 8]);
#pragma unroll
    for (int n = 0; n < NI; n++)
      bfr[n] = *reinterpret_cast<const bf16x8*>(&lsB[cur][(wc * WN + n * 16 + li) * 32 + lg * 8]);
#pragma unroll
    for (int m = 0; m < MI; m++)
#pragma unroll
      for (int n = 0; n < NI; n++)
        acc[m][n] = __builtin_amdgcn_mfma_f32_16x16x32_bf16(af[m], bfr[n], acc[m][n], 0, 0, 0);
    // ONE vmcnt(0)+barrier per K-step: next tile landed (flew under compute),
    // and read-before-overwrite is ordered by the same barrier.
    asm volatile("s_waitcnt vmcnt(0)" ::: "memory");
    __builtin_amdgcn_s_barrier();
    asm volatile("" ::: "memory");
  }
  // epilogue
#pragma unroll
  for (int m = 0; m < MI; m++) {
#pragma unroll
    for (int n = 0; n < NI; n++) {
      int col = bn * BN + wc * WN + n * 16 + li;
#pragma unroll
      for (int r = 0; r < 4; r++) {
        int row = bm * BM + wr * WM + m * 16 + lg * 4 + r;
        float val = acc[m][n][r];
        if constexpr (EPI == 0) {
          ep.obf[(size_t)row * 64 + col] = f2bf(val);
        } else if constexpr (EPI == 1) {
          ep.of32[(size_t)row * E_ + col] = val;
        } else if constexpr (EPI == 2) {
          if (col < KR_) {
            ep.kc[(size_t)row * KR_ + col] = f2bf(val);
          } else {
            ep.vt[(size_t)row * 2048 + (col - KR_)] = f2bf(val);  // coalesced natural v
          }
        } else {  // EPI 3: RoPE + per-head store
          int h = col >> 7, dl = col & 127;
          int b = row >> 11, sp = row & 2047;
          float outv;
          if (dl < 64) {
            float pv = acc[m][n ^ 2][r];
            int j = dl & 31;
            float c = ep.cost[sp * 32 + j];
            float s = ep.sint[sp * 32 + j];
            float rot = (dl < 32) ? -pv : pv;
            outv = val * c + rot * s;
          } else {
            outv = val;
          }
          ep.qk[((size_t)(b * H_ + h) * S_ + sp) * D_ + dl] = f2bf(outv);
        }
      }
    }
  }
}

// ---------------- causal flash attention (split-K blocks + LPT refill) ----------------
// Block = (bh, 64-row q-tile j), 4 waves: waves {0,1} = subtiles 0,1 sweeping keys
// [0, 32(j+1)); waves {2,3} = same subtiles sweeping [32(j+1), 64(j+1)). Every wave
// computes every iteration (n = j+1 for all waves). Partials merged through LDS at the
// end (flash combine). 1024 blocks, heavy-j first with 2 resident/CU -> LPT refill.
__global__ __launch_bounds__(256, 2) void k_attn(
    const u16* __restrict__ q_r, const u16* __restrict__ k_r,
    const u16* __restrict__ v_t, u16* __restrict__ y) {
  __shared__ alignas(16) u16 Ks[2][2][32 * 128];  // [dbuf][grp] K tile 32x128
  __shared__ alignas(16) u16 Vs[2][2][64 * 64];   // [dbuf][grp] packed V^T
  __shared__ float Ml[2][2][32];
  int tid = threadIdx.x, lane = tid & 63, wid = tid >> 6;  // wid 0..3
  int id = blockIdx.x;
  int bh = ((id & 7) << 2) | ((id >> 3) & 3);  // XCD-pinned: 4 bh per XCD
  int j = 31 - (id >> 5);                      // heavy tiles dispatched first
  int w2 = wid & 1, grp = wid >> 1;
  int b = bh >> 4, h = bh & 15;
  int li = lane & 31, hi = lane >> 5;
  int qb = 64 * j + w2 * 32;
  int qrow = qb + li;
  int n = j + 1;
  int kg_base = grp * 32 * n;
  const u16* qbase = q_r + (size_t)bh * S_ * D_;
  const u16* kbase = k_r + (size_t)bh * S_ * D_;
  const u16* vbase = v_t + (size_t)bh * D_ * S_;

  bf16x8 aq[8];
#pragma unroll
  for (int step = 0; step < 8; step++)
    aq[step] = *(const bf16x8*)&qbase[(size_t)qrow * D_ + step * 16 + hi * 8];

  f32x16 o[4];
#pragma unroll
  for (int dt = 0; dt < 4; dt++)
#pragma unroll
    for (int r = 0; r < 16; r++) o[dt][r] = 0.f;
  float mreg = -1e30f, lreg = 0.f;

  int kr_l = w2 * 16 + (lane >> 4);  // + i*4
  int kc_l = (lane & 15) * 8;
  int kswz = (li & 7) << 4;

  auto stage = [&](int nb, int p) {
    int kg0 = kg_base + p * 32;
    u16* Kst = &Ks[nb][grp][0];
    u16* Vst = &Vs[nb][grp][0];
#pragma unroll
    for (int i = 0; i < 4; i++) {
      int r = kr_l + i * 4;
      __builtin_amdgcn_global_load_lds(
          (gvoid*)(kbase + (size_t)(kg0 + r) * D_ + (kc_l ^ ((r & 7) << 3))),
          (lvoid*)(&Kst[r * 128 + kc_l]), 16, 0, 0);
    }
#pragma unroll
    for (int i = 0; i < 4; i++) {
      int r = w2 * 32 + i * 8 + (lane >> 3);
      int ss = lane & 7;
      int s = ss ^ (r & 7);
      int d = ((s >> 2) << 6) + r;        // slot half selects d or d+64
      int kk = kg0 + (s & 3) * 8;
      __builtin_amdgcn_global_load_lds(
          (gvoid*)(vbase + (size_t)d * S_ + kk),
          (lvoid*)(&Vst[r * 64 + ss * 8]), 16, 0, 0);
    }
  };

  stage(0, 0);
  int cbuf = 0;

  for (int p = 0; p < n; ++p) {
    int kg0 = kg_base + p * 32;
    asm volatile("s_waitcnt vmcnt(0)" ::: "memory");  // my loads landed (flew under compute)
    __builtin_amdgcn_s_barrier();                      // everyone's loads landed
    asm volatile("" ::: "memory");                     // fence only; scheduling stays free
    if (p + 1 < n) stage(cbuf ^ 1, p + 1);             // overlaps this iter's compute
    if (kg0 <= qb + 31) {
      bool domask = (kg0 + 31 > qb);
      const char* Kc = (const char*)&Ks[cbuf][grp][0];
      const char* Vc = (const char*)&Vs[cbuf][grp][0];
      // ---- QK^T (swapped), 32 keys; accumulator chain split in two (latency) ----
      bf16x8 kf[8];
#pragma unroll
      for (int step = 0; step < 8; step++)
        kf[step] = *(const bf16x8*)(Kc + li * 256 + ((step * 32 + hi * 16) ^ kswz));
      f32x16 c0, c1;
#pragma unroll
      for (int r = 0; r < 16; r++) { c0[r] = 0.f; c1[r] = 0.f; }
      __builtin_amdgcn_s_setprio(1);
#pragma unroll
      for (int step = 0; step < 4; step++) {
        c0 = __builtin_amdgcn_mfma_f32_32x32x16_bf16(kf[step], aq[step], c0, 0, 0, 0);
        c1 = __builtin_amdgcn_mfma_f32_32x32x16_bf16(kf[step + 4], aq[step + 4], c1, 0, 0, 0);
      }
      __builtin_amdgcn_s_setprio(0);
      float ps[16];
#pragma unroll
      for (int r = 0; r < 16; r++) ps[r] = (c0[r] + c1[r]) * SCL2_;  // exp2 domain
      if (domask) {  // wave-uniform boundary branch
#pragma unroll
        for (int r = 0; r < 16; r++) {
          int k = kg0 + (r & 3) + 8 * (r >> 2) + 4 * hi;
          if (k > qrow) ps[r] = -1e30f;
        }
      }
      // ---- in-register softmax (one q row per lane) ----
      float t8[8];
#pragma unroll
      for (int r = 0; r < 8; r++) t8[r] = fmaxf(ps[r], ps[r + 8]);
#pragma unroll
      for (int r = 0; r < 4; r++) t8[r] = fmaxf(t8[r], t8[r + 4]);
      float mt = fmaxf(fmaxf(t8[0], t8[1]), fmaxf(t8[2], t8[3]));
      mt = fmaxf(mt, __shfl_xor(mt, 32));
      // T13 defer-max
      if (!__all(mt <= mreg + 8.f)) {
        float mn = fmaxf(mreg, mt);
        float al = __builtin_amdgcn_exp2f(mreg - mn);
        mreg = mn;
        lreg *= al;
#pragma unroll
        for (int dt = 0; dt < 4; dt++)
#pragma unroll
          for (int r = 0; r < 16; r++) o[dt][r] *= al;
      }
#pragma unroll
      for (int r = 0; r < 16; r++) ps[r] = __builtin_amdgcn_exp2f(ps[r] - mreg);
      float s8[8];
#pragma unroll
      for (int r = 0; r < 8; r++) s8[r] = ps[r] + ps[r + 8];
#pragma unroll
      for (int r = 0; r < 4; r++) s8[r] = s8[r] + s8[r + 4];
      float rs = (s8[0] + s8[1]) + (s8[2] + s8[3]);
      rs += __shfl_xor(rs, 32);
      lreg += rs;
      // ---- PV: B-fragment in-register via cvt_pk + permlane32_swap (T12) ----
#pragma unroll
      for (int ks = 0; ks < 2; ks++) {
        const int bix = ks * 8;
        unsigned P0, P1, P2, P3;
        asm("v_cvt_pk_bf16_f32 %0, %1, %2" : "=v"(P0) : "v"(ps[bix + 0]), "v"(ps[bix + 1]));
        asm("v_cvt_pk_bf16_f32 %0, %1, %2" : "=v"(P1) : "v"(ps[bix + 2]), "v"(ps[bix + 3]));
        asm("v_cvt_pk_bf16_f32 %0, %1, %2" : "=v"(P2) : "v"(ps[bix + 4]), "v"(ps[bix + 5]));
        asm("v_cvt_pk_bf16_f32 %0, %1, %2" : "=v"(P3) : "v"(ps[bix + 6]), "v"(ps[bix + 7]));
        asm("v_permlane32_swap_b32 %0, %1" : "+v"(P0), "+v"(P2));
        asm("v_permlane32_swap_b32 %0, %1" : "+v"(P1), "+v"(P3));
        bf16x8 bp = __builtin_bit_cast(bf16x8, (u32x4){P0, P1, P2, P3});
        bf16x8 vf[4];
#pragma unroll
        for (int dt = 0; dt < 4; dt++) {
          int row = ((dt & 1) << 5) + li;
          vf[dt] = *(const bf16x8*)(Vc + row * 128 +
                                    ((((dt >> 1) * 4 + ks * 2 + hi) * 16) ^ ((row & 7) << 4)));
        }
        __builtin_amdgcn_s_setprio(1);
#pragma unroll
        for (int dt = 0; dt < 4; dt++)
          o[dt] = __builtin_amdgcn_mfma_f32_32x32x16_bf16(vf[dt], bp, o[dt], 0, 0, 0);
        __builtin_amdgcn_s_setprio(0);
      }
    }
    cbuf ^= 1;
  }
  // ---- merge partials: grp0 writes, grp1 combines + stores ----
  __syncthreads();
  float* fb = (float*)&Ks[0][0][0] + w2 * 4096;  // 16 KB region per writer wave
  if (grp == 0) {
#pragma unroll
    for (int k = 0; k < 64; ++k) fb[k * 64 + lane] = o[k >> 4][k & 15];
    if (lane < 32) {
      Ml[w2][0][li] = mreg;
      Ml[w2][1][li] = lreg;
    }
  }
  __syncthreads();
  if (grp == 1) {
    float m1 = Ml[w2][0][li], l1 = Ml[w2][1][li];
    float m = fmaxf(mreg, m1);
    float s2 = __builtin_amdgcn_exp2f(mreg - m);
    float s1 = __builtin_amdgcn_exp2f(m1 - m);
    float lsum = lreg * s2 + l1 * s1;
    float rl = 1.0f / lsum;
    u16* yrow = y + ((size_t)(b * S_ + qrow)) * E_ + h * D_;
#pragma unroll
    for (int dt = 0; dt < 4; dt++) {
#pragma unroll
      for (int g2 = 0; g2 < 4; g2++) {
        int d = dt * 32 + 8 * g2 + 4 * hi;
        ushort4 sv;
        float v0 = (o[dt][4 * g2 + 0] * s2 + fb[(dt * 16 + 4 * g2 + 0) * 64 + lane] * s1) * rl;
        float v1 = (o[dt][4 * g2 + 1] * s2 + fb[(dt * 16 + 4 * g2 + 1) * 64 + lane] * s1) * rl;
        float v2 = (o[dt][4 * g2 + 2] * s2 + fb[(dt * 16 + 4 * g2 + 2) * 64 + lane] * s1) * rl;
        float v3 = (o[dt][4 * g2 + 3] * s2 + fb[(dt * 16 + 4 * g2 + 3) * 64 + lane] * s1) * rl;
        sv.x = f2bf(v0);
        sv.y = f2bf(v1);
        sv.z = f2bf(v2);
        sv.w = f2bf(v3);
        *(ushort4*)(yrow + d) = sv;
      }
    }
  }
}

// ---------------- host ----------------
extern "C" void kernel_launch(void* const* d_in, const int* in_sizes, int n_in,
                              void* d_out, int out_size, void* d_ws, size_t ws_size,
                              hipStream_t stream) {
  const float* x = (const float*)d_in[0];
  const float* g_q = (const float*)d_in[1];
  const float* g_kv = (const float*)d_in[2];
  const float* w_qa = (const float*)d_in[3];
  const float* w_qb = (const float*)d_in[4];
  const float* w_kva = (const float*)d_in[5];
  const float* w_kvb = (const float*)d_in[6];
  const float* w_o = (const float*)d_in[7];
  float* out = (float*)d_out;
  char* ws = (char*)d_ws;

  size_t off = 0;
  float* cos_t = (float*)(ws + off); off += (size_t)S_ * 32 * 4;
  float* sin_t = (float*)(ws + off); off += (size_t)S_ * 32 * 4;
  u16* wqa_t = (u16*)(ws + off); off += (size_t)QR_ * E_ * 2;
  u16* wqb_t = (u16*)(ws + off); off += (size_t)E_ * QR_ * 2;
  u16* wkvb_t = (u16*)(ws + off); off += (size_t)E_ * KR_ * 2;
  u16* wo_t = (u16*)(ws + off); off += (size_t)E_ * E_ * 2;
  u16* wsel_t = (u16*)(ws + off); off += (size_t)NSEL_ * E_ * 2;
  u16* qlow = (u16*)(ws + off); off += (size_t)T_ * QR_ * 2;
  u16* kc = (u16*)(ws + off); off += (size_t)T_ * KR_ * 2;
  u16* ln_q = (u16*)(ws + off); off += (size_t)T_ * E_ * 2;   // reused as y
  u16* ln_kv = (u16*)(ws + off); off += (size_t)T_ * E_ * 2;  // reused as q_r
  u16* k_rb = (u16*)(ws + off); off += (size_t)T_ * E_ * 2;   // first v_nat, then k_r
  u16* v_tb = (u16*)(ws + off); off += (size_t)T_ * E_ * 2;
  u16* y = ln_q;
  u16* q_rb = ln_kv;
  u16* v_nat = k_rb;  // alias: consumed by k_vtr before k-GEMM writes k_r

  // LN + fused RoPE-table build (blocks 0..255 also fill cos_t/sin_t)
  k_ln<<<dim3(T_), dim3(256), 0, stream>>>(x, g_q, g_kv, ln_q, ln_kv, cos_t, sin_t);

  // all five weight transposes in one launch (8960 blocks)
  k_transp_all<<<dim3(8960), dim3(256), 0, stream>>>(
      w_qa, w_qb, w_kvb, w_o, w_kva, wqa_t, wqb_t, wkvb_t, wo_t, wsel_t);

  EpiP ep{};

  // q_low = ln_q @ w_qa  (M=4096, N=64, K=2048) -- BM=64: 64 blocks
  ep = EpiP{}; ep.obf = qlow;
  k_gemm<64, 64, 0><<<dim3(1, T_ / 64), dim3(256), 0, stream>>>(ln_q, wqa_t, T_, QR_, E_, ep);

  // kv = ln_kv @ w_kva_sel  (M=4096, N=2176, K=2048) -> kc + v natural (coalesced)
  ep = EpiP{}; ep.kc = kc; ep.vt = v_nat;
  k_gemm<128, 128, 2><<<dim3(NSEL_ / 128, T_ / 128), dim3(256), 0, stream>>>(ln_kv, wsel_t, T_, NSEL_, E_, ep);

  // q = q_low @ w_qb + RoPE  (M=4096, N=2048, K=64) -> q_r
  ep = EpiP{}; ep.qk = q_rb; ep.cost = cos_t; ep.sint = sin_t;
  k_gemm<128, 128, 3><<<dim3(E_ / 128, T_ / 128), dim3(256), 0, stream>>>(qlow, wqb_t, T_, E_, QR_, ep);

  // v^T: per-batch 2048x2048 bf16 transpose (v_nat -> v_tb), 64x64 ushort4 tiles
  k_vtr<<<dim3(32, 64), dim3(256), 0, stream>>>(v_nat, v_tb);

  // k = kc @ w_kvb + RoPE  (M=4096, N=2048, K=128) -> k_r
  ep = EpiP{}; ep.qk = k_rb; ep.cost = cos_t; ep.sint = sin_t;
  k_gemm<128, 128, 3><<<dim3(E_ / 128, T_ / 128), dim3(256), 0, stream>>>(kc, wkvb_t, T_, E_, KR_, ep);

  // attention -> y (overwrites ln_q). 1024 blocks x 4 waves, split-K + LPT refill.
  k_attn<<<dim3(1024), dim3(256), 0, stream>>>(q_rb, k_rb, v_tb, y);

  // out = y @ w_o  (M=4096, N=2048, K=2048), fp32
  ep = EpiP{}; ep.of32 = out;
  k_gemm<128, 128, 1><<<dim3(E_ / 128, T_ / 128), dim3(256), 0, stream>>>(y, wo_t, T_, E_, E_, ep);
}

// Round 26
// 249.099 us; speedup vs baseline: 1.4033x; 1.0008x over previous
//
#include <hip/hip_runtime.h>
#include <cstdint>
#include <cstddef>

typedef unsigned short u16;
typedef __attribute__((ext_vector_type(8))) __bf16 bf16x8;
typedef __attribute__((ext_vector_type(4))) float f32x4;
typedef __attribute__((ext_vector_type(16))) float f32x16;
typedef __attribute__((ext_vector_type(4))) unsigned u32x4;

#define E_ 2048
#define H_ 16
#define D_ 128
#define QR_ 64
#define KR_ 128
#define S_ 2048
#define B_ 2
#define T_ 4096
#define NSEL_ 2176
#define EPS_ 1e-5f
#define SCALE_ 0.08838834764831845f
#define SCL2_ 0.12751743f  // SCALE_ * log2(e); softmax in exp2 domain

typedef __attribute__((address_space(1))) const void gvoid;
typedef __attribute__((address_space(3))) void lvoid;

__device__ __forceinline__ u16 f2bf(float f) {
  unsigned u = __float_as_uint(f);
  unsigned r = (u + 0x7FFFu + ((u >> 16) & 1u)) >> 16;
  return (u16)r;
}

// ---------------- dual LayerNorm (+ fused RoPE table build in blocks 0..255) --------
__global__ __launch_bounds__(256) void k_ln(
    const float* __restrict__ x, const float* __restrict__ gq,
    const float* __restrict__ gkv, u16* __restrict__ lnq, u16* __restrict__ lnkv,
    float* __restrict__ cos_t, float* __restrict__ sin_t) {
  if (blockIdx.x < (S_ * 32) / 256) {  // fused k_rope_tables (same index math)
    int idx = blockIdx.x * 256 + threadIdx.x;
    int t = idx >> 5, j = idx & 31;
    float inv = powf(10000.0f, -(float)j / 32.0f);
    float a = (float)t * inv;
    cos_t[idx] = cosf(a);
    sin_t[idx] = sinf(a);
  }
  int row = blockIdx.x;
  const float* xr = x + (size_t)row * E_;
  int base = threadIdx.x * 8;
  float4 v0 = *(const float4*)(xr + base);
  float4 v1 = *(const float4*)(xr + base + 4);
  float xv[8] = {v0.x, v0.y, v0.z, v0.w, v1.x, v1.y, v1.z, v1.w};
  float s0 = 0.f, s1 = 0.f;
#pragma unroll
  for (int i = 0; i < 8; i++) { s0 += xv[i]; s1 += xv[i] * xv[i]; }
  for (int off = 32; off > 0; off >>= 1) {
    s0 += __shfl_down(s0, off);
    s1 += __shfl_down(s1, off);
  }
  __shared__ float red[2][4];
  int wid = threadIdx.x >> 6, lane = threadIdx.x & 63;
  if (lane == 0) { red[0][wid] = s0; red[1][wid] = s1; }
  __syncthreads();
  s0 = red[0][0] + red[0][1] + red[0][2] + red[0][3];
  s1 = red[1][0] + red[1][1] + red[1][2] + red[1][3];
  float mu = s0 * (1.0f / E_);
  float var = s1 * (1.0f / E_) - mu * mu;
  float rs = rsqrtf(var + EPS_);
  u16 oq[8], okv[8];
#pragma unroll
  for (int i = 0; i < 8; i++) {
    float nv = (xv[i] - mu) * rs;
    oq[i] = f2bf(nv * gq[base + i]);
    okv[i] = f2bf(nv * gkv[base + i]);
  }
  *(ushort4*)(lnq + (size_t)row * E_ + base) = make_ushort4(oq[0], oq[1], oq[2], oq[3]);
  *(ushort4*)(lnq + (size_t)row * E_ + base + 4) = make_ushort4(oq[4], oq[5], oq[6], oq[7]);
  *(ushort4*)(lnkv + (size_t)row * E_ + base) = make_ushort4(okv[0], okv[1], okv[2], okv[3]);
  *(ushort4*)(lnkv + (size_t)row * E_ + base + 4) = make_ushort4(okv[4], okv[5], okv[6], okv[7]);
}

// ---------------- ALL weight transposes f32 -> bf16 (out[N'][K]) in ONE launch ------
// Flat block decode reproduces each original (gridDim, blockIdx) exactly:
//   [0,128)      w_qb  : grid (64,2)   K=QR,  Nin=E
//   [128,256)    w_qa  : grid (2,64)   K=E,   Nin=QR
//   [256,512)    w_kvb : grid (64,4)   K=KR,  Nin=E
//   [512,4608)   w_o   : grid (64,64)  K=E,   Nin=E
//   [4608,8960)  w_kva : grid (68,64)  K=E,   Nin=128+H*2*D, SEL column remap
// Vectorized: float4 loads (16B/lane), ushort4 stores (8B/lane) via padded LDS.
__global__ __launch_bounds__(256) void k_transp_all(
    const float* __restrict__ w_qa, const float* __restrict__ w_qb,
    const float* __restrict__ w_kvb, const float* __restrict__ w_o,
    const float* __restrict__ w_kva,
    u16* __restrict__ wqa_t, u16* __restrict__ wqb_t, u16* __restrict__ wkvb_t,
    u16* __restrict__ wo_t, u16* __restrict__ wsel_t) {
  __shared__ float t[32][33];
  int f = blockIdx.x;
  const float* in;
  u16* out;
  int K, Nin, bx, by;
  bool sel = false;
  if (f < 128) {
    in = w_qb; out = wqb_t; K = QR_; Nin = E_; bx = f % 64; by = f / 64;
  } else if (f < 256) {
    f -= 128;
    in = w_qa; out = wqa_t; K = E_; Nin = QR_; bx = f % 2; by = f / 2;
  } else if (f < 512) {
    f -= 256;
    in = w_kvb; out = wkvb_t; K = KR_; Nin = E_; bx = f % 64; by = f / 64;
  } else if (f < 4608) {
    f -= 512;
    in = w_o; out = wo_t; K = E_; Nin = E_; bx = f % 64; by = f / 64;
  } else {
    f -= 4608;
    in = w_kva; out = wsel_t; K = E_; Nin = 128 + H_ * 2 * D_; sel = true;
    bx = f % 68; by = f / 68;
  }
  int orb = bx * 32;
  int icb;
  if (sel) {
    icb = (orb < 128) ? orb : 128 + ((orb - 128) >> 7) * 256 + ((orb - 128) & 127);
  } else {
    icb = orb;
  }
  int kb = by * 32;
  int r = threadIdx.x >> 3, q = threadIdx.x & 7;
  // load: t[r][4q+j] = in[kb+r][icb+4q+j]  (float4, 16B aligned)
  float4 lv = *(const float4*)&in[(size_t)(kb + r) * Nin + icb + q * 4];
  t[r][q * 4 + 0] = lv.x;
  t[r][q * 4 + 1] = lv.y;
  t[r][q * 4 + 2] = lv.z;
  t[r][q * 4 + 3] = lv.w;
  __syncthreads();
  // store: out[orb+c][kb+4q+j] = t[4q+j][c]  (ushort4, 8B aligned)
  int c = r;
  ushort4 sv;
  sv.x = f2bf(t[q * 4 + 0][c]);
  sv.y = f2bf(t[q * 4 + 1][c]);
  sv.z = f2bf(t[q * 4 + 2][c]);
  sv.w = f2bf(t[q * 4 + 3][c]);
  *(ushort4*)&out[(size_t)(orb + c) * K + kb + q * 4] = sv;
}

// ---------------- bf16 per-batch 2048x2048 transpose: v_nat -> v_t (vectorized) -----
// 64x64 tiles, ushort4 (8B) on both sides through padded LDS. vt[c][s] = vn[s][c].
__global__ __launch_bounds__(256) void k_vtr(
    const u16* __restrict__ vn, u16* __restrict__ vt) {
  __shared__ u16 t[64][68];
  int c0 = blockIdx.x * 64;
  int b = blockIdx.y >> 5;
  int s0 = (blockIdx.y & 31) * 64;
#pragma unroll
  for (int i = 0; i < 4; i++) {
    int flat = threadIdx.x + i * 256;
    int r = flat >> 4, q = flat & 15;
    ushort4 v = *(const ushort4*)&vn[((size_t)(b * 2048 + s0 + r)) * 2048 + c0 + q * 4];
    t[r][q * 4 + 0] = v.x;
    t[r][q * 4 + 1] = v.y;
    t[r][q * 4 + 2] = v.z;
    t[r][q * 4 + 3] = v.w;
  }
  __syncthreads();
#pragma unroll
  for (int i = 0; i < 4; i++) {
    int flat = threadIdx.x + i * 256;
    int c = flat >> 4, q = flat & 15;
    ushort4 v;
    v.x = t[q * 4 + 0][c];
    v.y = t[q * 4 + 1][c];
    v.z = t[q * 4 + 2][c];
    v.w = t[q * 4 + 3][c];
    *(ushort4*)&vt[((size_t)(b * 2048 + c0 + c)) * 2048 + s0 + q * 4] = v;
  }
}

// ---------------- GEMM: C = A[M][K] x Bt[N][K]^T  (T3-min single-barrier, XCD swz) --
struct EpiP {
  float* of32;
  u16* obf;
  u16* kc;
  u16* vt;
  u16* qk;
  const float* cost;
  const float* sint;
};

template <int BM, int BN, int EPI>
__global__ __launch_bounds__(256, 3) void k_gemm(
    const u16* __restrict__ A, const u16* __restrict__ Bt,
    int M, int N, int K, EpiP ep) {
  constexpr int WM = BM / 2;
  constexpr int MI = WM / 16;
  constexpr int WN = BN / 2;
  constexpr int NI = WN / 16;
  __shared__ alignas(16) u16 lsA[2][BM * 32];
  __shared__ alignas(16) u16 lsB[2][BN * 32];
  int tid = threadIdx.x, lane = tid & 63, wid = tid >> 6;
  int wr = wid >> 1, wc = wid & 1;
  // T1: bijective XCD swizzle (all launches have nwg % 8 == 0)
  int gx = gridDim.x;
  int nwg = gx * gridDim.y;
  int flat = blockIdx.y * gx + blockIdx.x;
  int cpx = nwg >> 3;
  int swz = (flat & 7) * cpx + (flat >> 3);
  int bm = swz / gx, bn = swz % gx;
  f32x4 zero4 = {0.f, 0.f, 0.f, 0.f};
  f32x4 acc[MI][NI];
#pragma unroll
  for (int m = 0; m < MI; m++)
#pragma unroll
    for (int n = 0; n < NI; n++) acc[m][n] = zero4;
  const int nkt = K >> 5;
  const u16* Ab = A + (size_t)bm * BM * K;
  const u16* Bb = Bt + (size_t)bn * BN * K;
  int arow = tid >> 2, acol8 = (tid & 3) * 8;
  int lg = lane >> 4, li = lane & 15;

  auto stage = [&](int buf, int kt) {
    int k0 = kt * 32;
#pragma unroll
    for (int c = 0; c < BM / 64; c++) {
      int row = c * 64 + arow;
      __builtin_amdgcn_global_load_lds(
          (gvoid*)(Ab + (size_t)row * K + k0 + acol8),
          (lvoid*)(&lsA[buf][row * 32 + acol8]), 16, 0, 0);
    }
#pragma unroll
    for (int c = 0; c < BN / 64; c++) {
      int row = c * 64 + arow;
      __builtin_amdgcn_global_load_lds(
          (gvoid*)(Bb + (size_t)row * K + k0 + acol8),
          (lvoid*)(&lsB[buf][row * 32 + acol8]), 16, 0, 0);
    }
  };

  // T3-min prologue: tile0 staged + landed before loop
  stage(0, 0);
  asm volatile("s_waitcnt vmcnt(0)" ::: "memory");
  __builtin_amdgcn_s_barrier();
  asm volatile("" ::: "memory");
  for (int kt = 0; kt < nkt; ++kt) {
    int cur = kt & 1;
    if (kt + 1 < nkt) stage(cur ^ 1, kt + 1);  // issue next-tile loads FIRST
    bf16x8 af[MI], bfr[NI];
#pragma unroll
    for (int m = 0; m < MI; m++)
      af[m] = *reinterpret_cast<const bf16x8*>(&lsA[cur][(wr * WM + m * 16 + li) * 32 + lg * 8]);
#pragma unroll
    for (int n = 0; n < NI; n++)
      bfr[n] = *reinterpret_cast<const bf16x8*>(&lsB[cur][(wc * WN + n * 16 + li) * 32 + lg * 8]);
#pragma unroll
    for (int m = 0; m < MI; m++)
#pragma unroll
      for (int n = 0; n < NI; n++)
        acc[m][n] = __builtin_amdgcn_mfma_f32_16x16x32_bf16(af[m], bfr[n], acc[m][n], 0, 0, 0);
    // ONE vmcnt(0)+barrier per K-step: next tile landed (flew under compute),
    // and read-before-overwrite is ordered by the same barrier.
    asm volatile("s_waitcnt vmcnt(0)" ::: "memory");
    __builtin_amdgcn_s_barrier();
    asm volatile("" ::: "memory");
  }
  // epilogue
#pragma unroll
  for (int m = 0; m < MI; m++) {
#pragma unroll
    for (int n = 0; n < NI; n++) {
      int col = bn * BN + wc * WN + n * 16 + li;
#pragma unroll
      for (int r = 0; r < 4; r++) {
        int row = bm * BM + wr * WM + m * 16 + lg * 4 + r;
        float val = acc[m][n][r];
        if constexpr (EPI == 0) {
          ep.obf[(size_t)row * 64 + col] = f2bf(val);
        } else if constexpr (EPI == 1) {
          ep.of32[(size_t)row * E_ + col] = val;
        } else if constexpr (EPI == 2) {
          if (col < KR_) {
            ep.kc[(size_t)row * KR_ + col] = f2bf(val);
          } else {
            ep.vt[(size_t)row * 2048 + (col - KR_)] = f2bf(val);  // coalesced natural v
          }
        } else {  // EPI 3: RoPE + per-head store
          int h = col >> 7, dl = col & 127;
          int b = row >> 11, sp = row & 2047;
          float outv;
          if (dl < 64) {
            float pv = acc[m][n ^ 2][r];
            int j = dl & 31;
            float c = ep.cost[sp * 32 + j];
            float s = ep.sint[sp * 32 + j];
            float rot = (dl < 32) ? -pv : pv;
            outv = val * c + rot * s;
          } else {
            outv = val;
          }
          ep.qk[((size_t)(b * H_ + h) * S_ + sp) * D_ + dl] = f2bf(outv);
        }
      }
    }
  }
}

// ---------------- causal flash attention (split-K blocks + LPT refill) ----------------
// Block = (bh, 64-row q-tile j), 4 waves: waves {0,1} = subtiles 0,1 sweeping keys
// [0, 32(j+1)); waves {2,3} = same subtiles sweeping [32(j+1), 64(j+1)). Every wave
// computes every iteration (n = j+1 for all waves). Partials merged through LDS at the
// end (flash combine). 1024 blocks, heavy-j first with 2 resident/CU -> LPT refill.
__global__ __launch_bounds__(256, 2) void k_attn(
    const u16* __restrict__ q_r, const u16* __restrict__ k_r,
    const u16* __restrict__ v_t, u16* __restrict__ y) {
  __shared__ alignas(16) u16 Ks[2][2][32 * 128];  // [dbuf][grp] K tile 32x128
  __shared__ alignas(16) u16 Vs[2][2][64 * 64];   // [dbuf][grp] packed V^T
  __shared__ float Ml[2][2][32];
  int tid = threadIdx.x, lane = tid & 63, wid = tid >> 6;  // wid 0..3
  int id = blockIdx.x;
  int bh = ((id & 7) << 2) | ((id >> 3) & 3);  // XCD-pinned: 4 bh per XCD
  int j = 31 - (id >> 5);                      // heavy tiles dispatched first
  int w2 = wid & 1, grp = wid >> 1;
  int b = bh >> 4, h = bh & 15;
  int li = lane & 31, hi = lane >> 5;
  int qb = 64 * j + w2 * 32;
  int qrow = qb + li;
  int n = j + 1;
  int kg_base = grp * 32 * n;
  const u16* qbase = q_r + (size_t)bh * S_ * D_;
  const u16* kbase = k_r + (size_t)bh * S_ * D_;
  const u16* vbase = v_t + (size_t)bh * D_ * S_;

  bf16x8 aq[8];
#pragma unroll
  for (int step = 0; step < 8; step++)
    aq[step] = *(const bf16x8*)&qbase[(size_t)qrow * D_ + step * 16 + hi * 8];

  f32x16 o[4];
#pragma unroll
  for (int dt = 0; dt < 4; dt++)
#pragma unroll
    for (int r = 0; r < 16; r++) o[dt][r] = 0.f;
  float mreg = -1e30f, lreg = 0.f;

  int kr_l = w2 * 16 + (lane >> 4);  // + i*4
  int kc_l = (lane & 15) * 8;
  int kswz = (li & 7) << 4;

  auto stage = [&](int nb, int p) {
    int kg0 = kg_base + p * 32;
    u16* Kst = &Ks[nb][grp][0];
    u16* Vst = &Vs[nb][grp][0];
#pragma unroll
    for (int i = 0; i < 4; i++) {
      int r = kr_l + i * 4;
      __builtin_amdgcn_global_load_lds(
          (gvoid*)(kbase + (size_t)(kg0 + r) * D_ + (kc_l ^ ((r & 7) << 3))),
          (lvoid*)(&Kst[r * 128 + kc_l]), 16, 0, 0);
    }
#pragma unroll
    for (int i = 0; i < 4; i++) {
      int r = w2 * 32 + i * 8 + (lane >> 3);
      int ss = lane & 7;
      int s = ss ^ (r & 7);
      int d = ((s >> 2) << 6) + r;        // slot half selects d or d+64
      int kk = kg0 + (s & 3) * 8;
      __builtin_amdgcn_global_load_lds(
          (gvoid*)(vbase + (size_t)d * S_ + kk),
          (lvoid*)(&Vst[r * 64 + ss * 8]), 16, 0, 0);
    }
  };

  stage(0, 0);
  int cbuf = 0;

  for (int p = 0; p < n; ++p) {
    int kg0 = kg_base + p * 32;
    asm volatile("s_waitcnt vmcnt(0)" ::: "memory");  // my loads landed (flew under compute)
    __builtin_amdgcn_s_barrier();                      // everyone's loads landed
    asm volatile("" ::: "memory");                     // fence only; scheduling stays free
    if (p + 1 < n) stage(cbuf ^ 1, p + 1);             // overlaps this iter's compute
    if (kg0 <= qb + 31) {
      bool domask = (kg0 + 31 > qb);
      const char* Kc = (const char*)&Ks[cbuf][grp][0];
      const char* Vc = (const char*)&Vs[cbuf][grp][0];
      // ---- QK^T (swapped), 32 keys; accumulator chain split in two (latency) ----
      bf16x8 kf[8];
#pragma unroll
      for (int step = 0; step < 8; step++)
        kf[step] = *(const bf16x8*)(Kc + li * 256 + ((step * 32 + hi * 16) ^ kswz));
      f32x16 c0, c1;
#pragma unroll
      for (int r = 0; r < 16; r++) { c0[r] = 0.f; c1[r] = 0.f; }
      __builtin_amdgcn_s_setprio(1);
#pragma unroll
      for (int step = 0; step < 4; step++) {
        c0 = __builtin_amdgcn_mfma_f32_32x32x16_bf16(kf[step], aq[step], c0, 0, 0, 0);
        c1 = __builtin_amdgcn_mfma_f32_32x32x16_bf16(kf[step + 4], aq[step + 4], c1, 0, 0, 0);
      }
      __builtin_amdgcn_s_setprio(0);
      float ps[16];
#pragma unroll
      for (int r = 0; r < 16; r++) ps[r] = (c0[r] + c1[r]) * SCL2_;  // exp2 domain
      if (domask) {  // wave-uniform boundary branch
#pragma unroll
        for (int r = 0; r < 16; r++) {
          int k = kg0 + (r & 3) + 8 * (r >> 2) + 4 * hi;
          if (k > qrow) ps[r] = -1e30f;
        }
      }
      // ---- in-register softmax (one q row per lane) ----
      float t8[8];
#pragma unroll
      for (int r = 0; r < 8; r++) t8[r] = fmaxf(ps[r], ps[r + 8]);
#pragma unroll
      for (int r = 0; r < 4; r++) t8[r] = fmaxf(t8[r], t8[r + 4]);
      float mt = fmaxf(fmaxf(t8[0], t8[1]), fmaxf(t8[2], t8[3]));
      mt = fmaxf(mt, __shfl_xor(mt, 32));
      // T13 defer-max
      if (!__all(mt <= mreg + 8.f)) {
        float mn = fmaxf(mreg, mt);
        float al = __builtin_amdgcn_exp2f(mreg - mn);
        mreg = mn;
        lreg *= al;
#pragma unroll
        for (int dt = 0; dt < 4; dt++)
#pragma unroll
          for (int r = 0; r < 16; r++) o[dt][r] *= al;
      }
#pragma unroll
      for (int r = 0; r < 16; r++) ps[r] = __builtin_amdgcn_exp2f(ps[r] - mreg);
      float s8[8];
#pragma unroll
      for (int r = 0; r < 8; r++) s8[r] = ps[r] + ps[r + 8];
#pragma unroll
      for (int r = 0; r < 4; r++) s8[r] = s8[r] + s8[r + 4];
      float rs = (s8[0] + s8[1]) + (s8[2] + s8[3]);
      rs += __shfl_xor(rs, 32);
      lreg += rs;
      // ---- PV: B-fragment in-register via cvt_pk + permlane32_swap (T12) ----
#pragma unroll
      for (int ks = 0; ks < 2; ks++) {
        const int bix = ks * 8;
        unsigned P0, P1, P2, P3;
        asm("v_cvt_pk_bf16_f32 %0, %1, %2" : "=v"(P0) : "v"(ps[bix + 0]), "v"(ps[bix + 1]));
        asm("v_cvt_pk_bf16_f32 %0, %1, %2" : "=v"(P1) : "v"(ps[bix + 2]), "v"(ps[bix + 3]));
        asm("v_cvt_pk_bf16_f32 %0, %1, %2" : "=v"(P2) : "v"(ps[bix + 4]), "v"(ps[bix + 5]));
        asm("v_cvt_pk_bf16_f32 %0, %1, %2" : "=v"(P3) : "v"(ps[bix + 6]), "v"(ps[bix + 7]));
        asm("v_permlane32_swap_b32 %0, %1" : "+v"(P0), "+v"(P2));
        asm("v_permlane32_swap_b32 %0, %1" : "+v"(P1), "+v"(P3));
        bf16x8 bp = __builtin_bit_cast(bf16x8, (u32x4){P0, P1, P2, P3});
        bf16x8 vf[4];
#pragma unroll
        for (int dt = 0; dt < 4; dt++) {
          int row = ((dt & 1) << 5) + li;
          vf[dt] = *(const bf16x8*)(Vc + row * 128 +
                                    ((((dt >> 1) * 4 + ks * 2 + hi) * 16) ^ ((row & 7) << 4)));
        }
        __builtin_amdgcn_s_setprio(1);
#pragma unroll
        for (int dt = 0; dt < 4; dt++)
          o[dt] = __builtin_amdgcn_mfma_f32_32x32x16_bf16(vf[dt], bp, o[dt], 0, 0, 0);
        __builtin_amdgcn_s_setprio(0);
      }
    }
    cbuf ^= 1;
  }
  // ---- merge partials: grp0 writes, grp1 combines + stores ----
  __syncthreads();
  float* fb = (float*)&Ks[0][0][0] + w2 * 4096;  // 16 KB region per writer wave
  if (grp == 0) {
#pragma unroll
    for (int k = 0; k < 64; ++k) fb[k * 64 + lane] = o[k >> 4][k & 15];
    if (lane < 32) {
      Ml[w2][0][li] = mreg;
      Ml[w2][1][li] = lreg;
    }
  }
  __syncthreads();
  if (grp == 1) {
    float m1 = Ml[w2][0][li], l1 = Ml[w2][1][li];
    float m = fmaxf(mreg, m1);
    float s2 = __builtin_amdgcn_exp2f(mreg - m);
    float s1 = __builtin_amdgcn_exp2f(m1 - m);
    float lsum = lreg * s2 + l1 * s1;
    float rl = 1.0f / lsum;
    u16* yrow = y + ((size_t)(b * S_ + qrow)) * E_ + h * D_;
#pragma unroll
    for (int dt = 0; dt < 4; dt++) {
#pragma unroll
      for (int g2 = 0; g2 < 4; g2++) {
        int d = dt * 32 + 8 * g2 + 4 * hi;
        ushort4 sv;
        float v0 = (o[dt][4 * g2 + 0] * s2 + fb[(dt * 16 + 4 * g2 + 0) * 64 + lane] * s1) * rl;
        float v1 = (o[dt][4 * g2 + 1] * s2 + fb[(dt * 16 + 4 * g2 + 1) * 64 + lane] * s1) * rl;
        float v2 = (o[dt][4 * g2 + 2] * s2 + fb[(dt * 16 + 4 * g2 + 2) * 64 + lane] * s1) * rl;
        float v3 = (o[dt][4 * g2 + 3] * s2 + fb[(dt * 16 + 4 * g2 + 3) * 64 + lane] * s1) * rl;
        sv.x = f2bf(v0);
        sv.y = f2bf(v1);
        sv.z = f2bf(v2);
        sv.w = f2bf(v3);
        *(ushort4*)(yrow + d) = sv;
      }
    }
  }
}

// ---------------- host ----------------
extern "C" void kernel_launch(void* const* d_in, const int* in_sizes, int n_in,
                              void* d_out, int out_size, void* d_ws, size_t ws_size,
                              hipStream_t stream) {
  const float* x = (const float*)d_in[0];
  const float* g_q = (const float*)d_in[1];
  const float* g_kv = (const float*)d_in[2];
  const float* w_qa = (const float*)d_in[3];
  const float* w_qb = (const float*)d_in[4];
  const float* w_kva = (const float*)d_in[5];
  const float* w_kvb = (const float*)d_in[6];
  const float* w_o = (const float*)d_in[7];
  float* out = (float*)d_out;
  char* ws = (char*)d_ws;

  size_t off = 0;
  float* cos_t = (float*)(ws + off); off += (size_t)S_ * 32 * 4;
  float* sin_t = (float*)(ws + off); off += (size_t)S_ * 32 * 4;
  u16* wqa_t = (u16*)(ws + off); off += (size_t)QR_ * E_ * 2;
  u16* wqb_t = (u16*)(ws + off); off += (size_t)E_ * QR_ * 2;
  u16* wkvb_t = (u16*)(ws + off); off += (size_t)E_ * KR_ * 2;
  u16* wo_t = (u16*)(ws + off); off += (size_t)E_ * E_ * 2;
  u16* wsel_t = (u16*)(ws + off); off += (size_t)NSEL_ * E_ * 2;
  u16* qlow = (u16*)(ws + off); off += (size_t)T_ * QR_ * 2;
  u16* kc = (u16*)(ws + off); off += (size_t)T_ * KR_ * 2;
  u16* ln_q = (u16*)(ws + off); off += (size_t)T_ * E_ * 2;   // reused as y
  u16* ln_kv = (u16*)(ws + off); off += (size_t)T_ * E_ * 2;  // reused as q_r
  u16* k_rb = (u16*)(ws + off); off += (size_t)T_ * E_ * 2;   // first v_nat, then k_r
  u16* v_tb = (u16*)(ws + off); off += (size_t)T_ * E_ * 2;
  u16* y = ln_q;
  u16* q_rb = ln_kv;
  u16* v_nat = k_rb;  // alias: consumed by k_vtr before k-GEMM writes k_r

  // LN + fused RoPE-table build (blocks 0..255 also fill cos_t/sin_t)
  k_ln<<<dim3(T_), dim3(256), 0, stream>>>(x, g_q, g_kv, ln_q, ln_kv, cos_t, sin_t);

  // all five weight transposes in one launch (8960 blocks, vectorized)
  k_transp_all<<<dim3(8960), dim3(256), 0, stream>>>(
      w_qa, w_qb, w_kvb, w_o, w_kva, wqa_t, wqb_t, wkvb_t, wo_t, wsel_t);

  EpiP ep{};

  // q_low = ln_q @ w_qa  (M=4096, N=64, K=2048) -- BM=64: 64 blocks
  ep = EpiP{}; ep.obf = qlow;
  k_gemm<64, 64, 0><<<dim3(1, T_ / 64), dim3(256), 0, stream>>>(ln_q, wqa_t, T_, QR_, E_, ep);

  // kv = ln_kv @ w_kva_sel  (M=4096, N=2176, K=2048) -> kc + v natural (coalesced)
  ep = EpiP{}; ep.kc = kc; ep.vt = v_nat;
  k_gemm<128, 128, 2><<<dim3(NSEL_ / 128, T_ / 128), dim3(256), 0, stream>>>(ln_kv, wsel_t, T_, NSEL_, E_, ep);

  // q = q_low @ w_qb + RoPE  (M=4096, N=2048, K=64) -> q_r
  ep = EpiP{}; ep.qk = q_rb; ep.cost = cos_t; ep.sint = sin_t;
  k_gemm<128, 128, 3><<<dim3(E_ / 128, T_ / 128), dim3(256), 0, stream>>>(qlow, wqb_t, T_, E_, QR_, ep);

  // v^T: per-batch 2048x2048 bf16 transpose (v_nat -> v_tb), 64x64 ushort4 tiles
  k_vtr<<<dim3(32, 64), dim3(256), 0, stream>>>(v_nat, v_tb);

  // k = kc @ w_kvb + RoPE  (M=4096, N=2048, K=128) -> k_r
  ep = EpiP{}; ep.qk = k_rb; ep.cost = cos_t; ep.sint = sin_t;
  k_gemm<128, 128, 3><<<dim3(E_ / 128, T_ / 128), dim3(256), 0, stream>>>(kc, wkvb_t, T_, E_, KR_, ep);

  // attention -> y (overwrites ln_q). 1024 blocks x 4 waves, split-K + LPT refill.
  k_attn<<<dim3(1024), dim3(256), 0, stream>>>(q_rb, k_rb, v_tb, y);

  // out = y @ w_o  (M=4096, N=2048, K=2048), fp32
  ep = EpiP{}; ep.of32 = out;
  k_gemm<128, 128, 1><<<dim3(E_ / 128, T_ / 128), dim3(256), 0, stream>>>(y, wo_t, T_, E_, E_, ep);
}

// Round 27
// 233.881 us; speedup vs baseline: 1.4946x; 1.0651x over previous
//
#include <hip/hip_runtime.h>
#include <cstdint>
#include <cstddef>

typedef unsigned short u16;
typedef __attribute__((ext_vector_type(8))) __bf16 bf16x8;
typedef __attribute__((ext_vector_type(4))) float f32x4;
typedef __attribute__((ext_vector_type(16))) float f32x16;
typedef __attribute__((ext_vector_type(4))) unsigned u32x4;

#define E_ 2048
#define H_ 16
#define D_ 128
#define QR_ 64
#define KR_ 128
#define S_ 2048
#define B_ 2
#define T_ 4096
#define NSEL_ 2176
#define EPS_ 1e-5f
#define SCALE_ 0.08838834764831845f
#define SCL2_ 0.12751743f  // SCALE_ * log2(e); softmax in exp2 domain

typedef __attribute__((address_space(1))) const void gvoid;
typedef __attribute__((address_space(3))) void lvoid;

__device__ __forceinline__ u16 f2bf(float f) {
  unsigned u = __float_as_uint(f);
  unsigned r = (u + 0x7FFFu + ((u >> 16) & 1u)) >> 16;
  return (u16)r;
}

// ---------------- dual LayerNorm (+ fused RoPE table build in blocks 0..255) --------
__global__ __launch_bounds__(256) void k_ln(
    const float* __restrict__ x, const float* __restrict__ gq,
    const float* __restrict__ gkv, u16* __restrict__ lnq, u16* __restrict__ lnkv,
    float* __restrict__ cos_t, float* __restrict__ sin_t) {
  if (blockIdx.x < (S_ * 32) / 256) {  // fused k_rope_tables (same index math)
    int idx = blockIdx.x * 256 + threadIdx.x;
    int t = idx >> 5, j = idx & 31;
    float inv = powf(10000.0f, -(float)j / 32.0f);
    float a = (float)t * inv;
    cos_t[idx] = cosf(a);
    sin_t[idx] = sinf(a);
  }
  int row = blockIdx.x;
  const float* xr = x + (size_t)row * E_;
  int base = threadIdx.x * 8;
  float4 v0 = *(const float4*)(xr + base);
  float4 v1 = *(const float4*)(xr + base + 4);
  float xv[8] = {v0.x, v0.y, v0.z, v0.w, v1.x, v1.y, v1.z, v1.w};
  float s0 = 0.f, s1 = 0.f;
#pragma unroll
  for (int i = 0; i < 8; i++) { s0 += xv[i]; s1 += xv[i] * xv[i]; }
  for (int off = 32; off > 0; off >>= 1) {
    s0 += __shfl_down(s0, off);
    s1 += __shfl_down(s1, off);
  }
  __shared__ float red[2][4];
  int wid = threadIdx.x >> 6, lane = threadIdx.x & 63;
  if (lane == 0) { red[0][wid] = s0; red[1][wid] = s1; }
  __syncthreads();
  s0 = red[0][0] + red[0][1] + red[0][2] + red[0][3];
  s1 = red[1][0] + red[1][1] + red[1][2] + red[1][3];
  float mu = s0 * (1.0f / E_);
  float var = s1 * (1.0f / E_) - mu * mu;
  float rs = rsqrtf(var + EPS_);
  u16 oq[8], okv[8];
#pragma unroll
  for (int i = 0; i < 8; i++) {
    float nv = (xv[i] - mu) * rs;
    oq[i] = f2bf(nv * gq[base + i]);
    okv[i] = f2bf(nv * gkv[base + i]);
  }
  *(ushort4*)(lnq + (size_t)row * E_ + base) = make_ushort4(oq[0], oq[1], oq[2], oq[3]);
  *(ushort4*)(lnq + (size_t)row * E_ + base + 4) = make_ushort4(oq[4], oq[5], oq[6], oq[7]);
  *(ushort4*)(lnkv + (size_t)row * E_ + base) = make_ushort4(okv[0], okv[1], okv[2], okv[3]);
  *(ushort4*)(lnkv + (size_t)row * E_ + base + 4) = make_ushort4(okv[4], okv[5], okv[6], okv[7]);
}

// ---------------- ALL weight transposes f32 -> bf16 (out[N'][K]) in ONE launch ------
__global__ __launch_bounds__(256) void k_transp_all(
    const float* __restrict__ w_qa, const float* __restrict__ w_qb,
    const float* __restrict__ w_kvb, const float* __restrict__ w_o,
    const float* __restrict__ w_kva,
    u16* __restrict__ wqa_t, u16* __restrict__ wqb_t, u16* __restrict__ wkvb_t,
    u16* __restrict__ wo_t, u16* __restrict__ wsel_t) {
  __shared__ float t[32][33];
  int f = blockIdx.x;
  const float* in;
  u16* out;
  int K, Nin, bx, by;
  bool sel = false;
  if (f < 128) {
    in = w_qb; out = wqb_t; K = QR_; Nin = E_; bx = f % 64; by = f / 64;
  } else if (f < 256) {
    f -= 128;
    in = w_qa; out = wqa_t; K = E_; Nin = QR_; bx = f % 2; by = f / 2;
  } else if (f < 512) {
    f -= 256;
    in = w_kvb; out = wkvb_t; K = KR_; Nin = E_; bx = f % 64; by = f / 64;
  } else if (f < 4608) {
    f -= 512;
    in = w_o; out = wo_t; K = E_; Nin = E_; bx = f % 64; by = f / 64;
  } else {
    f -= 4608;
    in = w_kva; out = wsel_t; K = E_; Nin = 128 + H_ * 2 * D_; sel = true;
    bx = f % 68; by = f / 68;
  }
  int orb = bx * 32;
  int icb;
  if (sel) {
    icb = (orb < 128) ? orb : 128 + ((orb - 128) >> 7) * 256 + ((orb - 128) & 127);
  } else {
    icb = orb;
  }
  int kb = by * 32;
  int r = threadIdx.x >> 3, q = threadIdx.x & 7;
  float4 lv = *(const float4*)&in[(size_t)(kb + r) * Nin + icb + q * 4];
  t[r][q * 4 + 0] = lv.x;
  t[r][q * 4 + 1] = lv.y;
  t[r][q * 4 + 2] = lv.z;
  t[r][q * 4 + 3] = lv.w;
  __syncthreads();
  int c = r;
  ushort4 sv;
  sv.x = f2bf(t[q * 4 + 0][c]);
  sv.y = f2bf(t[q * 4 + 1][c]);
  sv.z = f2bf(t[q * 4 + 2][c]);
  sv.w = f2bf(t[q * 4 + 3][c]);
  *(ushort4*)&out[(size_t)(orb + c) * K + kb + q * 4] = sv;
}

// ---------------- bf16 per-batch 2048x2048 transpose: v_nat -> v_t (vectorized) -----
__global__ __launch_bounds__(256) void k_vtr(
    const u16* __restrict__ vn, u16* __restrict__ vt) {
  __shared__ u16 t[64][68];
  int c0 = blockIdx.x * 64;
  int b = blockIdx.y >> 5;
  int s0 = (blockIdx.y & 31) * 64;
#pragma unroll
  for (int i = 0; i < 4; i++) {
    int flat = threadIdx.x + i * 256;
    int r = flat >> 4, q = flat & 15;
    ushort4 v = *(const ushort4*)&vn[((size_t)(b * 2048 + s0 + r)) * 2048 + c0 + q * 4];
    t[r][q * 4 + 0] = v.x;
    t[r][q * 4 + 1] = v.y;
    t[r][q * 4 + 2] = v.z;
    t[r][q * 4 + 3] = v.w;
  }
  __syncthreads();
#pragma unroll
  for (int i = 0; i < 4; i++) {
    int flat = threadIdx.x + i * 256;
    int c = flat >> 4, q = flat & 15;
    ushort4 v;
    v.x = t[q * 4 + 0][c];
    v.y = t[q * 4 + 1][c];
    v.z = t[q * 4 + 2][c];
    v.w = t[q * 4 + 3][c];
    *(ushort4*)&vt[((size_t)(b * 2048 + c0 + c)) * 2048 + s0 + q * 4] = v;
  }
}

// ---------------- GEMM: C = A[M][K] x Bt[N][K]^T  (T3-min single-barrier, XCD swz) --
struct EpiP {
  float* of32;
  u16* obf;
  u16* kc;
  u16* vt;
  u16* qk;
  const float* cost;
  const float* sint;
};

template <int BM, int BN, int EPI>
__global__ __launch_bounds__(256, 3) void k_gemm(
    const u16* __restrict__ A, const u16* __restrict__ Bt,
    int M, int N, int K, EpiP ep) {
  constexpr int WM = BM / 2;
  constexpr int MI = WM / 16;
  constexpr int WN = BN / 2;
  constexpr int NI = WN / 16;
  __shared__ alignas(16) u16 lsA[2][BM * 32];
  __shared__ alignas(16) u16 lsB[2][BN * 32];
  int tid = threadIdx.x, lane = tid & 63, wid = tid >> 6;
  int wr = wid >> 1, wc = wid & 1;
  // T1: bijective XCD swizzle (all launches have nwg % 8 == 0)
  int gx = gridDim.x;
  int nwg = gx * gridDim.y;
  int flat = blockIdx.y * gx + blockIdx.x;
  int cpx = nwg >> 3;
  int swz = (flat & 7) * cpx + (flat >> 3);
  int bm = swz / gx, bn = swz % gx;
  f32x4 zero4 = {0.f, 0.f, 0.f, 0.f};
  f32x4 acc[MI][NI];
#pragma unroll
  for (int m = 0; m < MI; m++)
#pragma unroll
    for (int n = 0; n < NI; n++) acc[m][n] = zero4;
  const int nkt = K >> 5;
  const u16* Ab = A + (size_t)bm * BM * K;
  const u16* Bb = Bt + (size_t)bn * BN * K;
  int arow = tid >> 2, acol8 = (tid & 3) * 8;
  int lg = lane >> 4, li = lane & 15;

  auto stage = [&](int buf, int kt) {
    int k0 = kt * 32;
#pragma unroll
    for (int c = 0; c < BM / 64; c++) {
      int row = c * 64 + arow;
      __builtin_amdgcn_global_load_lds(
          (gvoid*)(Ab + (size_t)row * K + k0 + acol8),
          (lvoid*)(&lsA[buf][row * 32 + acol8]), 16, 0, 0);
    }
#pragma unroll
    for (int c = 0; c < BN / 64; c++) {
      int row = c * 64 + arow;
      __builtin_amdgcn_global_load_lds(
          (gvoid*)(Bb + (size_t)row * K + k0 + acol8),
          (lvoid*)(&lsB[buf][row * 32 + acol8]), 16, 0, 0);
    }
  };

  // T3-min prologue: tile0 staged + landed before loop
  stage(0, 0);
  asm volatile("s_waitcnt vmcnt(0)" ::: "memory");
  __builtin_amdgcn_s_barrier();
  asm volatile("" ::: "memory");
  for (int kt = 0; kt < nkt; ++kt) {
    int cur = kt & 1;
    if (kt + 1 < nkt) stage(cur ^ 1, kt + 1);  // issue next-tile loads FIRST
    bf16x8 af[MI], bfr[NI];
#pragma unroll
    for (int m = 0; m < MI; m++)
      af[m] = *reinterpret_cast<const bf16x8*>(&lsA[cur][(wr * WM + m * 16 + li) * 32 + lg * 8]);
#pragma unroll
    for (int n = 0; n < NI; n++)
      bfr[n] = *reinterpret_cast<const bf16x8*>(&lsB[cur][(wc * WN + n * 16 + li) * 32 + lg * 8]);
#pragma unroll
    for (int m = 0; m < MI; m++)
#pragma unroll
      for (int n = 0; n < NI; n++)
        acc[m][n] = __builtin_amdgcn_mfma_f32_16x16x32_bf16(af[m], bfr[n], acc[m][n], 0, 0, 0);
    // ONE vmcnt(0)+barrier per K-step
    asm volatile("s_waitcnt vmcnt(0)" ::: "memory");
    __builtin_amdgcn_s_barrier();
    asm volatile("" ::: "memory");
  }
  // epilogue
#pragma unroll
  for (int m = 0; m < MI; m++) {
#pragma unroll
    for (int n = 0; n < NI; n++) {
      int col = bn * BN + wc * WN + n * 16 + li;
#pragma unroll
      for (int r = 0; r < 4; r++) {
        int row = bm * BM + wr * WM + m * 16 + lg * 4 + r;
        float val = acc[m][n][r];
        if constexpr (EPI == 0) {
          ep.obf[(size_t)row * 64 + col] = f2bf(val);
        } else if constexpr (EPI == 1) {
          ep.of32[(size_t)row * E_ + col] = val;
        } else if constexpr (EPI == 2) {
          if (col < KR_) {
            ep.kc[(size_t)row * KR_ + col] = f2bf(val);
          } else {
            ep.vt[(size_t)row * 2048 + (col - KR_)] = f2bf(val);  // coalesced natural v
          }
        } else {  // EPI 3: RoPE + per-head store
          int h = col >> 7, dl = col & 127;
          int b = row >> 11, sp = row & 2047;
          float outv;
          if (dl < 64) {
            float pv = acc[m][n ^ 2][r];
            int j = dl & 31;
            float c = ep.cost[sp * 32 + j];
            float s = ep.sint[sp * 32 + j];
            float rot = (dl < 32) ? -pv : pv;
            outv = val * c + rot * s;
          } else {
            outv = val;
          }
          ep.qk[((size_t)(b * H_ + h) * S_ + sp) * D_ + dl] = f2bf(outv);
        }
      }
    }
  }
}

// ---------------- merged RoPE GEMMs: q (K=64) + k (K=128) in one launch -------------
// blocks [0,512): q-half (A=qlow, Bt=wqb_t, out=q_r); [512,1024): k-half (A=kc,
// Bt=wkvb_t, out=k_r). Per-half XCD swizzle identical to the original 16x32 launches.
__global__ __launch_bounds__(256, 3) void k_gemm_rope2(
    const u16* __restrict__ Aq, const u16* __restrict__ Btq, u16* __restrict__ outq,
    const u16* __restrict__ Ak, const u16* __restrict__ Btk, u16* __restrict__ outk,
    const float* __restrict__ cost, const float* __restrict__ sint) {
  constexpr int BM = 128, BN = 128;
  constexpr int WM = 64, MI = 4, WN = 64, NI = 4;
  __shared__ alignas(16) u16 lsA[2][BM * 32];
  __shared__ alignas(16) u16 lsB[2][BN * 32];
  int tid = threadIdx.x, lane = tid & 63, wid = tid >> 6;
  int wr = wid >> 1, wc = wid & 1;
  int f = blockIdx.x;
  bool isK = f >= 512;
  int lf = f & 511;
  // per-half swizzle: nwg=512, gx=16, cpx=64 (matches original 2-D launch decode)
  int swz = (lf & 7) * 64 + (lf >> 3);
  int bm = swz >> 4, bn = swz & 15;
  const u16* A = isK ? Ak : Aq;
  const u16* Bt = isK ? Btk : Btq;
  u16* qk = isK ? outk : outq;
  const int K = isK ? KR_ : QR_;
  f32x4 zero4 = {0.f, 0.f, 0.f, 0.f};
  f32x4 acc[MI][NI];
#pragma unroll
  for (int m = 0; m < MI; m++)
#pragma unroll
    for (int n = 0; n < NI; n++) acc[m][n] = zero4;
  const int nkt = K >> 5;
  const u16* Ab = A + (size_t)bm * BM * K;
  const u16* Bb = Bt + (size_t)bn * BN * K;
  int arow = tid >> 2, acol8 = (tid & 3) * 8;
  int lg = lane >> 4, li = lane & 15;

  auto stage = [&](int buf, int kt) {
    int k0 = kt * 32;
#pragma unroll
    for (int c = 0; c < 2; c++) {
      int row = c * 64 + arow;
      __builtin_amdgcn_global_load_lds(
          (gvoid*)(Ab + (size_t)row * K + k0 + acol8),
          (lvoid*)(&lsA[buf][row * 32 + acol8]), 16, 0, 0);
    }
#pragma unroll
    for (int c = 0; c < 2; c++) {
      int row = c * 64 + arow;
      __builtin_amdgcn_global_load_lds(
          (gvoid*)(Bb + (size_t)row * K + k0 + acol8),
          (lvoid*)(&lsB[buf][row * 32 + acol8]), 16, 0, 0);
    }
  };

  stage(0, 0);
  asm volatile("s_waitcnt vmcnt(0)" ::: "memory");
  __builtin_amdgcn_s_barrier();
  asm volatile("" ::: "memory");
  for (int kt = 0; kt < nkt; ++kt) {
    int cur = kt & 1;
    if (kt + 1 < nkt) stage(cur ^ 1, kt + 1);
    bf16x8 af[MI], bfr[NI];
#pragma unroll
    for (int m = 0; m < MI; m++)
      af[m] = *reinterpret_cast<const bf16x8*>(&lsA[cur][(wr * WM + m * 16 + li) * 32 + lg * 8]);
#pragma unroll
    for (int n = 0; n < NI; n++)
      bfr[n] = *reinterpret_cast<const bf16x8*>(&lsB[cur][(wc * WN + n * 16 + li) * 32 + lg * 8]);
#pragma unroll
    for (int m = 0; m < MI; m++)
#pragma unroll
      for (int n = 0; n < NI; n++)
        acc[m][n] = __builtin_amdgcn_mfma_f32_16x16x32_bf16(af[m], bfr[n], acc[m][n], 0, 0, 0);
    asm volatile("s_waitcnt vmcnt(0)" ::: "memory");
    __builtin_amdgcn_s_barrier();
    asm volatile("" ::: "memory");
  }
  // EPI-3 epilogue (RoPE + per-head store), identical math
#pragma unroll
  for (int m = 0; m < MI; m++) {
#pragma unroll
    for (int n = 0; n < NI; n++) {
      int col = bn * BN + wc * WN + n * 16 + li;
#pragma unroll
      for (int r = 0; r < 4; r++) {
        int row = bm * BM + wr * WM + m * 16 + lg * 4 + r;
        float val = acc[m][n][r];
        int h = col >> 7, dl = col & 127;
        int b = row >> 11, sp = row & 2047;
        float outv;
        if (dl < 64) {
          float pv = acc[m][n ^ 2][r];
          int j = dl & 31;
          float c = cost[sp * 32 + j];
          float s = sint[sp * 32 + j];
          float rot = (dl < 32) ? -pv : pv;
          outv = val * c + rot * s;
        } else {
          outv = val;
        }
        qk[((size_t)(b * H_ + h) * S_ + sp) * D_ + dl] = f2bf(outv);
      }
    }
  }
}

// ---------------- causal flash attention (split-K blocks + LPT refill) ----------------
__global__ __launch_bounds__(256, 2) void k_attn(
    const u16* __restrict__ q_r, const u16* __restrict__ k_r,
    const u16* __restrict__ v_t, u16* __restrict__ y) {
  __shared__ alignas(16) u16 Ks[2][2][32 * 128];  // [dbuf][grp] K tile 32x128
  __shared__ alignas(16) u16 Vs[2][2][64 * 64];   // [dbuf][grp] packed V^T
  __shared__ float Ml[2][2][32];
  int tid = threadIdx.x, lane = tid & 63, wid = tid >> 6;  // wid 0..3
  int id = blockIdx.x;
  int bh = ((id & 7) << 2) | ((id >> 3) & 3);  // XCD-pinned: 4 bh per XCD
  int j = 31 - (id >> 5);                      // heavy tiles dispatched first
  int w2 = wid & 1, grp = wid >> 1;
  int b = bh >> 4, h = bh & 15;
  int li = lane & 31, hi = lane >> 5;
  int qb = 64 * j + w2 * 32;
  int qrow = qb + li;
  int n = j + 1;
  int kg_base = grp * 32 * n;
  const u16* qbase = q_r + (size_t)bh * S_ * D_;
  const u16* kbase = k_r + (size_t)bh * S_ * D_;
  const u16* vbase = v_t + (size_t)bh * D_ * S_;

  bf16x8 aq[8];
#pragma unroll
  for (int step = 0; step < 8; step++)
    aq[step] = *(const bf16x8*)&qbase[(size_t)qrow * D_ + step * 16 + hi * 8];

  f32x16 o[4];
#pragma unroll
  for (int dt = 0; dt < 4; dt++)
#pragma unroll
    for (int r = 0; r < 16; r++) o[dt][r] = 0.f;
  float mreg = -1e30f, lreg = 0.f;

  int kr_l = w2 * 16 + (lane >> 4);  // + i*4
  int kc_l = (lane & 15) * 8;
  int kswz = (li & 7) << 4;

  auto stage = [&](int nb, int p) {
    int kg0 = kg_base + p * 32;
    u16* Kst = &Ks[nb][grp][0];
    u16* Vst = &Vs[nb][grp][0];
#pragma unroll
    for (int i = 0; i < 4; i++) {
      int r = kr_l + i * 4;
      __builtin_amdgcn_global_load_lds(
          (gvoid*)(kbase + (size_t)(kg0 + r) * D_ + (kc_l ^ ((r & 7) << 3))),
          (lvoid*)(&Kst[r * 128 + kc_l]), 16, 0, 0);
    }
#pragma unroll
    for (int i = 0; i < 4; i++) {
      int r = w2 * 32 + i * 8 + (lane >> 3);
      int ss = lane & 7;
      int s = ss ^ (r & 7);
      int d = ((s >> 2) << 6) + r;        // slot half selects d or d+64
      int kk = kg0 + (s & 3) * 8;
      __builtin_amdgcn_global_load_lds(
          (gvoid*)(vbase + (size_t)d * S_ + kk),
          (lvoid*)(&Vst[r * 64 + ss * 8]), 16, 0, 0);
    }
  };

  stage(0, 0);
  int cbuf = 0;

  for (int p = 0; p < n; ++p) {
    int kg0 = kg_base + p * 32;
    asm volatile("s_waitcnt vmcnt(0)" ::: "memory");  // my loads landed (flew under compute)
    __builtin_amdgcn_s_barrier();                      // everyone's loads landed
    asm volatile("" ::: "memory");                     // fence only; scheduling stays free
    if (p + 1 < n) stage(cbuf ^ 1, p + 1);             // overlaps this iter's compute
    if (kg0 <= qb + 31) {
      bool domask = (kg0 + 31 > qb);
      const char* Kc = (const char*)&Ks[cbuf][grp][0];
      const char* Vc = (const char*)&Vs[cbuf][grp][0];
      // ---- QK^T (swapped), 32 keys; accumulator chain split in two (latency) ----
      bf16x8 kf[8];
#pragma unroll
      for (int step = 0; step < 8; step++)
        kf[step] = *(const bf16x8*)(Kc + li * 256 + ((step * 32 + hi * 16) ^ kswz));
      f32x16 c0, c1;
#pragma unroll
      for (int r = 0; r < 16; r++) { c0[r] = 0.f; c1[r] = 0.f; }
      __builtin_amdgcn_s_setprio(1);
#pragma unroll
      for (int step = 0; step < 4; step++) {
        c0 = __builtin_amdgcn_mfma_f32_32x32x16_bf16(kf[step], aq[step], c0, 0, 0, 0);
        c1 = __builtin_amdgcn_mfma_f32_32x32x16_bf16(kf[step + 4], aq[step + 4], c1, 0, 0, 0);
      }
      __builtin_amdgcn_s_setprio(0);
      float ps[16];
#pragma unroll
      for (int r = 0; r < 16; r++) ps[r] = (c0[r] + c1[r]) * SCL2_;  // exp2 domain
      if (domask) {  // wave-uniform boundary branch
#pragma unroll
        for (int r = 0; r < 16; r++) {
          int k = kg0 + (r & 3) + 8 * (r >> 2) + 4 * hi;
          if (k > qrow) ps[r] = -1e30f;
        }
      }
      // ---- in-register softmax (one q row per lane) ----
      float t8[8];
#pragma unroll
      for (int r = 0; r < 8; r++) t8[r] = fmaxf(ps[r], ps[r + 8]);
#pragma unroll
      for (int r = 0; r < 4; r++) t8[r] = fmaxf(t8[r], t8[r + 4]);
      float mt = fmaxf(fmaxf(t8[0], t8[1]), fmaxf(t8[2], t8[3]));
      mt = fmaxf(mt, __shfl_xor(mt, 32));
      // T13 defer-max
      if (!__all(mt <= mreg + 8.f)) {
        float mn = fmaxf(mreg, mt);
        float al = __builtin_amdgcn_exp2f(mreg - mn);
        mreg = mn;
        lreg *= al;
#pragma unroll
        for (int dt = 0; dt < 4; dt++)
#pragma unroll
          for (int r = 0; r < 16; r++) o[dt][r] *= al;
      }
#pragma unroll
      for (int r = 0; r < 16; r++) ps[r] = __builtin_amdgcn_exp2f(ps[r] - mreg);
      float s8[8];
#pragma unroll
      for (int r = 0; r < 8; r++) s8[r] = ps[r] + ps[r + 8];
#pragma unroll
      for (int r = 0; r < 4; r++) s8[r] = s8[r] + s8[r + 4];
      float rs = (s8[0] + s8[1]) + (s8[2] + s8[3]);
      rs += __shfl_xor(rs, 32);
      lreg += rs;
      // ---- PV: B-fragment in-register via cvt_pk + permlane32_swap (T12) ----
#pragma unroll
      for (int ks = 0; ks < 2; ks++) {
        const int bix = ks * 8;
        unsigned P0, P1, P2, P3;
        asm("v_cvt_pk_bf16_f32 %0, %1, %2" : "=v"(P0) : "v"(ps[bix + 0]), "v"(ps[bix + 1]));
        asm("v_cvt_pk_bf16_f32 %0, %1, %2" : "=v"(P1) : "v"(ps[bix + 2]), "v"(ps[bix + 3]));
        asm("v_cvt_pk_bf16_f32 %0, %1, %2" : "=v"(P2) : "v"(ps[bix + 4]), "v"(ps[bix + 5]));
        asm("v_cvt_pk_bf16_f32 %0, %1, %2" : "=v"(P3) : "v"(ps[bix + 6]), "v"(ps[bix + 7]));
        asm("v_permlane32_swap_b32 %0, %1" : "+v"(P0), "+v"(P2));
        asm("v_permlane32_swap_b32 %0, %1" : "+v"(P1), "+v"(P3));
        bf16x8 bp = __builtin_bit_cast(bf16x8, (u32x4){P0, P1, P2, P3});
        bf16x8 vf[4];
#pragma unroll
        for (int dt = 0; dt < 4; dt++) {
          int row = ((dt & 1) << 5) + li;
          vf[dt] = *(const bf16x8*)(Vc + row * 128 +
                                    ((((dt >> 1) * 4 + ks * 2 + hi) * 16) ^ ((row & 7) << 4)));
        }
        __builtin_amdgcn_s_setprio(1);
#pragma unroll
        for (int dt = 0; dt < 4; dt++)
          o[dt] = __builtin_amdgcn_mfma_f32_32x32x16_bf16(vf[dt], bp, o[dt], 0, 0, 0);
        __builtin_amdgcn_s_setprio(0);
      }
    }
    cbuf ^= 1;
  }
  // ---- merge partials: grp0 writes, grp1 combines + stores ----
  __syncthreads();
  float* fb = (float*)&Ks[0][0][0] + w2 * 4096;  // 16 KB region per writer wave
  if (grp == 0) {
#pragma unroll
    for (int k = 0; k < 64; ++k) fb[k * 64 + lane] = o[k >> 4][k & 15];
    if (lane < 32) {
      Ml[w2][0][li] = mreg;
      Ml[w2][1][li] = lreg;
    }
  }
  __syncthreads();
  if (grp == 1) {
    float m1 = Ml[w2][0][li], l1 = Ml[w2][1][li];
    float m = fmaxf(mreg, m1);
    float s2 = __builtin_amdgcn_exp2f(mreg - m);
    float s1 = __builtin_amdgcn_exp2f(m1 - m);
    float lsum = lreg * s2 + l1 * s1;
    float rl = 1.0f / lsum;
    u16* yrow = y + ((size_t)(b * S_ + qrow)) * E_ + h * D_;
#pragma unroll
    for (int dt = 0; dt < 4; dt++) {
#pragma unroll
      for (int g2 = 0; g2 < 4; g2++) {
        int d = dt * 32 + 8 * g2 + 4 * hi;
        ushort4 sv;
        float v0 = (o[dt][4 * g2 + 0] * s2 + fb[(dt * 16 + 4 * g2 + 0) * 64 + lane] * s1) * rl;
        float v1 = (o[dt][4 * g2 + 1] * s2 + fb[(dt * 16 + 4 * g2 + 1) * 64 + lane] * s1) * rl;
        float v2 = (o[dt][4 * g2 + 2] * s2 + fb[(dt * 16 + 4 * g2 + 2) * 64 + lane] * s1) * rl;
        float v3 = (o[dt][4 * g2 + 3] * s2 + fb[(dt * 16 + 4 * g2 + 3) * 64 + lane] * s1) * rl;
        sv.x = f2bf(v0);
        sv.y = f2bf(v1);
        sv.z = f2bf(v2);
        sv.w = f2bf(v3);
        *(ushort4*)(yrow + d) = sv;
      }
    }
  }
}

// ---------------- host ----------------
extern "C" void kernel_launch(void* const* d_in, const int* in_sizes, int n_in,
                              void* d_out, int out_size, void* d_ws, size_t ws_size,
                              hipStream_t stream) {
  const float* x = (const float*)d_in[0];
  const float* g_q = (const float*)d_in[1];
  const float* g_kv = (const float*)d_in[2];
  const float* w_qa = (const float*)d_in[3];
  const float* w_qb = (const float*)d_in[4];
  const float* w_kva = (const float*)d_in[5];
  const float* w_kvb = (const float*)d_in[6];
  const float* w_o = (const float*)d_in[7];
  float* out = (float*)d_out;
  char* ws = (char*)d_ws;

  size_t off = 0;
  float* cos_t = (float*)(ws + off); off += (size_t)S_ * 32 * 4;
  float* sin_t = (float*)(ws + off); off += (size_t)S_ * 32 * 4;
  u16* wqa_t = (u16*)(ws + off); off += (size_t)QR_ * E_ * 2;
  u16* wqb_t = (u16*)(ws + off); off += (size_t)E_ * QR_ * 2;
  u16* wkvb_t = (u16*)(ws + off); off += (size_t)E_ * KR_ * 2;
  u16* wo_t = (u16*)(ws + off); off += (size_t)E_ * E_ * 2;
  u16* wsel_t = (u16*)(ws + off); off += (size_t)NSEL_ * E_ * 2;
  u16* qlow = (u16*)(ws + off); off += (size_t)T_ * QR_ * 2;
  u16* kc = (u16*)(ws + off); off += (size_t)T_ * KR_ * 2;
  u16* ln_q = (u16*)(ws + off); off += (size_t)T_ * E_ * 2;   // reused as y
  u16* ln_kv = (u16*)(ws + off); off += (size_t)T_ * E_ * 2;  // reused as q_r
  u16* k_rb = (u16*)(ws + off); off += (size_t)T_ * E_ * 2;   // first v_nat, then k_r
  u16* v_tb = (u16*)(ws + off); off += (size_t)T_ * E_ * 2;
  u16* y = ln_q;
  u16* q_rb = ln_kv;
  u16* v_nat = k_rb;  // alias: consumed by k_vtr before rope2's k-half writes k_r

  // LN + fused RoPE-table build (blocks 0..255 also fill cos_t/sin_t)
  k_ln<<<dim3(T_), dim3(256), 0, stream>>>(x, g_q, g_kv, ln_q, ln_kv, cos_t, sin_t);

  // all five weight transposes in one launch (8960 blocks, vectorized)
  k_transp_all<<<dim3(8960), dim3(256), 0, stream>>>(
      w_qa, w_qb, w_kvb, w_o, w_kva, wqa_t, wqb_t, wkvb_t, wo_t, wsel_t);

  EpiP ep{};

  // q_low = ln_q @ w_qa  (M=4096, N=64, K=2048) -- BM=64: 64 blocks
  ep = EpiP{}; ep.obf = qlow;
  k_gemm<64, 64, 0><<<dim3(1, T_ / 64), dim3(256), 0, stream>>>(ln_q, wqa_t, T_, QR_, E_, ep);

  // kv = ln_kv @ w_kva_sel  (M=4096, N=2176, K=2048) -> kc + v natural (coalesced)
  ep = EpiP{}; ep.kc = kc; ep.vt = v_nat;
  k_gemm<128, 128, 2><<<dim3(NSEL_ / 128, T_ / 128), dim3(256), 0, stream>>>(ln_kv, wsel_t, T_, NSEL_, E_, ep);

  // v^T transpose first (consumes v_nat before rope2's k-half overwrites it)
  k_vtr<<<dim3(32, 64), dim3(256), 0, stream>>>(v_nat, v_tb);

  // merged RoPE GEMMs: q (K=64) + k (K=128) in one 1024-block launch
  k_gemm_rope2<<<dim3(1024), dim3(256), 0, stream>>>(
      qlow, wqb_t, q_rb, kc, wkvb_t, k_rb, cos_t, sin_t);

  // attention -> y (overwrites ln_q). 1024 blocks x 4 waves, split-K + LPT refill.
  k_attn<<<dim3(1024), dim3(256), 0, stream>>>(q_rb, k_rb, v_tb, y);

  // out = y @ w_o  (M=4096, N=2048, K=2048), fp32
  ep = EpiP{}; ep.of32 = out;
  k_gemm<128, 128, 1><<<dim3(E_ / 128, T_ / 128), dim3(256), 0, stream>>>(y, wo_t, T_, E_, E_, ep);
}

// Round 28
// 203.665 us; speedup vs baseline: 1.7163x; 1.1484x over previous
//
#include <hip/hip_runtime.h>
#include <cstdint>
#include <cstddef>

typedef unsigned short u16;
typedef __attribute__((ext_vector_type(8))) __bf16 bf16x8;
typedef __attribute__((ext_vector_type(4))) float f32x4;
typedef __attribute__((ext_vector_type(16))) float f32x16;
typedef __attribute__((ext_vector_type(4))) unsigned u32x4;

#define E_ 2048
#define H_ 16
#define D_ 128
#define QR_ 64
#define KR_ 128
#define S_ 2048
#define B_ 2
#define T_ 4096
#define NSEL_ 2176
#define EPS_ 1e-5f
#define SCALE_ 0.08838834764831845f
#define SCL2_ 0.12751743f  // SCALE_ * log2(e); softmax in exp2 domain

typedef __attribute__((address_space(1))) const void gvoid;
typedef __attribute__((address_space(3))) void lvoid;

__device__ __forceinline__ u16 f2bf(float f) {
  unsigned u = __float_as_uint(f);
  unsigned r = (u + 0x7FFFu + ((u >> 16) & 1u)) >> 16;
  return (u16)r;
}

// ---------------- dual LayerNorm (+ fused RoPE table build in blocks 0..255) --------
__global__ __launch_bounds__(256) void k_ln(
    const float* __restrict__ x, const float* __restrict__ gq,
    const float* __restrict__ gkv, u16* __restrict__ lnq, u16* __restrict__ lnkv,
    float* __restrict__ cos_t, float* __restrict__ sin_t) {
  if (blockIdx.x < (S_ * 32) / 256) {  // fused k_rope_tables (same index math)
    int idx = blockIdx.x * 256 + threadIdx.x;
    int t = idx >> 5, j = idx & 31;
    float inv = powf(10000.0f, -(float)j / 32.0f);
    float a = (float)t * inv;
    cos_t[idx] = cosf(a);
    sin_t[idx] = sinf(a);
  }
  int row = blockIdx.x;
  const float* xr = x + (size_t)row * E_;
  int base = threadIdx.x * 8;
  float4 v0 = *(const float4*)(xr + base);
  float4 v1 = *(const float4*)(xr + base + 4);
  float xv[8] = {v0.x, v0.y, v0.z, v0.w, v1.x, v1.y, v1.z, v1.w};
  float s0 = 0.f, s1 = 0.f;
#pragma unroll
  for (int i = 0; i < 8; i++) { s0 += xv[i]; s1 += xv[i] * xv[i]; }
  for (int off = 32; off > 0; off >>= 1) {
    s0 += __shfl_down(s0, off);
    s1 += __shfl_down(s1, off);
  }
  __shared__ float red[2][4];
  int wid = threadIdx.x >> 6, lane = threadIdx.x & 63;
  if (lane == 0) { red[0][wid] = s0; red[1][wid] = s1; }
  __syncthreads();
  s0 = red[0][0] + red[0][1] + red[0][2] + red[0][3];
  s1 = red[1][0] + red[1][1] + red[1][2] + red[1][3];
  float mu = s0 * (1.0f / E_);
  float var = s1 * (1.0f / E_) - mu * mu;
  float rs = rsqrtf(var + EPS_);
  u16 oq[8], okv[8];
#pragma unroll
  for (int i = 0; i < 8; i++) {
    float nv = (xv[i] - mu) * rs;
    oq[i] = f2bf(nv * gq[base + i]);
    okv[i] = f2bf(nv * gkv[base + i]);
  }
  *(ushort4*)(lnq + (size_t)row * E_ + base) = make_ushort4(oq[0], oq[1], oq[2], oq[3]);
  *(ushort4*)(lnq + (size_t)row * E_ + base + 4) = make_ushort4(oq[4], oq[5], oq[6], oq[7]);
  *(ushort4*)(lnkv + (size_t)row * E_ + base) = make_ushort4(okv[0], okv[1], okv[2], okv[3]);
  *(ushort4*)(lnkv + (size_t)row * E_ + base + 4) = make_ushort4(okv[4], okv[5], okv[6], okv[7]);
}

// ---------------- ALL weight transposes f32 -> bf16 (out[N'][K]) in ONE launch ------
__global__ __launch_bounds__(256) void k_transp_all(
    const float* __restrict__ w_qa, const float* __restrict__ w_qb,
    const float* __restrict__ w_kvb, const float* __restrict__ w_o,
    const float* __restrict__ w_kva,
    u16* __restrict__ wqa_t, u16* __restrict__ wqb_t, u16* __restrict__ wkvb_t,
    u16* __restrict__ wo_t, u16* __restrict__ wsel_t) {
  __shared__ float t[32][33];
  int f = blockIdx.x;
  const float* in;
  u16* out;
  int K, Nin, bx, by;
  bool sel = false;
  if (f < 128) {
    in = w_qb; out = wqb_t; K = QR_; Nin = E_; bx = f % 64; by = f / 64;
  } else if (f < 256) {
    f -= 128;
    in = w_qa; out = wqa_t; K = E_; Nin = QR_; bx = f % 2; by = f / 2;
  } else if (f < 512) {
    f -= 256;
    in = w_kvb; out = wkvb_t; K = KR_; Nin = E_; bx = f % 64; by = f / 64;
  } else if (f < 4608) {
    f -= 512;
    in = w_o; out = wo_t; K = E_; Nin = E_; bx = f % 64; by = f / 64;
  } else {
    f -= 4608;
    in = w_kva; out = wsel_t; K = E_; Nin = 128 + H_ * 2 * D_; sel = true;
    bx = f % 68; by = f / 68;
  }
  int orb = bx * 32;
  int icb;
  if (sel) {
    icb = (orb < 128) ? orb : 128 + ((orb - 128) >> 7) * 256 + ((orb - 128) & 127);
  } else {
    icb = orb;
  }
  int kb = by * 32;
  int r = threadIdx.x >> 3, q = threadIdx.x & 7;
  float4 lv = *(const float4*)&in[(size_t)(kb + r) * Nin + icb + q * 4];
  t[r][q * 4 + 0] = lv.x;
  t[r][q * 4 + 1] = lv.y;
  t[r][q * 4 + 2] = lv.z;
  t[r][q * 4 + 3] = lv.w;
  __syncthreads();
  int c = r;
  ushort4 sv;
  sv.x = f2bf(t[q * 4 + 0][c]);
  sv.y = f2bf(t[q * 4 + 1][c]);
  sv.z = f2bf(t[q * 4 + 2][c]);
  sv.w = f2bf(t[q * 4 + 3][c]);
  *(ushort4*)&out[(size_t)(orb + c) * K + kb + q * 4] = sv;
}

// ---------------- bf16 per-batch 2048x2048 transpose: v_nat -> v_t (vectorized) -----
__global__ __launch_bounds__(256) void k_vtr(
    const u16* __restrict__ vn, u16* __restrict__ vt) {
  __shared__ u16 t[64][68];
  int c0 = blockIdx.x * 64;
  int b = blockIdx.y >> 5;
  int s0 = (blockIdx.y & 31) * 64;
#pragma unroll
  for (int i = 0; i < 4; i++) {
    int flat = threadIdx.x + i * 256;
    int r = flat >> 4, q = flat & 15;
    ushort4 v = *(const ushort4*)&vn[((size_t)(b * 2048 + s0 + r)) * 2048 + c0 + q * 4];
    t[r][q * 4 + 0] = v.x;
    t[r][q * 4 + 1] = v.y;
    t[r][q * 4 + 2] = v.z;
    t[r][q * 4 + 3] = v.w;
  }
  __syncthreads();
#pragma unroll
  for (int i = 0; i < 4; i++) {
    int flat = threadIdx.x + i * 256;
    int c = flat >> 4, q = flat & 15;
    ushort4 v;
    v.x = t[q * 4 + 0][c];
    v.y = t[q * 4 + 1][c];
    v.z = t[q * 4 + 2][c];
    v.w = t[q * 4 + 3][c];
    *(ushort4*)&vt[((size_t)(b * 2048 + c0 + c)) * 2048 + s0 + q * 4] = v;
  }
}

// ---------------- shared GEMM body (T3-min single-barrier), flat-indexed LDS --------
struct EpiP {
  float* of32;
  u16* obf;
  u16* kc;
  u16* vt;
  u16* qk;
  const float* cost;
  const float* sint;
};

template <int BM, int BN, int EPI>
__device__ __forceinline__ void gemm_body(
    const u16* __restrict__ A, const u16* __restrict__ Bt,
    int K, EpiP ep, int bm, int bn, u16* ls) {
  constexpr int WM = BM / 2;
  constexpr int MI = WM / 16;
  constexpr int WN = BN / 2;
  constexpr int NI = WN / 16;
  u16* lsA = ls;                    // [2][BM*32]
  u16* lsB = ls + 2 * BM * 32;      // [2][BN*32]
  int tid = threadIdx.x, lane = tid & 63, wid = tid >> 6;
  int wr = wid >> 1, wc = wid & 1;
  f32x4 zero4 = {0.f, 0.f, 0.f, 0.f};
  f32x4 acc[MI][NI];
#pragma unroll
  for (int m = 0; m < MI; m++)
#pragma unroll
    for (int n = 0; n < NI; n++) acc[m][n] = zero4;
  const int nkt = K >> 5;
  const u16* Ab = A + (size_t)bm * BM * K;
  const u16* Bb = Bt + (size_t)bn * BN * K;
  int arow = tid >> 2, acol8 = (tid & 3) * 8;
  int lg = lane >> 4, li = lane & 15;

  auto stage = [&](int buf, int kt) {
    int k0 = kt * 32;
#pragma unroll
    for (int c = 0; c < BM / 64; c++) {
      int row = c * 64 + arow;
      __builtin_amdgcn_global_load_lds(
          (gvoid*)(Ab + (size_t)row * K + k0 + acol8),
          (lvoid*)(&lsA[buf * BM * 32 + row * 32 + acol8]), 16, 0, 0);
    }
#pragma unroll
    for (int c = 0; c < BN / 64; c++) {
      int row = c * 64 + arow;
      __builtin_amdgcn_global_load_lds(
          (gvoid*)(Bb + (size_t)row * K + k0 + acol8),
          (lvoid*)(&lsB[buf * BN * 32 + row * 32 + acol8]), 16, 0, 0);
    }
  };

  stage(0, 0);
  asm volatile("s_waitcnt vmcnt(0)" ::: "memory");
  __builtin_amdgcn_s_barrier();
  asm volatile("" ::: "memory");
  for (int kt = 0; kt < nkt; ++kt) {
    int cur = kt & 1;
    if (kt + 1 < nkt) stage(cur ^ 1, kt + 1);  // issue next-tile loads FIRST
    bf16x8 af[MI], bfr[NI];
#pragma unroll
    for (int m = 0; m < MI; m++)
      af[m] = *reinterpret_cast<const bf16x8*>(
          &lsA[cur * BM * 32 + (wr * WM + m * 16 + li) * 32 + lg * 8]);
#pragma unroll
    for (int n = 0; n < NI; n++)
      bfr[n] = *reinterpret_cast<const bf16x8*>(
          &lsB[cur * BN * 32 + (wc * WN + n * 16 + li) * 32 + lg * 8]);
#pragma unroll
    for (int m = 0; m < MI; m++)
#pragma unroll
      for (int n = 0; n < NI; n++)
        acc[m][n] = __builtin_amdgcn_mfma_f32_16x16x32_bf16(af[m], bfr[n], acc[m][n], 0, 0, 0);
    asm volatile("s_waitcnt vmcnt(0)" ::: "memory");
    __builtin_amdgcn_s_barrier();
    asm volatile("" ::: "memory");
  }
  // epilogue
#pragma unroll
  for (int m = 0; m < MI; m++) {
#pragma unroll
    for (int n = 0; n < NI; n++) {
      int col = bn * BN + wc * WN + n * 16 + li;
#pragma unroll
      for (int r = 0; r < 4; r++) {
        int row = bm * BM + wr * WM + m * 16 + lg * 4 + r;
        float val = acc[m][n][r];
        if constexpr (EPI == 0) {
          ep.obf[(size_t)row * 64 + col] = f2bf(val);
        } else if constexpr (EPI == 1) {
          ep.of32[(size_t)row * E_ + col] = val;
        } else if constexpr (EPI == 2) {
          if (col < KR_) {
            ep.kc[(size_t)row * KR_ + col] = f2bf(val);
          } else {
            ep.vt[(size_t)row * 2048 + (col - KR_)] = f2bf(val);  // coalesced natural v
          }
        } else {  // EPI 3: RoPE + per-head store
          int h = col >> 7, dl = col & 127;
          int b = row >> 11, sp = row & 2047;
          float outv;
          if (dl < 64) {
            float pv = acc[m][n ^ 2][r];
            int j = dl & 31;
            float c = ep.cost[sp * 32 + j];
            float s = ep.sint[sp * 32 + j];
            float rot = (dl < 32) ? -pv : pv;
            outv = val * c + rot * s;
          } else {
            outv = val;
          }
          ep.qk[((size_t)(b * H_ + h) * S_ + sp) * D_ + dl] = f2bf(outv);
        }
      }
    }
  }
}

// ---------------- out-GEMM (EPI=1), original 2-D launch form ----------------
template <int BM, int BN, int EPI>
__global__ __launch_bounds__(256, 3) void k_gemm(
    const u16* __restrict__ A, const u16* __restrict__ Bt,
    int M, int N, int K, EpiP ep) {
  __shared__ alignas(16) u16 ls[2 * BM * 32 + 2 * BN * 32];
  int gx = gridDim.x;
  int nwg = gx * gridDim.y;
  int flat = blockIdx.y * gx + blockIdx.x;
  int cpx = nwg >> 3;
  int swz = (flat & 7) * cpx + (flat >> 3);
  int bm = swz / gx, bn = swz % gx;
  gemm_body<BM, BN, EPI>(A, Bt, K, ep, bm, bn, ls);
}

// ---------------- merged qa + kv GEMMs in one launch --------------------------------
// blocks [0,544): kv (BM=BN=128, EPI=2; swizzle == original 17x32 grid decode)
// blocks [544,608): qa (BM=BN=64, EPI=0; swizzle == original 1x64 grid decode)
__global__ __launch_bounds__(256, 3) void k_gemm_qakv(
    const u16* __restrict__ lnq, const u16* __restrict__ wqa, u16* __restrict__ qlow,
    const u16* __restrict__ lnkv, const u16* __restrict__ wsel,
    u16* __restrict__ kc, u16* __restrict__ vnat) {
  __shared__ alignas(16) u16 ls[2 * 128 * 32 + 2 * 128 * 32];  // 32 KB (kv max; qa uses prefix)
  int f = blockIdx.x;
  if (f < 544) {
    int swz = (f & 7) * 68 + (f >> 3);
    int bm = swz / 17, bn = swz % 17;
    EpiP ep{};
    ep.kc = kc;
    ep.vt = vnat;
    gemm_body<128, 128, 2>(lnkv, wsel, E_, ep, bm, bn, ls);
  } else {
    int lf = f - 544;
    int bm = (lf & 7) * 8 + (lf >> 3);
    EpiP ep{};
    ep.obf = qlow;
    gemm_body<64, 64, 0>(lnq, wqa, E_, ep, bm, 0, ls);
  }
}

// ---------------- merged RoPE GEMMs: q (K=64) + k (K=128) in one launch -------------
__global__ __launch_bounds__(256, 3) void k_gemm_rope2(
    const u16* __restrict__ Aq, const u16* __restrict__ Btq, u16* __restrict__ outq,
    const u16* __restrict__ Ak, const u16* __restrict__ Btk, u16* __restrict__ outk,
    const float* __restrict__ cost, const float* __restrict__ sint) {
  __shared__ alignas(16) u16 ls[2 * 128 * 32 + 2 * 128 * 32];
  int f = blockIdx.x;
  bool isK = f >= 512;
  int lf = f & 511;
  int swz = (lf & 7) * 64 + (lf >> 3);
  int bm = swz >> 4, bn = swz & 15;
  EpiP ep{};
  ep.cost = cost;
  ep.sint = sint;
  if (isK) {
    ep.qk = outk;
    gemm_body<128, 128, 3>(Ak, Btk, KR_, ep, bm, bn, ls);
  } else {
    ep.qk = outq;
    gemm_body<128, 128, 3>(Aq, Btq, QR_, ep, bm, bn, ls);
  }
}

// ---------------- causal flash attention (split-K blocks + LPT refill) ----------------
__global__ __launch_bounds__(256, 2) void k_attn(
    const u16* __restrict__ q_r, const u16* __restrict__ k_r,
    const u16* __restrict__ v_t, u16* __restrict__ y) {
  __shared__ alignas(16) u16 Ks[2][2][32 * 128];  // [dbuf][grp] K tile 32x128
  __shared__ alignas(16) u16 Vs[2][2][64 * 64];   // [dbuf][grp] packed V^T
  __shared__ float Ml[2][2][32];
  int tid = threadIdx.x, lane = tid & 63, wid = tid >> 6;  // wid 0..3
  int id = blockIdx.x;
  int bh = ((id & 7) << 2) | ((id >> 3) & 3);  // XCD-pinned: 4 bh per XCD
  int j = 31 - (id >> 5);                      // heavy tiles dispatched first
  int w2 = wid & 1, grp = wid >> 1;
  int b = bh >> 4, h = bh & 15;
  int li = lane & 31, hi = lane >> 5;
  int qb = 64 * j + w2 * 32;
  int qrow = qb + li;
  int n = j + 1;
  int kg_base = grp * 32 * n;
  const u16* qbase = q_r + (size_t)bh * S_ * D_;
  const u16* kbase = k_r + (size_t)bh * S_ * D_;
  const u16* vbase = v_t + (size_t)bh * D_ * S_;

  bf16x8 aq[8];
#pragma unroll
  for (int step = 0; step < 8; step++)
    aq[step] = *(const bf16x8*)&qbase[(size_t)qrow * D_ + step * 16 + hi * 8];

  f32x16 o[4];
#pragma unroll
  for (int dt = 0; dt < 4; dt++)
#pragma unroll
    for (int r = 0; r < 16; r++) o[dt][r] = 0.f;
  float mreg = -1e30f, lreg = 0.f;

  int kr_l = w2 * 16 + (lane >> 4);  // + i*4
  int kc_l = (lane & 15) * 8;
  int kswz = (li & 7) << 4;

  auto stage = [&](int nb, int p) {
    int kg0 = kg_base + p * 32;
    u16* Kst = &Ks[nb][grp][0];
    u16* Vst = &Vs[nb][grp][0];
#pragma unroll
    for (int i = 0; i < 4; i++) {
      int r = kr_l + i * 4;
      __builtin_amdgcn_global_load_lds(
          (gvoid*)(kbase + (size_t)(kg0 + r) * D_ + (kc_l ^ ((r & 7) << 3))),
          (lvoid*)(&Kst[r * 128 + kc_l]), 16, 0, 0);
    }
#pragma unroll
    for (int i = 0; i < 4; i++) {
      int r = w2 * 32 + i * 8 + (lane >> 3);
      int ss = lane & 7;
      int s = ss ^ (r & 7);
      int d = ((s >> 2) << 6) + r;        // slot half selects d or d+64
      int kk = kg0 + (s & 3) * 8;
      __builtin_amdgcn_global_load_lds(
          (gvoid*)(vbase + (size_t)d * S_ + kk),
          (lvoid*)(&Vst[r * 64 + ss * 8]), 16, 0, 0);
    }
  };

  stage(0, 0);
  int cbuf = 0;

  for (int p = 0; p < n; ++p) {
    int kg0 = kg_base + p * 32;
    asm volatile("s_waitcnt vmcnt(0)" ::: "memory");  // my loads landed (flew under compute)
    __builtin_amdgcn_s_barrier();                      // everyone's loads landed
    asm volatile("" ::: "memory");                     // fence only; scheduling stays free
    if (p + 1 < n) stage(cbuf ^ 1, p + 1);             // overlaps this iter's compute
    if (kg0 <= qb + 31) {
      bool domask = (kg0 + 31 > qb);
      const char* Kc = (const char*)&Ks[cbuf][grp][0];
      const char* Vc = (const char*)&Vs[cbuf][grp][0];
      // ---- QK^T (swapped), 32 keys; accumulator chain split in two (latency) ----
      bf16x8 kf[8];
#pragma unroll
      for (int step = 0; step < 8; step++)
        kf[step] = *(const bf16x8*)(Kc + li * 256 + ((step * 32 + hi * 16) ^ kswz));
      f32x16 c0, c1;
#pragma unroll
      for (int r = 0; r < 16; r++) { c0[r] = 0.f; c1[r] = 0.f; }
      __builtin_amdgcn_s_setprio(1);
#pragma unroll
      for (int step = 0; step < 4; step++) {
        c0 = __builtin_amdgcn_mfma_f32_32x32x16_bf16(kf[step], aq[step], c0, 0, 0, 0);
        c1 = __builtin_amdgcn_mfma_f32_32x32x16_bf16(kf[step + 4], aq[step + 4], c1, 0, 0, 0);
      }
      __builtin_amdgcn_s_setprio(0);
      float ps[16];
#pragma unroll
      for (int r = 0; r < 16; r++) ps[r] = (c0[r] + c1[r]) * SCL2_;  // exp2 domain
      if (domask) {  // wave-uniform boundary branch
#pragma unroll
        for (int r = 0; r < 16; r++) {
          int k = kg0 + (r & 3) + 8 * (r >> 2) + 4 * hi;
          if (k > qrow) ps[r] = -1e30f;
        }
      }
      // ---- in-register softmax (one q row per lane) ----
      float t8[8];
#pragma unroll
      for (int r = 0; r < 8; r++) t8[r] = fmaxf(ps[r], ps[r + 8]);
#pragma unroll
      for (int r = 0; r < 4; r++) t8[r] = fmaxf(t8[r], t8[r + 4]);
      float mt = fmaxf(fmaxf(t8[0], t8[1]), fmaxf(t8[2], t8[3]));
      mt = fmaxf(mt, __shfl_xor(mt, 32));
      // T13 defer-max
      if (!__all(mt <= mreg + 8.f)) {
        float mn = fmaxf(mreg, mt);
        float al = __builtin_amdgcn_exp2f(mreg - mn);
        mreg = mn;
        lreg *= al;
#pragma unroll
        for (int dt = 0; dt < 4; dt++)
#pragma unroll
          for (int r = 0; r < 16; r++) o[dt][r] *= al;
      }
#pragma unroll
      for (int r = 0; r < 16; r++) ps[r] = __builtin_amdgcn_exp2f(ps[r] - mreg);
      float s8[8];
#pragma unroll
      for (int r = 0; r < 8; r++) s8[r] = ps[r] + ps[r + 8];
#pragma unroll
      for (int r = 0; r < 4; r++) s8[r] = s8[r] + s8[r + 4];
      float rs = (s8[0] + s8[1]) + (s8[2] + s8[3]);
      rs += __shfl_xor(rs, 32);
      lreg += rs;
      // ---- PV: B-fragment in-register via cvt_pk + permlane32_swap (T12) ----
#pragma unroll
      for (int ks = 0; ks < 2; ks++) {
        const int bix = ks * 8;
        unsigned P0, P1, P2, P3;
        asm("v_cvt_pk_bf16_f32 %0, %1, %2" : "=v"(P0) : "v"(ps[bix + 0]), "v"(ps[bix + 1]));
        asm("v_cvt_pk_bf16_f32 %0, %1, %2" : "=v"(P1) : "v"(ps[bix + 2]), "v"(ps[bix + 3]));
        asm("v_cvt_pk_bf16_f32 %0, %1, %2" : "=v"(P2) : "v"(ps[bix + 4]), "v"(ps[bix + 5]));
        asm("v_cvt_pk_bf16_f32 %0, %1, %2" : "=v"(P3) : "v"(ps[bix + 6]), "v"(ps[bix + 7]));
        asm("v_permlane32_swap_b32 %0, %1" : "+v"(P0), "+v"(P2));
        asm("v_permlane32_swap_b32 %0, %1" : "+v"(P1), "+v"(P3));
        bf16x8 bp = __builtin_bit_cast(bf16x8, (u32x4){P0, P1, P2, P3});
        bf16x8 vf[4];
#pragma unroll
        for (int dt = 0; dt < 4; dt++) {
          int row = ((dt & 1) << 5) + li;
          vf[dt] = *(const bf16x8*)(Vc + row * 128 +
                                    ((((dt >> 1) * 4 + ks * 2 + hi) * 16) ^ ((row & 7) << 4)));
        }
        __builtin_amdgcn_s_setprio(1);
#pragma unroll
        for (int dt = 0; dt < 4; dt++)
          o[dt] = __builtin_amdgcn_mfma_f32_32x32x16_bf16(vf[dt], bp, o[dt], 0, 0, 0);
        __builtin_amdgcn_s_setprio(0);
      }
    }
    cbuf ^= 1;
  }
  // ---- merge partials: grp0 writes, grp1 combines + stores ----
  __syncthreads();
  float* fb = (float*)&Ks[0][0][0] + w2 * 4096;  // 16 KB region per writer wave
  if (grp == 0) {
#pragma unroll
    for (int k = 0; k < 64; ++k) fb[k * 64 + lane] = o[k >> 4][k & 15];
    if (lane < 32) {
      Ml[w2][0][li] = mreg;
      Ml[w2][1][li] = lreg;
    }
  }
  __syncthreads();
  if (grp == 1) {
    float m1 = Ml[w2][0][li], l1 = Ml[w2][1][li];
    float m = fmaxf(mreg, m1);
    float s2 = __builtin_amdgcn_exp2f(mreg - m);
    float s1 = __builtin_amdgcn_exp2f(m1 - m);
    float lsum = lreg * s2 + l1 * s1;
    float rl = 1.0f / lsum;
    u16* yrow = y + ((size_t)(b * S_ + qrow)) * E_ + h * D_;
#pragma unroll
    for (int dt = 0; dt < 4; dt++) {
#pragma unroll
      for (int g2 = 0; g2 < 4; g2++) {
        int d = dt * 32 + 8 * g2 + 4 * hi;
        ushort4 sv;
        float v0 = (o[dt][4 * g2 + 0] * s2 + fb[(dt * 16 + 4 * g2 + 0) * 64 + lane] * s1) * rl;
        float v1 = (o[dt][4 * g2 + 1] * s2 + fb[(dt * 16 + 4 * g2 + 1) * 64 + lane] * s1) * rl;
        float v2 = (o[dt][4 * g2 + 2] * s2 + fb[(dt * 16 + 4 * g2 + 2) * 64 + lane] * s1) * rl;
        float v3 = (o[dt][4 * g2 + 3] * s2 + fb[(dt * 16 + 4 * g2 + 3) * 64 + lane] * s1) * rl;
        sv.x = f2bf(v0);
        sv.y = f2bf(v1);
        sv.z = f2bf(v2);
        sv.w = f2bf(v3);
        *(ushort4*)(yrow + d) = sv;
      }
    }
  }
}

// ---------------- host ----------------
extern "C" void kernel_launch(void* const* d_in, const int* in_sizes, int n_in,
                              void* d_out, int out_size, void* d_ws, size_t ws_size,
                              hipStream_t stream) {
  const float* x = (const float*)d_in[0];
  const float* g_q = (const float*)d_in[1];
  const float* g_kv = (const float*)d_in[2];
  const float* w_qa = (const float*)d_in[3];
  const float* w_qb = (const float*)d_in[4];
  const float* w_kva = (const float*)d_in[5];
  const float* w_kvb = (const float*)d_in[6];
  const float* w_o = (const float*)d_in[7];
  float* out = (float*)d_out;
  char* ws = (char*)d_ws;

  size_t off = 0;
  float* cos_t = (float*)(ws + off); off += (size_t)S_ * 32 * 4;
  float* sin_t = (float*)(ws + off); off += (size_t)S_ * 32 * 4;
  u16* wqa_t = (u16*)(ws + off); off += (size_t)QR_ * E_ * 2;
  u16* wqb_t = (u16*)(ws + off); off += (size_t)E_ * QR_ * 2;
  u16* wkvb_t = (u16*)(ws + off); off += (size_t)E_ * KR_ * 2;
  u16* wo_t = (u16*)(ws + off); off += (size_t)E_ * E_ * 2;
  u16* wsel_t = (u16*)(ws + off); off += (size_t)NSEL_ * E_ * 2;
  u16* qlow = (u16*)(ws + off); off += (size_t)T_ * QR_ * 2;
  u16* kc = (u16*)(ws + off); off += (size_t)T_ * KR_ * 2;
  u16* ln_q = (u16*)(ws + off); off += (size_t)T_ * E_ * 2;   // reused as y
  u16* ln_kv = (u16*)(ws + off); off += (size_t)T_ * E_ * 2;  // reused as q_r
  u16* k_rb = (u16*)(ws + off); off += (size_t)T_ * E_ * 2;   // first v_nat, then k_r
  u16* v_tb = (u16*)(ws + off); off += (size_t)T_ * E_ * 2;
  u16* y = ln_q;
  u16* q_rb = ln_kv;
  u16* v_nat = k_rb;  // alias: consumed by k_vtr before rope2's k-half writes k_r

  // LN + fused RoPE-table build (blocks 0..255 also fill cos_t/sin_t)
  k_ln<<<dim3(T_), dim3(256), 0, stream>>>(x, g_q, g_kv, ln_q, ln_kv, cos_t, sin_t);

  // all five weight transposes in one launch (8960 blocks, vectorized)
  k_transp_all<<<dim3(8960), dim3(256), 0, stream>>>(
      w_qa, w_qb, w_kvb, w_o, w_kva, wqa_t, wqb_t, wkvb_t, wo_t, wsel_t);

  // merged qa + kv GEMMs: 544 kv blocks + 64 qa blocks, all co-resident
  k_gemm_qakv<<<dim3(608), dim3(256), 0, stream>>>(
      ln_q, wqa_t, qlow, ln_kv, wsel_t, kc, v_nat);

  // v^T transpose (consumes v_nat before rope2's k-half overwrites it)
  k_vtr<<<dim3(32, 64), dim3(256), 0, stream>>>(v_nat, v_tb);

  // merged RoPE GEMMs: q (K=64) + k (K=128) in one 1024-block launch
  k_gemm_rope2<<<dim3(1024), dim3(256), 0, stream>>>(
      qlow, wqb_t, q_rb, kc, wkvb_t, k_rb, cos_t, sin_t);

  // attention -> y (overwrites ln_q). 1024 blocks x 4 waves, split-K + LPT refill.
  k_attn<<<dim3(1024), dim3(256), 0, stream>>>(q_rb, k_rb, v_tb, y);

  // out = y @ w_o  (M=4096, N=2048, K=2048), fp32
  ep_out:
  {
    EpiP ep{};
    ep.of32 = out;
    k_gemm<128, 128, 1><<<dim3(E_ / 128, T_ / 128), dim3(256), 0, stream>>>(y, wo_t, T_, E_, E_, ep);
  }
}

// Round 29
// 202.904 us; speedup vs baseline: 1.7228x; 1.0037x over previous
//
#include <hip/hip_runtime.h>
#include <cstdint>
#include <cstddef>

typedef unsigned short u16;
typedef __attribute__((ext_vector_type(8))) __bf16 bf16x8;
typedef __attribute__((ext_vector_type(4))) float f32x4;
typedef __attribute__((ext_vector_type(16))) float f32x16;
typedef __attribute__((ext_vector_type(4))) unsigned u32x4;

#define E_ 2048
#define H_ 16
#define D_ 128
#define QR_ 64
#define KR_ 128
#define S_ 2048
#define B_ 2
#define T_ 4096
#define NSEL_ 2176
#define EPS_ 1e-5f
#define SCALE_ 0.08838834764831845f
#define SCL2_ 0.12751743f  // SCALE_ * log2(e); softmax in exp2 domain

typedef __attribute__((address_space(1))) const void gvoid;
typedef __attribute__((address_space(3))) void lvoid;

__device__ __forceinline__ u16 f2bf(float f) {
  unsigned u = __float_as_uint(f);
  unsigned r = (u + 0x7FFFu + ((u >> 16) & 1u)) >> 16;
  return (u16)r;
}

// -------- merged pre-pass: LN (+RoPE tables) for f<4096; weight transposes after ----
// LN body and transp body are the round-28-verified kernels verbatim; block-level
// decode only. transp range [4096,13056) maps to the old k_transp_all f = bid-4096.
__global__ __launch_bounds__(256) void k_pre(
    const float* __restrict__ x, const float* __restrict__ gq,
    const float* __restrict__ gkv, u16* __restrict__ lnq, u16* __restrict__ lnkv,
    float* __restrict__ cos_t, float* __restrict__ sin_t,
    const float* __restrict__ w_qa, const float* __restrict__ w_qb,
    const float* __restrict__ w_kvb, const float* __restrict__ w_o,
    const float* __restrict__ w_kva,
    u16* __restrict__ wqa_t, u16* __restrict__ wqb_t, u16* __restrict__ wkvb_t,
    u16* __restrict__ wo_t, u16* __restrict__ wsel_t) {
  if (blockIdx.x < T_) {  // ---------------- LN body ----------------
    if (blockIdx.x < (S_ * 32) / 256) {  // fused RoPE tables
      int idx = blockIdx.x * 256 + threadIdx.x;
      int t = idx >> 5, j = idx & 31;
      float inv = powf(10000.0f, -(float)j / 32.0f);
      float a = (float)t * inv;
      cos_t[idx] = cosf(a);
      sin_t[idx] = sinf(a);
    }
    int row = blockIdx.x;
    const float* xr = x + (size_t)row * E_;
    int base = threadIdx.x * 8;
    float4 v0 = *(const float4*)(xr + base);
    float4 v1 = *(const float4*)(xr + base + 4);
    float xv[8] = {v0.x, v0.y, v0.z, v0.w, v1.x, v1.y, v1.z, v1.w};
    float s0 = 0.f, s1 = 0.f;
#pragma unroll
    for (int i = 0; i < 8; i++) { s0 += xv[i]; s1 += xv[i] * xv[i]; }
    for (int off = 32; off > 0; off >>= 1) {
      s0 += __shfl_down(s0, off);
      s1 += __shfl_down(s1, off);
    }
    __shared__ float red[2][4];
    int wid = threadIdx.x >> 6, lane = threadIdx.x & 63;
    if (lane == 0) { red[0][wid] = s0; red[1][wid] = s1; }
    __syncthreads();
    s0 = red[0][0] + red[0][1] + red[0][2] + red[0][3];
    s1 = red[1][0] + red[1][1] + red[1][2] + red[1][3];
    float mu = s0 * (1.0f / E_);
    float var = s1 * (1.0f / E_) - mu * mu;
    float rs = rsqrtf(var + EPS_);
    u16 oq[8], okv[8];
#pragma unroll
    for (int i = 0; i < 8; i++) {
      float nv = (xv[i] - mu) * rs;
      oq[i] = f2bf(nv * gq[base + i]);
      okv[i] = f2bf(nv * gkv[base + i]);
    }
    *(ushort4*)(lnq + (size_t)row * E_ + base) = make_ushort4(oq[0], oq[1], oq[2], oq[3]);
    *(ushort4*)(lnq + (size_t)row * E_ + base + 4) = make_ushort4(oq[4], oq[5], oq[6], oq[7]);
    *(ushort4*)(lnkv + (size_t)row * E_ + base) = make_ushort4(okv[0], okv[1], okv[2], okv[3]);
    *(ushort4*)(lnkv + (size_t)row * E_ + base + 4) = make_ushort4(okv[4], okv[5], okv[6], okv[7]);
  } else {  // ---------------- transpose body ----------------
    __shared__ float t[32][33];
    int f = blockIdx.x - T_;
    const float* in;
    u16* out;
    int K, Nin, bx, by;
    bool sel = false;
    if (f < 128) {
      in = w_qb; out = wqb_t; K = QR_; Nin = E_; bx = f % 64; by = f / 64;
    } else if (f < 256) {
      f -= 128;
      in = w_qa; out = wqa_t; K = E_; Nin = QR_; bx = f % 2; by = f / 2;
    } else if (f < 512) {
      f -= 256;
      in = w_kvb; out = wkvb_t; K = KR_; Nin = E_; bx = f % 64; by = f / 64;
    } else if (f < 4608) {
      f -= 512;
      in = w_o; out = wo_t; K = E_; Nin = E_; bx = f % 64; by = f / 64;
    } else {
      f -= 4608;
      in = w_kva; out = wsel_t; K = E_; Nin = 128 + H_ * 2 * D_; sel = true;
      bx = f % 68; by = f / 68;
    }
    int orb = bx * 32;
    int icb;
    if (sel) {
      icb = (orb < 128) ? orb : 128 + ((orb - 128) >> 7) * 256 + ((orb - 128) & 127);
    } else {
      icb = orb;
    }
    int kb = by * 32;
    int r = threadIdx.x >> 3, q = threadIdx.x & 7;
    float4 lv = *(const float4*)&in[(size_t)(kb + r) * Nin + icb + q * 4];
    t[r][q * 4 + 0] = lv.x;
    t[r][q * 4 + 1] = lv.y;
    t[r][q * 4 + 2] = lv.z;
    t[r][q * 4 + 3] = lv.w;
    __syncthreads();
    int c = r;
    ushort4 sv;
    sv.x = f2bf(t[q * 4 + 0][c]);
    sv.y = f2bf(t[q * 4 + 1][c]);
    sv.z = f2bf(t[q * 4 + 2][c]);
    sv.w = f2bf(t[q * 4 + 3][c]);
    *(ushort4*)&out[(size_t)(orb + c) * K + kb + q * 4] = sv;
  }
}

// ---------------- bf16 per-batch 2048x2048 transpose: v_nat -> v_t (vectorized) -----
__global__ __launch_bounds__(256) void k_vtr(
    const u16* __restrict__ vn, u16* __restrict__ vt) {
  __shared__ u16 t[64][68];
  int c0 = blockIdx.x * 64;
  int b = blockIdx.y >> 5;
  int s0 = (blockIdx.y & 31) * 64;
#pragma unroll
  for (int i = 0; i < 4; i++) {
    int flat = threadIdx.x + i * 256;
    int r = flat >> 4, q = flat & 15;
    ushort4 v = *(const ushort4*)&vn[((size_t)(b * 2048 + s0 + r)) * 2048 + c0 + q * 4];
    t[r][q * 4 + 0] = v.x;
    t[r][q * 4 + 1] = v.y;
    t[r][q * 4 + 2] = v.z;
    t[r][q * 4 + 3] = v.w;
  }
  __syncthreads();
#pragma unroll
  for (int i = 0; i < 4; i++) {
    int flat = threadIdx.x + i * 256;
    int c = flat >> 4, q = flat & 15;
    ushort4 v;
    v.x = t[q * 4 + 0][c];
    v.y = t[q * 4 + 1][c];
    v.z = t[q * 4 + 2][c];
    v.w = t[q * 4 + 3][c];
    *(ushort4*)&vt[((size_t)(b * 2048 + c0 + c)) * 2048 + s0 + q * 4] = v;
  }
}

// ---------------- shared GEMM body (T3-min single-barrier), flat-indexed LDS --------
struct EpiP {
  float* of32;
  u16* obf;
  u16* kc;
  u16* vt;
  u16* qk;
  const float* cost;
  const float* sint;
};

template <int BM, int BN, int EPI>
__device__ __forceinline__ void gemm_body(
    const u16* __restrict__ A, const u16* __restrict__ Bt,
    int K, EpiP ep, int bm, int bn, u16* ls) {
  constexpr int WM = BM / 2;
  constexpr int MI = WM / 16;
  constexpr int WN = BN / 2;
  constexpr int NI = WN / 16;
  u16* lsA = ls;                    // [2][BM*32]
  u16* lsB = ls + 2 * BM * 32;      // [2][BN*32]
  int tid = threadIdx.x, lane = tid & 63, wid = tid >> 6;
  int wr = wid >> 1, wc = wid & 1;
  f32x4 zero4 = {0.f, 0.f, 0.f, 0.f};
  f32x4 acc[MI][NI];
#pragma unroll
  for (int m = 0; m < MI; m++)
#pragma unroll
    for (int n = 0; n < NI; n++) acc[m][n] = zero4;
  const int nkt = K >> 5;
  const u16* Ab = A + (size_t)bm * BM * K;
  const u16* Bb = Bt + (size_t)bn * BN * K;
  int arow = tid >> 2, acol8 = (tid & 3) * 8;
  int lg = lane >> 4, li = lane & 15;

  auto stage = [&](int buf, int kt) {
    int k0 = kt * 32;
#pragma unroll
    for (int c = 0; c < BM / 64; c++) {
      int row = c * 64 + arow;
      __builtin_amdgcn_global_load_lds(
          (gvoid*)(Ab + (size_t)row * K + k0 + acol8),
          (lvoid*)(&lsA[buf * BM * 32 + row * 32 + acol8]), 16, 0, 0);
    }
#pragma unroll
    for (int c = 0; c < BN / 64; c++) {
      int row = c * 64 + arow;
      __builtin_amdgcn_global_load_lds(
          (gvoid*)(Bb + (size_t)row * K + k0 + acol8),
          (lvoid*)(&lsB[buf * BN * 32 + row * 32 + acol8]), 16, 0, 0);
    }
  };

  stage(0, 0);
  asm volatile("s_waitcnt vmcnt(0)" ::: "memory");
  __builtin_amdgcn_s_barrier();
  asm volatile("" ::: "memory");
  for (int kt = 0; kt < nkt; ++kt) {
    int cur = kt & 1;
    if (kt + 1 < nkt) stage(cur ^ 1, kt + 1);  // issue next-tile loads FIRST
    bf16x8 af[MI], bfr[NI];
#pragma unroll
    for (int m = 0; m < MI; m++)
      af[m] = *reinterpret_cast<const bf16x8*>(
          &lsA[cur * BM * 32 + (wr * WM + m * 16 + li) * 32 + lg * 8]);
#pragma unroll
    for (int n = 0; n < NI; n++)
      bfr[n] = *reinterpret_cast<const bf16x8*>(
          &lsB[cur * BN * 32 + (wc * WN + n * 16 + li) * 32 + lg * 8]);
#pragma unroll
    for (int m = 0; m < MI; m++)
#pragma unroll
      for (int n = 0; n < NI; n++)
        acc[m][n] = __builtin_amdgcn_mfma_f32_16x16x32_bf16(af[m], bfr[n], acc[m][n], 0, 0, 0);
    asm volatile("s_waitcnt vmcnt(0)" ::: "memory");
    __builtin_amdgcn_s_barrier();
    asm volatile("" ::: "memory");
  }
  // epilogue
#pragma unroll
  for (int m = 0; m < MI; m++) {
#pragma unroll
    for (int n = 0; n < NI; n++) {
      int col = bn * BN + wc * WN + n * 16 + li;
#pragma unroll
      for (int r = 0; r < 4; r++) {
        int row = bm * BM + wr * WM + m * 16 + lg * 4 + r;
        float val = acc[m][n][r];
        if constexpr (EPI == 0) {
          ep.obf[(size_t)row * 64 + col] = f2bf(val);
        } else if constexpr (EPI == 1) {
          ep.of32[(size_t)row * E_ + col] = val;
        } else if constexpr (EPI == 2) {
          if (col < KR_) {
            ep.kc[(size_t)row * KR_ + col] = f2bf(val);
          } else {
            ep.vt[(size_t)row * 2048 + (col - KR_)] = f2bf(val);  // coalesced natural v
          }
        } else {  // EPI 3: RoPE + per-head store
          int h = col >> 7, dl = col & 127;
          int b = row >> 11, sp = row & 2047;
          float outv;
          if (dl < 64) {
            float pv = acc[m][n ^ 2][r];
            int j = dl & 31;
            float c = ep.cost[sp * 32 + j];
            float s = ep.sint[sp * 32 + j];
            float rot = (dl < 32) ? -pv : pv;
            outv = val * c + rot * s;
          } else {
            outv = val;
          }
          ep.qk[((size_t)(b * H_ + h) * S_ + sp) * D_ + dl] = f2bf(outv);
        }
      }
    }
  }
}

// ---------------- out-GEMM (EPI=1), original 2-D launch form ----------------
template <int BM, int BN, int EPI>
__global__ __launch_bounds__(256, 3) void k_gemm(
    const u16* __restrict__ A, const u16* __restrict__ Bt,
    int M, int N, int K, EpiP ep) {
  __shared__ alignas(16) u16 ls[2 * BM * 32 + 2 * BN * 32];
  int gx = gridDim.x;
  int nwg = gx * gridDim.y;
  int flat = blockIdx.y * gx + blockIdx.x;
  int cpx = nwg >> 3;
  int swz = (flat & 7) * cpx + (flat >> 3);
  int bm = swz / gx, bn = swz % gx;
  gemm_body<BM, BN, EPI>(A, Bt, K, ep, bm, bn, ls);
}

// ---------------- merged qa + kv GEMMs in one launch --------------------------------
__global__ __launch_bounds__(256, 3) void k_gemm_qakv(
    const u16* __restrict__ lnq, const u16* __restrict__ wqa, u16* __restrict__ qlow,
    const u16* __restrict__ lnkv, const u16* __restrict__ wsel,
    u16* __restrict__ kc, u16* __restrict__ vnat) {
  __shared__ alignas(16) u16 ls[2 * 128 * 32 + 2 * 128 * 32];  // 32 KB (kv max; qa uses prefix)
  int f = blockIdx.x;
  if (f < 544) {
    int swz = (f & 7) * 68 + (f >> 3);
    int bm = swz / 17, bn = swz % 17;
    EpiP ep{};
    ep.kc = kc;
    ep.vt = vnat;
    gemm_body<128, 128, 2>(lnkv, wsel, E_, ep, bm, bn, ls);
  } else {
    int lf = f - 544;
    int bm = (lf & 7) * 8 + (lf >> 3);
    EpiP ep{};
    ep.obf = qlow;
    gemm_body<64, 64, 0>(lnq, wqa, E_, ep, bm, 0, ls);
  }
}

// ---------------- merged RoPE GEMMs: q (K=64) + k (K=128) in one launch -------------
__global__ __launch_bounds__(256, 3) void k_gemm_rope2(
    const u16* __restrict__ Aq, const u16* __restrict__ Btq, u16* __restrict__ outq,
    const u16* __restrict__ Ak, const u16* __restrict__ Btk, u16* __restrict__ outk,
    const float* __restrict__ cost, const float* __restrict__ sint) {
  __shared__ alignas(16) u16 ls[2 * 128 * 32 + 2 * 128 * 32];
  int f = blockIdx.x;
  bool isK = f >= 512;
  int lf = f & 511;
  int swz = (lf & 7) * 64 + (lf >> 3);
  int bm = swz >> 4, bn = swz & 15;
  EpiP ep{};
  ep.cost = cost;
  ep.sint = sint;
  if (isK) {
    ep.qk = outk;
    gemm_body<128, 128, 3>(Ak, Btk, KR_, ep, bm, bn, ls);
  } else {
    ep.qk = outq;
    gemm_body<128, 128, 3>(Aq, Btq, QR_, ep, bm, bn, ls);
  }
}

// ---------------- causal flash attention (split-K blocks + LPT refill) ----------------
__global__ __launch_bounds__(256, 2) void k_attn(
    const u16* __restrict__ q_r, const u16* __restrict__ k_r,
    const u16* __restrict__ v_t, u16* __restrict__ y) {
  __shared__ alignas(16) u16 Ks[2][2][32 * 128];  // [dbuf][grp] K tile 32x128
  __shared__ alignas(16) u16 Vs[2][2][64 * 64];   // [dbuf][grp] packed V^T
  __shared__ float Ml[2][2][32];
  int tid = threadIdx.x, lane = tid & 63, wid = tid >> 6;  // wid 0..3
  int id = blockIdx.x;
  int bh = ((id & 7) << 2) | ((id >> 3) & 3);  // XCD-pinned: 4 bh per XCD
  int j = 31 - (id >> 5);                      // heavy tiles dispatched first
  int w2 = wid & 1, grp = wid >> 1;
  int b = bh >> 4, h = bh & 15;
  int li = lane & 31, hi = lane >> 5;
  int qb = 64 * j + w2 * 32;
  int qrow = qb + li;
  int n = j + 1;
  int kg_base = grp * 32 * n;
  const u16* qbase = q_r + (size_t)bh * S_ * D_;
  const u16* kbase = k_r + (size_t)bh * S_ * D_;
  const u16* vbase = v_t + (size_t)bh * D_ * S_;

  bf16x8 aq[8];
#pragma unroll
  for (int step = 0; step < 8; step++)
    aq[step] = *(const bf16x8*)&qbase[(size_t)qrow * D_ + step * 16 + hi * 8];

  f32x16 o[4];
#pragma unroll
  for (int dt = 0; dt < 4; dt++)
#pragma unroll
    for (int r = 0; r < 16; r++) o[dt][r] = 0.f;
  float mreg = -1e30f, lreg = 0.f;

  int kr_l = w2 * 16 + (lane >> 4);  // + i*4
  int kc_l = (lane & 15) * 8;
  int kswz = (li & 7) << 4;

  auto stage = [&](int nb, int p) {
    int kg0 = kg_base + p * 32;
    u16* Kst = &Ks[nb][grp][0];
    u16* Vst = &Vs[nb][grp][0];
#pragma unroll
    for (int i = 0; i < 4; i++) {
      int r = kr_l + i * 4;
      __builtin_amdgcn_global_load_lds(
          (gvoid*)(kbase + (size_t)(kg0 + r) * D_ + (kc_l ^ ((r & 7) << 3))),
          (lvoid*)(&Kst[r * 128 + kc_l]), 16, 0, 0);
    }
#pragma unroll
    for (int i = 0; i < 4; i++) {
      int r = w2 * 32 + i * 8 + (lane >> 3);
      int ss = lane & 7;
      int s = ss ^ (r & 7);
      int d = ((s >> 2) << 6) + r;        // slot half selects d or d+64
      int kk = kg0 + (s & 3) * 8;
      __builtin_amdgcn_global_load_lds(
          (gvoid*)(vbase + (size_t)d * S_ + kk),
          (lvoid*)(&Vst[r * 64 + ss * 8]), 16, 0, 0);
    }
  };

  stage(0, 0);
  int cbuf = 0;

  for (int p = 0; p < n; ++p) {
    int kg0 = kg_base + p * 32;
    asm volatile("s_waitcnt vmcnt(0)" ::: "memory");  // my loads landed (flew under compute)
    __builtin_amdgcn_s_barrier();                      // everyone's loads landed
    asm volatile("" ::: "memory");                     // fence only; scheduling stays free
    if (p + 1 < n) stage(cbuf ^ 1, p + 1);             // overlaps this iter's compute
    if (kg0 <= qb + 31) {
      bool domask = (kg0 + 31 > qb);
      const char* Kc = (const char*)&Ks[cbuf][grp][0];
      const char* Vc = (const char*)&Vs[cbuf][grp][0];
      // ---- QK^T (swapped), 32 keys; accumulator chain split in two (latency) ----
      bf16x8 kf[8];
#pragma unroll
      for (int step = 0; step < 8; step++)
        kf[step] = *(const bf16x8*)(Kc + li * 256 + ((step * 32 + hi * 16) ^ kswz));
      f32x16 c0, c1;
#pragma unroll
      for (int r = 0; r < 16; r++) { c0[r] = 0.f; c1[r] = 0.f; }
      __builtin_amdgcn_s_setprio(1);
#pragma unroll
      for (int step = 0; step < 4; step++) {
        c0 = __builtin_amdgcn_mfma_f32_32x32x16_bf16(kf[step], aq[step], c0, 0, 0, 0);
        c1 = __builtin_amdgcn_mfma_f32_32x32x16_bf16(kf[step + 4], aq[step + 4], c1, 0, 0, 0);
      }
      __builtin_amdgcn_s_setprio(0);
      float ps[16];
#pragma unroll
      for (int r = 0; r < 16; r++) ps[r] = (c0[r] + c1[r]) * SCL2_;  // exp2 domain
      if (domask) {  // wave-uniform boundary branch
#pragma unroll
        for (int r = 0; r < 16; r++) {
          int k = kg0 + (r & 3) + 8 * (r >> 2) + 4 * hi;
          if (k > qrow) ps[r] = -1e30f;
        }
      }
      // ---- in-register softmax (one q row per lane) ----
      float t8[8];
#pragma unroll
      for (int r = 0; r < 8; r++) t8[r] = fmaxf(ps[r], ps[r + 8]);
#pragma unroll
      for (int r = 0; r < 4; r++) t8[r] = fmaxf(t8[r], t8[r + 4]);
      float mt = fmaxf(fmaxf(t8[0], t8[1]), fmaxf(t8[2], t8[3]));
      mt = fmaxf(mt, __shfl_xor(mt, 32));
      // T13 defer-max
      if (!__all(mt <= mreg + 8.f)) {
        float mn = fmaxf(mreg, mt);
        float al = __builtin_amdgcn_exp2f(mreg - mn);
        mreg = mn;
        lreg *= al;
#pragma unroll
        for (int dt = 0; dt < 4; dt++)
#pragma unroll
          for (int r = 0; r < 16; r++) o[dt][r] *= al;
      }
#pragma unroll
      for (int r = 0; r < 16; r++) ps[r] = __builtin_amdgcn_exp2f(ps[r] - mreg);
      float s8[8];
#pragma unroll
      for (int r = 0; r < 8; r++) s8[r] = ps[r] + ps[r + 8];
#pragma unroll
      for (int r = 0; r < 4; r++) s8[r] = s8[r] + s8[r + 4];
      float rs = (s8[0] + s8[1]) + (s8[2] + s8[3]);
      rs += __shfl_xor(rs, 32);
      lreg += rs;
      // ---- PV: B-fragment in-register via cvt_pk + permlane32_swap (T12) ----
#pragma unroll
      for (int ks = 0; ks < 2; ks++) {
        const int bix = ks * 8;
        unsigned P0, P1, P2, P3;
        asm("v_cvt_pk_bf16_f32 %0, %1, %2" : "=v"(P0) : "v"(ps[bix + 0]), "v"(ps[bix + 1]));
        asm("v_cvt_pk_bf16_f32 %0, %1, %2" : "=v"(P1) : "v"(ps[bix + 2]), "v"(ps[bix + 3]));
        asm("v_cvt_pk_bf16_f32 %0, %1, %2" : "=v"(P2) : "v"(ps[bix + 4]), "v"(ps[bix + 5]));
        asm("v_cvt_pk_bf16_f32 %0, %1, %2" : "=v"(P3) : "v"(ps[bix + 6]), "v"(ps[bix + 7]));
        asm("v_permlane32_swap_b32 %0, %1" : "+v"(P0), "+v"(P2));
        asm("v_permlane32_swap_b32 %0, %1" : "+v"(P1), "+v"(P3));
        bf16x8 bp = __builtin_bit_cast(bf16x8, (u32x4){P0, P1, P2, P3});
        bf16x8 vf[4];
#pragma unroll
        for (int dt = 0; dt < 4; dt++) {
          int row = ((dt & 1) << 5) + li;
          vf[dt] = *(const bf16x8*)(Vc + row * 128 +
                                    ((((dt >> 1) * 4 + ks * 2 + hi) * 16) ^ ((row & 7) << 4)));
        }
        __builtin_amdgcn_s_setprio(1);
#pragma unroll
        for (int dt = 0; dt < 4; dt++)
          o[dt] = __builtin_amdgcn_mfma_f32_32x32x16_bf16(vf[dt], bp, o[dt], 0, 0, 0);
        __builtin_amdgcn_s_setprio(0);
      }
    }
    cbuf ^= 1;
  }
  // ---- merge partials: grp0 writes, grp1 combines + stores ----
  __syncthreads();
  float* fb = (float*)&Ks[0][0][0] + w2 * 4096;  // 16 KB region per writer wave
  if (grp == 0) {
#pragma unroll
    for (int k = 0; k < 64; ++k) fb[k * 64 + lane] = o[k >> 4][k & 15];
    if (lane < 32) {
      Ml[w2][0][li] = mreg;
      Ml[w2][1][li] = lreg;
    }
  }
  __syncthreads();
  if (grp == 1) {
    float m1 = Ml[w2][0][li], l1 = Ml[w2][1][li];
    float m = fmaxf(mreg, m1);
    float s2 = __builtin_amdgcn_exp2f(mreg - m);
    float s1 = __builtin_amdgcn_exp2f(m1 - m);
    float lsum = lreg * s2 + l1 * s1;
    float rl = 1.0f / lsum;
    u16* yrow = y + ((size_t)(b * S_ + qrow)) * E_ + h * D_;
#pragma unroll
    for (int dt = 0; dt < 4; dt++) {
#pragma unroll
      for (int g2 = 0; g2 < 4; g2++) {
        int d = dt * 32 + 8 * g2 + 4 * hi;
        ushort4 sv;
        float v0 = (o[dt][4 * g2 + 0] * s2 + fb[(dt * 16 + 4 * g2 + 0) * 64 + lane] * s1) * rl;
        float v1 = (o[dt][4 * g2 + 1] * s2 + fb[(dt * 16 + 4 * g2 + 1) * 64 + lane] * s1) * rl;
        float v2 = (o[dt][4 * g2 + 2] * s2 + fb[(dt * 16 + 4 * g2 + 2) * 64 + lane] * s1) * rl;
        float v3 = (o[dt][4 * g2 + 3] * s2 + fb[(dt * 16 + 4 * g2 + 3) * 64 + lane] * s1) * rl;
        sv.x = f2bf(v0);
        sv.y = f2bf(v1);
        sv.z = f2bf(v2);
        sv.w = f2bf(v3);
        *(ushort4*)(yrow + d) = sv;
      }
    }
  }
}

// ---------------- host ----------------
extern "C" void kernel_launch(void* const* d_in, const int* in_sizes, int n_in,
                              void* d_out, int out_size, void* d_ws, size_t ws_size,
                              hipStream_t stream) {
  const float* x = (const float*)d_in[0];
  const float* g_q = (const float*)d_in[1];
  const float* g_kv = (const float*)d_in[2];
  const float* w_qa = (const float*)d_in[3];
  const float* w_qb = (const float*)d_in[4];
  const float* w_kva = (const float*)d_in[5];
  const float* w_kvb = (const float*)d_in[6];
  const float* w_o = (const float*)d_in[7];
  float* out = (float*)d_out;
  char* ws = (char*)d_ws;

  size_t off = 0;
  float* cos_t = (float*)(ws + off); off += (size_t)S_ * 32 * 4;
  float* sin_t = (float*)(ws + off); off += (size_t)S_ * 32 * 4;
  u16* wqa_t = (u16*)(ws + off); off += (size_t)QR_ * E_ * 2;
  u16* wqb_t = (u16*)(ws + off); off += (size_t)E_ * QR_ * 2;
  u16* wkvb_t = (u16*)(ws + off); off += (size_t)E_ * KR_ * 2;
  u16* wo_t = (u16*)(ws + off); off += (size_t)E_ * E_ * 2;
  u16* wsel_t = (u16*)(ws + off); off += (size_t)NSEL_ * E_ * 2;
  u16* qlow = (u16*)(ws + off); off += (size_t)T_ * QR_ * 2;
  u16* kc = (u16*)(ws + off); off += (size_t)T_ * KR_ * 2;
  u16* ln_q = (u16*)(ws + off); off += (size_t)T_ * E_ * 2;   // reused as y
  u16* ln_kv = (u16*)(ws + off); off += (size_t)T_ * E_ * 2;  // reused as q_r
  u16* k_rb = (u16*)(ws + off); off += (size_t)T_ * E_ * 2;   // first v_nat, then k_r
  u16* v_tb = (u16*)(ws + off); off += (size_t)T_ * E_ * 2;
  u16* y = ln_q;
  u16* q_rb = ln_kv;
  u16* v_nat = k_rb;  // alias: consumed by k_vtr before rope2's k-half writes k_r

  // merged pre-pass: LN (+RoPE tables) and all five weight transposes, one launch
  k_pre<<<dim3(T_ + 8960), dim3(256), 0, stream>>>(
      x, g_q, g_kv, ln_q, ln_kv, cos_t, sin_t,
      w_qa, w_qb, w_kvb, w_o, w_kva, wqa_t, wqb_t, wkvb_t, wo_t, wsel_t);

  // merged qa + kv GEMMs: 544 kv blocks + 64 qa blocks, all co-resident
  k_gemm_qakv<<<dim3(608), dim3(256), 0, stream>>>(
      ln_q, wqa_t, qlow, ln_kv, wsel_t, kc, v_nat);

  // v^T transpose (consumes v_nat before rope2's k-half overwrites it)
  k_vtr<<<dim3(32, 64), dim3(256), 0, stream>>>(v_nat, v_tb);

  // merged RoPE GEMMs: q (K=64) + k (K=128) in one 1024-block launch
  k_gemm_rope2<<<dim3(1024), dim3(256), 0, stream>>>(
      qlow, wqb_t, q_rb, kc, wkvb_t, k_rb, cos_t, sin_t);

  // attention -> y (overwrites ln_q). 1024 blocks x 4 waves, split-K + LPT refill.
  k_attn<<<dim3(1024), dim3(256), 0, stream>>>(q_rb, k_rb, v_tb, y);

  // out = y @ w_o  (M=4096, N=2048, K=2048), fp32
  {
    EpiP ep{};
    ep.of32 = out;
    k_gemm<128, 128, 1><<<dim3(E_ / 128, T_ / 128), dim3(256), 0, stream>>>(y, wo_t, T_, E_, E_, ep);
  }
}

// Round 30
// 200.307 us; speedup vs baseline: 1.7451x; 1.0130x over previous
//
#include <hip/hip_runtime.h>
#include <cstdint>
#include <cstddef>

typedef unsigned short u16;
typedef __attribute__((ext_vector_type(8))) __bf16 bf16x8;
typedef __attribute__((ext_vector_type(4))) float f32x4;
typedef __attribute__((ext_vector_type(16))) float f32x16;
typedef __attribute__((ext_vector_type(4))) unsigned u32x4;

#define E_ 2048
#define H_ 16
#define D_ 128
#define QR_ 64
#define KR_ 128
#define S_ 2048
#define B_ 2
#define T_ 4096
#define NSEL_ 2176
#define EPS_ 1e-5f
#define SCALE_ 0.08838834764831845f
#define SCL2_ 0.12751743f  // SCALE_ * log2(e); softmax in exp2 domain

typedef __attribute__((address_space(1))) const void gvoid;
typedef __attribute__((address_space(3))) void lvoid;

__device__ __forceinline__ u16 f2bf(float f) {
  unsigned u = __float_as_uint(f);
  unsigned r = (u + 0x7FFFu + ((u >> 16) & 1u)) >> 16;
  return (u16)r;
}

// -------- merged pre-pass: LN (+RoPE tables) for f<4096; weight transposes after ----
__global__ __launch_bounds__(256) void k_pre(
    const float* __restrict__ x, const float* __restrict__ gq,
    const float* __restrict__ gkv, u16* __restrict__ lnq, u16* __restrict__ lnkv,
    float* __restrict__ cos_t, float* __restrict__ sin_t,
    const float* __restrict__ w_qa, const float* __restrict__ w_qb,
    const float* __restrict__ w_kvb, const float* __restrict__ w_o,
    const float* __restrict__ w_kva,
    u16* __restrict__ wqa_t, u16* __restrict__ wqb_t, u16* __restrict__ wkvb_t,
    u16* __restrict__ wo_t, u16* __restrict__ wsel_t) {
  if (blockIdx.x < T_) {  // ---------------- LN body ----------------
    if (blockIdx.x < (S_ * 32) / 256) {  // fused RoPE tables
      int idx = blockIdx.x * 256 + threadIdx.x;
      int t = idx >> 5, j = idx & 31;
      float inv = powf(10000.0f, -(float)j / 32.0f);
      float a = (float)t * inv;
      cos_t[idx] = cosf(a);
      sin_t[idx] = sinf(a);
    }
    int row = blockIdx.x;
    const float* xr = x + (size_t)row * E_;
    int base = threadIdx.x * 8;
    float4 v0 = *(const float4*)(xr + base);
    float4 v1 = *(const float4*)(xr + base + 4);
    float xv[8] = {v0.x, v0.y, v0.z, v0.w, v1.x, v1.y, v1.z, v1.w};
    float s0 = 0.f, s1 = 0.f;
#pragma unroll
    for (int i = 0; i < 8; i++) { s0 += xv[i]; s1 += xv[i] * xv[i]; }
    for (int off = 32; off > 0; off >>= 1) {
      s0 += __shfl_down(s0, off);
      s1 += __shfl_down(s1, off);
    }
    __shared__ float red[2][4];
    int wid = threadIdx.x >> 6, lane = threadIdx.x & 63;
    if (lane == 0) { red[0][wid] = s0; red[1][wid] = s1; }
    __syncthreads();
    s0 = red[0][0] + red[0][1] + red[0][2] + red[0][3];
    s1 = red[1][0] + red[1][1] + red[1][2] + red[1][3];
    float mu = s0 * (1.0f / E_);
    float var = s1 * (1.0f / E_) - mu * mu;
    float rs = rsqrtf(var + EPS_);
    u16 oq[8], okv[8];
#pragma unroll
    for (int i = 0; i < 8; i++) {
      float nv = (xv[i] - mu) * rs;
      oq[i] = f2bf(nv * gq[base + i]);
      okv[i] = f2bf(nv * gkv[base + i]);
    }
    *(ushort4*)(lnq + (size_t)row * E_ + base) = make_ushort4(oq[0], oq[1], oq[2], oq[3]);
    *(ushort4*)(lnq + (size_t)row * E_ + base + 4) = make_ushort4(oq[4], oq[5], oq[6], oq[7]);
    *(ushort4*)(lnkv + (size_t)row * E_ + base) = make_ushort4(okv[0], okv[1], okv[2], okv[3]);
    *(ushort4*)(lnkv + (size_t)row * E_ + base + 4) = make_ushort4(okv[4], okv[5], okv[6], okv[7]);
  } else {  // ---------------- transpose body ----------------
    __shared__ float t[32][33];
    int f = blockIdx.x - T_;
    const float* in;
    u16* out;
    int K, Nin, bx, by;
    bool sel = false;
    if (f < 128) {
      in = w_qb; out = wqb_t; K = QR_; Nin = E_; bx = f % 64; by = f / 64;
    } else if (f < 256) {
      f -= 128;
      in = w_qa; out = wqa_t; K = E_; Nin = QR_; bx = f % 2; by = f / 2;
    } else if (f < 512) {
      f -= 256;
      in = w_kvb; out = wkvb_t; K = KR_; Nin = E_; bx = f % 64; by = f / 64;
    } else if (f < 4608) {
      f -= 512;
      in = w_o; out = wo_t; K = E_; Nin = E_; bx = f % 64; by = f / 64;
    } else {
      f -= 4608;
      in = w_kva; out = wsel_t; K = E_; Nin = 128 + H_ * 2 * D_; sel = true;
      bx = f % 68; by = f / 68;
    }
    int orb = bx * 32;
    int icb;
    if (sel) {
      icb = (orb < 128) ? orb : 128 + ((orb - 128) >> 7) * 256 + ((orb - 128) & 127);
    } else {
      icb = orb;
    }
    int kb = by * 32;
    int r = threadIdx.x >> 3, q = threadIdx.x & 7;
    float4 lv = *(const float4*)&in[(size_t)(kb + r) * Nin + icb + q * 4];
    t[r][q * 4 + 0] = lv.x;
    t[r][q * 4 + 1] = lv.y;
    t[r][q * 4 + 2] = lv.z;
    t[r][q * 4 + 3] = lv.w;
    __syncthreads();
    int c = r;
    ushort4 sv;
    sv.x = f2bf(t[q * 4 + 0][c]);
    sv.y = f2bf(t[q * 4 + 1][c]);
    sv.z = f2bf(t[q * 4 + 2][c]);
    sv.w = f2bf(t[q * 4 + 3][c]);
    *(ushort4*)&out[(size_t)(orb + c) * K + kb + q * 4] = sv;
  }
}

// ---------------- shared GEMM body (T3-min single-barrier), flat-indexed LDS --------
struct EpiP {
  float* of32;
  u16* obf;
  u16* kc;
  u16* vt;
  u16* qk;
  const float* cost;
  const float* sint;
};

template <int BM, int BN, int EPI>
__device__ __forceinline__ void gemm_body(
    const u16* __restrict__ A, const u16* __restrict__ Bt,
    int K, EpiP ep, int bm, int bn, u16* ls) {
  constexpr int WM = BM / 2;
  constexpr int MI = WM / 16;
  constexpr int WN = BN / 2;
  constexpr int NI = WN / 16;
  u16* lsA = ls;                    // [2][BM*32]
  u16* lsB = ls + 2 * BM * 32;      // [2][BN*32]
  int tid = threadIdx.x, lane = tid & 63, wid = tid >> 6;
  int wr = wid >> 1, wc = wid & 1;
  f32x4 zero4 = {0.f, 0.f, 0.f, 0.f};
  f32x4 acc[MI][NI];
#pragma unroll
  for (int m = 0; m < MI; m++)
#pragma unroll
    for (int n = 0; n < NI; n++) acc[m][n] = zero4;
  const int nkt = K >> 5;
  const u16* Ab = A + (size_t)bm * BM * K;
  const u16* Bb = Bt + (size_t)bn * BN * K;
  int arow = tid >> 2, acol8 = (tid & 3) * 8;
  int lg = lane >> 4, li = lane & 15;

  auto stage = [&](int buf, int kt) {
    int k0 = kt * 32;
#pragma unroll
    for (int c = 0; c < BM / 64; c++) {
      int row = c * 64 + arow;
      __builtin_amdgcn_global_load_lds(
          (gvoid*)(Ab + (size_t)row * K + k0 + acol8),
          (lvoid*)(&lsA[buf * BM * 32 + row * 32 + acol8]), 16, 0, 0);
    }
#pragma unroll
    for (int c = 0; c < BN / 64; c++) {
      int row = c * 64 + arow;
      __builtin_amdgcn_global_load_lds(
          (gvoid*)(Bb + (size_t)row * K + k0 + acol8),
          (lvoid*)(&lsB[buf * BN * 32 + row * 32 + acol8]), 16, 0, 0);
    }
  };

  stage(0, 0);
  asm volatile("s_waitcnt vmcnt(0)" ::: "memory");
  __builtin_amdgcn_s_barrier();
  asm volatile("" ::: "memory");
  for (int kt = 0; kt < nkt; ++kt) {
    int cur = kt & 1;
    if (kt + 1 < nkt) stage(cur ^ 1, kt + 1);  // issue next-tile loads FIRST
    bf16x8 af[MI], bfr[NI];
#pragma unroll
    for (int m = 0; m < MI; m++)
      af[m] = *reinterpret_cast<const bf16x8*>(
          &lsA[cur * BM * 32 + (wr * WM + m * 16 + li) * 32 + lg * 8]);
#pragma unroll
    for (int n = 0; n < NI; n++)
      bfr[n] = *reinterpret_cast<const bf16x8*>(
          &lsB[cur * BN * 32 + (wc * WN + n * 16 + li) * 32 + lg * 8]);
#pragma unroll
    for (int m = 0; m < MI; m++)
#pragma unroll
      for (int n = 0; n < NI; n++)
        acc[m][n] = __builtin_amdgcn_mfma_f32_16x16x32_bf16(af[m], bfr[n], acc[m][n], 0, 0, 0);
    asm volatile("s_waitcnt vmcnt(0)" ::: "memory");
    __builtin_amdgcn_s_barrier();
    asm volatile("" ::: "memory");
  }
  // epilogue
#pragma unroll
  for (int m = 0; m < MI; m++) {
#pragma unroll
    for (int n = 0; n < NI; n++) {
      int col = bn * BN + wc * WN + n * 16 + li;
#pragma unroll
      for (int r = 0; r < 4; r++) {
        int row = bm * BM + wr * WM + m * 16 + lg * 4 + r;
        float val = acc[m][n][r];
        if constexpr (EPI == 0) {
          ep.obf[(size_t)row * 64 + col] = f2bf(val);
        } else if constexpr (EPI == 1) {
          ep.of32[(size_t)row * E_ + col] = val;
        } else if constexpr (EPI == 2) {
          if (col < KR_) {
            ep.kc[(size_t)row * KR_ + col] = f2bf(val);
          } else {
            ep.vt[(size_t)row * 2048 + (col - KR_)] = f2bf(val);  // coalesced natural v
          }
        } else {  // EPI 3: RoPE + per-head store
          int h = col >> 7, dl = col & 127;
          int b = row >> 11, sp = row & 2047;
          float outv;
          if (dl < 64) {
            float pv = acc[m][n ^ 2][r];
            int j = dl & 31;
            float c = ep.cost[sp * 32 + j];
            float s = ep.sint[sp * 32 + j];
            float rot = (dl < 32) ? -pv : pv;
            outv = val * c + rot * s;
          } else {
            outv = val;
          }
          ep.qk[((size_t)(b * H_ + h) * S_ + sp) * D_ + dl] = f2bf(outv);
        }
      }
    }
  }
}

// ---------------- out-GEMM (EPI=1), original 2-D launch form ----------------
template <int BM, int BN, int EPI>
__global__ __launch_bounds__(256, 3) void k_gemm(
    const u16* __restrict__ A, const u16* __restrict__ Bt,
    int M, int N, int K, EpiP ep) {
  __shared__ alignas(16) u16 ls[2 * BM * 32 + 2 * BN * 32];
  int gx = gridDim.x;
  int nwg = gx * gridDim.y;
  int flat = blockIdx.y * gx + blockIdx.x;
  int cpx = nwg >> 3;
  int swz = (flat & 7) * cpx + (flat >> 3);
  int bm = swz / gx, bn = swz % gx;
  gemm_body<BM, BN, EPI>(A, Bt, K, ep, bm, bn, ls);
}

// ---------------- merged qa + kv GEMMs in one launch --------------------------------
__global__ __launch_bounds__(256, 3) void k_gemm_qakv(
    const u16* __restrict__ lnq, const u16* __restrict__ wqa, u16* __restrict__ qlow,
    const u16* __restrict__ lnkv, const u16* __restrict__ wsel,
    u16* __restrict__ kc, u16* __restrict__ vnat) {
  __shared__ alignas(16) u16 ls[2 * 128 * 32 + 2 * 128 * 32];  // 32 KB (kv max; qa uses prefix)
  int f = blockIdx.x;
  if (f < 544) {
    int swz = (f & 7) * 68 + (f >> 3);
    int bm = swz / 17, bn = swz % 17;
    EpiP ep{};
    ep.kc = kc;
    ep.vt = vnat;
    gemm_body<128, 128, 2>(lnkv, wsel, E_, ep, bm, bn, ls);
  } else {
    int lf = f - 544;
    int bm = (lf & 7) * 8 + (lf >> 3);
    EpiP ep{};
    ep.obf = qlow;
    gemm_body<64, 64, 0>(lnq, wqa, E_, ep, bm, 0, ls);
  }
}

// -------- merged v^T transpose + RoPE GEMMs (independent after v_nat -> d_out) ------
// blocks [0,2048): vtr body (decode == old (32,64) grid: bx=f%32, by=f/32)
// blocks [2048,2560): rope2 q-half; [2560,3072): rope2 k-half
__global__ __launch_bounds__(256, 3) void k_vtr_rope2(
    const u16* __restrict__ vn, u16* __restrict__ vt,
    const u16* __restrict__ Aq, const u16* __restrict__ Btq, u16* __restrict__ outq,
    const u16* __restrict__ Ak, const u16* __restrict__ Btk, u16* __restrict__ outk,
    const float* __restrict__ cost, const float* __restrict__ sint) {
  __shared__ alignas(16) u16 ls[2 * 128 * 32 + 2 * 128 * 32];  // 32 KB; vtr uses prefix
  int f0 = blockIdx.x;
  if (f0 < 2048) {
    // ---- vtr body (64x64 ushort4 tiles via padded LDS in ls prefix) ----
    u16(*t)[68] = (u16(*)[68])ls;  // 64*68*2 = 8704 B
    int bx = f0 % 32, by = f0 / 32;
    int c0 = bx * 64;
    int b = by >> 5;
    int s0 = (by & 31) * 64;
#pragma unroll
    for (int i = 0; i < 4; i++) {
      int flat = threadIdx.x + i * 256;
      int r = flat >> 4, q = flat & 15;
      ushort4 v = *(const ushort4*)&vn[((size_t)(b * 2048 + s0 + r)) * 2048 + c0 + q * 4];
      t[r][q * 4 + 0] = v.x;
      t[r][q * 4 + 1] = v.y;
      t[r][q * 4 + 2] = v.z;
      t[r][q * 4 + 3] = v.w;
    }
    __syncthreads();
#pragma unroll
    for (int i = 0; i < 4; i++) {
      int flat = threadIdx.x + i * 256;
      int c = flat >> 4, q = flat & 15;
      ushort4 v;
      v.x = t[q * 4 + 0][c];
      v.y = t[q * 4 + 1][c];
      v.z = t[q * 4 + 2][c];
      v.w = t[q * 4 + 3][c];
      *(ushort4*)&vt[((size_t)(b * 2048 + c0 + c)) * 2048 + s0 + q * 4] = v;
    }
  } else {
    // ---- rope2 body (verbatim round-29 decode on f = f0 - 2048) ----
    int f = f0 - 2048;
    bool isK = f >= 512;
    int lf = f & 511;
    int swz = (lf & 7) * 64 + (lf >> 3);
    int bm = swz >> 4, bn = swz & 15;
    EpiP ep{};
    ep.cost = cost;
    ep.sint = sint;
    if (isK) {
      ep.qk = outk;
      gemm_body<128, 128, 3>(Ak, Btk, KR_, ep, bm, bn, ls);
    } else {
      ep.qk = outq;
      gemm_body<128, 128, 3>(Aq, Btq, QR_, ep, bm, bn, ls);
    }
  }
}

// ---------------- causal flash attention (split-K blocks + LPT refill) ----------------
__global__ __launch_bounds__(256, 2) void k_attn(
    const u16* __restrict__ q_r, const u16* __restrict__ k_r,
    const u16* __restrict__ v_t, u16* __restrict__ y) {
  __shared__ alignas(16) u16 Ks[2][2][32 * 128];  // [dbuf][grp] K tile 32x128
  __shared__ alignas(16) u16 Vs[2][2][64 * 64];   // [dbuf][grp] packed V^T
  __shared__ float Ml[2][2][32];
  int tid = threadIdx.x, lane = tid & 63, wid = tid >> 6;  // wid 0..3
  int id = blockIdx.x;
  int bh = ((id & 7) << 2) | ((id >> 3) & 3);  // XCD-pinned: 4 bh per XCD
  int j = 31 - (id >> 5);                      // heavy tiles dispatched first
  int w2 = wid & 1, grp = wid >> 1;
  int b = bh >> 4, h = bh & 15;
  int li = lane & 31, hi = lane >> 5;
  int qb = 64 * j + w2 * 32;
  int qrow = qb + li;
  int n = j + 1;
  int kg_base = grp * 32 * n;
  const u16* qbase = q_r + (size_t)bh * S_ * D_;
  const u16* kbase = k_r + (size_t)bh * S_ * D_;
  const u16* vbase = v_t + (size_t)bh * D_ * S_;

  bf16x8 aq[8];
#pragma unroll
  for (int step = 0; step < 8; step++)
    aq[step] = *(const bf16x8*)&qbase[(size_t)qrow * D_ + step * 16 + hi * 8];

  f32x16 o[4];
#pragma unroll
  for (int dt = 0; dt < 4; dt++)
#pragma unroll
    for (int r = 0; r < 16; r++) o[dt][r] = 0.f;
  float mreg = -1e30f, lreg = 0.f;

  int kr_l = w2 * 16 + (lane >> 4);  // + i*4
  int kc_l = (lane & 15) * 8;
  int kswz = (li & 7) << 4;

  auto stage = [&](int nb, int p) {
    int kg0 = kg_base + p * 32;
    u16* Kst = &Ks[nb][grp][0];
    u16* Vst = &Vs[nb][grp][0];
#pragma unroll
    for (int i = 0; i < 4; i++) {
      int r = kr_l + i * 4;
      __builtin_amdgcn_global_load_lds(
          (gvoid*)(kbase + (size_t)(kg0 + r) * D_ + (kc_l ^ ((r & 7) << 3))),
          (lvoid*)(&Kst[r * 128 + kc_l]), 16, 0, 0);
    }
#pragma unroll
    for (int i = 0; i < 4; i++) {
      int r = w2 * 32 + i * 8 + (lane >> 3);
      int ss = lane & 7;
      int s = ss ^ (r & 7);
      int d = ((s >> 2) << 6) + r;        // slot half selects d or d+64
      int kk = kg0 + (s & 3) * 8;
      __builtin_amdgcn_global_load_lds(
          (gvoid*)(vbase + (size_t)d * S_ + kk),
          (lvoid*)(&Vst[r * 64 + ss * 8]), 16, 0, 0);
    }
  };

  stage(0, 0);
  int cbuf = 0;

  for (int p = 0; p < n; ++p) {
    int kg0 = kg_base + p * 32;
    asm volatile("s_waitcnt vmcnt(0)" ::: "memory");  // my loads landed (flew under compute)
    __builtin_amdgcn_s_barrier();                      // everyone's loads landed
    asm volatile("" ::: "memory");                     // fence only; scheduling stays free
    if (p + 1 < n) stage(cbuf ^ 1, p + 1);             // overlaps this iter's compute
    if (kg0 <= qb + 31) {
      bool domask = (kg0 + 31 > qb);
      const char* Kc = (const char*)&Ks[cbuf][grp][0];
      const char* Vc = (const char*)&Vs[cbuf][grp][0];
      // ---- QK^T (swapped), 32 keys; accumulator chain split in two (latency) ----
      bf16x8 kf[8];
#pragma unroll
      for (int step = 0; step < 8; step++)
        kf[step] = *(const bf16x8*)(Kc + li * 256 + ((step * 32 + hi * 16) ^ kswz));
      f32x16 c0, c1;
#pragma unroll
      for (int r = 0; r < 16; r++) { c0[r] = 0.f; c1[r] = 0.f; }
      __builtin_amdgcn_s_setprio(1);
#pragma unroll
      for (int step = 0; step < 4; step++) {
        c0 = __builtin_amdgcn_mfma_f32_32x32x16_bf16(kf[step], aq[step], c0, 0, 0, 0);
        c1 = __builtin_amdgcn_mfma_f32_32x32x16_bf16(kf[step + 4], aq[step + 4], c1, 0, 0, 0);
      }
      __builtin_amdgcn_s_setprio(0);
      float ps[16];
#pragma unroll
      for (int r = 0; r < 16; r++) ps[r] = (c0[r] + c1[r]) * SCL2_;  // exp2 domain
      if (domask) {  // wave-uniform boundary branch
#pragma unroll
        for (int r = 0; r < 16; r++) {
          int k = kg0 + (r & 3) + 8 * (r >> 2) + 4 * hi;
          if (k > qrow) ps[r] = -1e30f;
        }
      }
      // ---- in-register softmax (one q row per lane) ----
      float t8[8];
#pragma unroll
      for (int r = 0; r < 8; r++) t8[r] = fmaxf(ps[r], ps[r + 8]);
#pragma unroll
      for (int r = 0; r < 4; r++) t8[r] = fmaxf(t8[r], t8[r + 4]);
      float mt = fmaxf(fmaxf(t8[0], t8[1]), fmaxf(t8[2], t8[3]));
      mt = fmaxf(mt, __shfl_xor(mt, 32));
      // T13 defer-max
      if (!__all(mt <= mreg + 8.f)) {
        float mn = fmaxf(mreg, mt);
        float al = __builtin_amdgcn_exp2f(mreg - mn);
        mreg = mn;
        lreg *= al;
#pragma unroll
        for (int dt = 0; dt < 4; dt++)
#pragma unroll
          for (int r = 0; r < 16; r++) o[dt][r] *= al;
      }
#pragma unroll
      for (int r = 0; r < 16; r++) ps[r] = __builtin_amdgcn_exp2f(ps[r] - mreg);
      float s8[8];
#pragma unroll
      for (int r = 0; r < 8; r++) s8[r] = ps[r] + ps[r + 8];
#pragma unroll
      for (int r = 0; r < 4; r++) s8[r] = s8[r] + s8[r + 4];
      float rs = (s8[0] + s8[1]) + (s8[2] + s8[3]);
      rs += __shfl_xor(rs, 32);
      lreg += rs;
      // ---- PV: B-fragment in-register via cvt_pk + permlane32_swap (T12) ----
#pragma unroll
      for (int ks = 0; ks < 2; ks++) {
        const int bix = ks * 8;
        unsigned P0, P1, P2, P3;
        asm("v_cvt_pk_bf16_f32 %0, %1, %2" : "=v"(P0) : "v"(ps[bix + 0]), "v"(ps[bix + 1]));
        asm("v_cvt_pk_bf16_f32 %0, %1, %2" : "=v"(P1) : "v"(ps[bix + 2]), "v"(ps[bix + 3]));
        asm("v_cvt_pk_bf16_f32 %0, %1, %2" : "=v"(P2) : "v"(ps[bix + 4]), "v"(ps[bix + 5]));
        asm("v_cvt_pk_bf16_f32 %0, %1, %2" : "=v"(P3) : "v"(ps[bix + 6]), "v"(ps[bix + 7]));
        asm("v_permlane32_swap_b32 %0, %1" : "+v"(P0), "+v"(P2));
        asm("v_permlane32_swap_b32 %0, %1" : "+v"(P1), "+v"(P3));
        bf16x8 bp = __builtin_bit_cast(bf16x8, (u32x4){P0, P1, P2, P3});
        bf16x8 vf[4];
#pragma unroll
        for (int dt = 0; dt < 4; dt++) {
          int row = ((dt & 1) << 5) + li;
          vf[dt] = *(const bf16x8*)(Vc + row * 128 +
                                    ((((dt >> 1) * 4 + ks * 2 + hi) * 16) ^ ((row & 7) << 4)));
        }
        __builtin_amdgcn_s_setprio(1);
#pragma unroll
        for (int dt = 0; dt < 4; dt++)
          o[dt] = __builtin_amdgcn_mfma_f32_32x32x16_bf16(vf[dt], bp, o[dt], 0, 0, 0);
        __builtin_amdgcn_s_setprio(0);
      }
    }
    cbuf ^= 1;
  }
  // ---- merge partials: grp0 writes, grp1 combines + stores ----
  __syncthreads();
  float* fb = (float*)&Ks[0][0][0] + w2 * 4096;  // 16 KB region per writer wave
  if (grp == 0) {
#pragma unroll
    for (int k = 0; k < 64; ++k) fb[k * 64 + lane] = o[k >> 4][k & 15];
    if (lane < 32) {
      Ml[w2][0][li] = mreg;
      Ml[w2][1][li] = lreg;
    }
  }
  __syncthreads();
  if (grp == 1) {
    float m1 = Ml[w2][0][li], l1 = Ml[w2][1][li];
    float m = fmaxf(mreg, m1);
    float s2 = __builtin_amdgcn_exp2f(mreg - m);
    float s1 = __builtin_amdgcn_exp2f(m1 - m);
    float lsum = lreg * s2 + l1 * s1;
    float rl = 1.0f / lsum;
    u16* yrow = y + ((size_t)(b * S_ + qrow)) * E_ + h * D_;
#pragma unroll
    for (int dt = 0; dt < 4; dt++) {
#pragma unroll
      for (int g2 = 0; g2 < 4; g2++) {
        int d = dt * 32 + 8 * g2 + 4 * hi;
        ushort4 sv;
        float v0 = (o[dt][4 * g2 + 0] * s2 + fb[(dt * 16 + 4 * g2 + 0) * 64 + lane] * s1) * rl;
        float v1 = (o[dt][4 * g2 + 1] * s2 + fb[(dt * 16 + 4 * g2 + 1) * 64 + lane] * s1) * rl;
        float v2 = (o[dt][4 * g2 + 2] * s2 + fb[(dt * 16 + 4 * g2 + 2) * 64 + lane] * s1) * rl;
        float v3 = (o[dt][4 * g2 + 3] * s2 + fb[(dt * 16 + 4 * g2 + 3) * 64 + lane] * s1) * rl;
        sv.x = f2bf(v0);
        sv.y = f2bf(v1);
        sv.z = f2bf(v2);
        sv.w = f2bf(v3);
        *(ushort4*)(yrow + d) = sv;
      }
    }
  }
}

// ---------------- host ----------------
extern "C" void kernel_launch(void* const* d_in, const int* in_sizes, int n_in,
                              void* d_out, int out_size, void* d_ws, size_t ws_size,
                              hipStream_t stream) {
  const float* x = (const float*)d_in[0];
  const float* g_q = (const float*)d_in[1];
  const float* g_kv = (const float*)d_in[2];
  const float* w_qa = (const float*)d_in[3];
  const float* w_qb = (const float*)d_in[4];
  const float* w_kva = (const float*)d_in[5];
  const float* w_kvb = (const float*)d_in[6];
  const float* w_o = (const float*)d_in[7];
  float* out = (float*)d_out;
  char* ws = (char*)d_ws;

  size_t off = 0;
  float* cos_t = (float*)(ws + off); off += (size_t)S_ * 32 * 4;
  float* sin_t = (float*)(ws + off); off += (size_t)S_ * 32 * 4;
  u16* wqa_t = (u16*)(ws + off); off += (size_t)QR_ * E_ * 2;
  u16* wqb_t = (u16*)(ws + off); off += (size_t)E_ * QR_ * 2;
  u16* wkvb_t = (u16*)(ws + off); off += (size_t)E_ * KR_ * 2;
  u16* wo_t = (u16*)(ws + off); off += (size_t)E_ * E_ * 2;
  u16* wsel_t = (u16*)(ws + off); off += (size_t)NSEL_ * E_ * 2;
  u16* qlow = (u16*)(ws + off); off += (size_t)T_ * QR_ * 2;
  u16* kc = (u16*)(ws + off); off += (size_t)T_ * KR_ * 2;
  u16* ln_q = (u16*)(ws + off); off += (size_t)T_ * E_ * 2;   // reused as y
  u16* ln_kv = (u16*)(ws + off); off += (size_t)T_ * E_ * 2;  // reused as q_r
  u16* k_rb = (u16*)(ws + off); off += (size_t)T_ * E_ * 2;   // k_r (no alias now)
  u16* v_tb = (u16*)(ws + off); off += (size_t)T_ * E_ * 2;
  u16* y = ln_q;
  u16* q_rb = ln_kv;
  u16* v_nat = (u16*)d_out;  // scratch in d_out (16 MB of 32 MB); overwritten by out-GEMM

  // merged pre-pass: LN (+RoPE tables) and all five weight transposes, one launch
  k_pre<<<dim3(T_ + 8960), dim3(256), 0, stream>>>(
      x, g_q, g_kv, ln_q, ln_kv, cos_t, sin_t,
      w_qa, w_qb, w_kvb, w_o, w_kva, wqa_t, wqb_t, wkvb_t, wo_t, wsel_t);

  // merged qa + kv GEMMs: 544 kv blocks + 64 qa blocks (v natural -> d_out scratch)
  k_gemm_qakv<<<dim3(608), dim3(256), 0, stream>>>(
      ln_q, wqa_t, qlow, ln_kv, wsel_t, kc, v_nat);

  // merged v^T transpose + RoPE GEMMs (independent now): 2048 + 1024 blocks
  k_vtr_rope2<<<dim3(3072), dim3(256), 0, stream>>>(
      v_nat, v_tb, qlow, wqb_t, q_rb, kc, wkvb_t, k_rb, cos_t, sin_t);

  // attention -> y (overwrites ln_q). 1024 blocks x 4 waves, split-K + LPT refill.
  k_attn<<<dim3(1024), dim3(256), 0, stream>>>(q_rb, k_rb, v_tb, y);

  // out = y @ w_o  (M=4096, N=2048, K=2048), fp32 (overwrites d_out scratch)
  {
    EpiP ep{};
    ep.of32 = out;
    k_gemm<128, 128, 1><<<dim3(E_ / 128, T_ / 128), dim3(256), 0, stream>>>(y, wo_t, T_, E_, E_, ep);
  }
}